// Round 3
// baseline (1072.269 us; speedup 1.0000x reference)
//
#include <hip/hip_runtime.h>
#include <hip/hip_bf16.h>

// Problem constants
#define B_   16
#define C_   512
#define N_   1024   // H*W = 32*32
#define L_   512
#define CTX_ 768
#define NH_  8
#define HD_  64
#define EPS_ 1e-5f

// ---------------------------------------------------------------------------
// Kernel 1: LayerNorm over C with transpose (B,C,N) -> hn[(b*N+n)*C + c]
// grid (B, N/64), 256 threads. Coalesced reads along n, LDS-transposed writes
// coalesced along c.
// ---------------------------------------------------------------------------
__global__ __launch_bounds__(256) void ln_kernel(const float* __restrict__ x,
                                                 const float* __restrict__ w,
                                                 const float* __restrict__ bia,
                                                 float* __restrict__ hn) {
  const int b  = blockIdx.x;
  const int n0 = blockIdx.y * 64;
  const int tid = threadIdx.x;
  const int nx = tid & 63, cg = tid >> 6;
  const float* xb = x + (size_t)b * C_ * N_;

  float s = 0.f, s2 = 0.f;
  for (int c = cg; c < C_; c += 4) {
    float v = xb[(size_t)c * N_ + n0 + nx];
    s += v; s2 += v * v;
  }
  __shared__ float red[2][4][64];
  __shared__ float mean[64], rstd[64];
  red[0][cg][nx] = s; red[1][cg][nx] = s2;
  __syncthreads();
  if (cg == 0) {
    float ss  = red[0][0][nx] + red[0][1][nx] + red[0][2][nx] + red[0][3][nx];
    float ss2 = red[1][0][nx] + red[1][1][nx] + red[1][2][nx] + red[1][3][nx];
    float mu  = ss * (1.f / C_);
    float var = ss2 * (1.f / C_) - mu * mu;
    mean[nx] = mu;
    rstd[nx] = rsqrtf(var + EPS_);
  }
  __syncthreads();

  __shared__ float tile[64][65];
  for (int ct = 0; ct < 8; ++ct) {
    const int c0 = ct * 64;
    for (int cy = cg; cy < 64; cy += 4)
      tile[cy][nx] = xb[(size_t)(c0 + cy) * N_ + n0 + nx];
    __syncthreads();
    const int cx = tid & 63, ng = tid >> 6;
    const float wv = w[c0 + cx], bv = bia[c0 + cx];
    for (int ny = ng; ny < 64; ny += 4) {
      float val = (tile[cx][ny] - mean[ny]) * rstd[ny] * wv + bv;
      hn[((size_t)b * N_ + n0 + ny) * C_ + c0 + cx] = val;
    }
    __syncthreads();
  }
}

// ---------------------------------------------------------------------------
// Kernel 2: fp32 GEMM  out[m][e] = sum_k A[m][k] * W[e][k],  E = 512 fixed.
// A: (M,K) row-major.  W: (512,K) row-major.  out: (M,512) row-major.
// 128x128 block tile, BK=32, 256 threads, 8x8 micro-tile per thread.
// ---------------------------------------------------------------------------
#define BM 128
#define BE 128
#define BK 32

__global__ __launch_bounds__(256) void gemm_kernel(const float* __restrict__ A,
                                                   const float* __restrict__ W,
                                                   float* __restrict__ out,
                                                   int M, int K) {
  __shared__ float la[BK][BM + 4];
  __shared__ float lb[BK][BE + 4];
  const int m0 = blockIdx.x * BM;
  const int e0 = blockIdx.y * BE;
  const int tid = threadIdx.x;
  const int tx = tid & 15, ty = tid >> 4;
  const int f = tid & 7, r = tid >> 3;   // staging map: 8 float4 per 32-float k-row

  float acc[8][8] = {};

  for (int k0 = 0; k0 < K; k0 += BK) {
#pragma unroll
    for (int i = 0; i < 4; ++i) {
      const int row = r + i * 32;
      const float4 va = *(const float4*)&A[(size_t)(m0 + row) * K + k0 + f * 4];
      la[f * 4 + 0][row] = va.x;
      la[f * 4 + 1][row] = va.y;
      la[f * 4 + 2][row] = va.z;
      la[f * 4 + 3][row] = va.w;
      const float4 vb = *(const float4*)&W[(size_t)(e0 + row) * K + k0 + f * 4];
      lb[f * 4 + 0][row] = vb.x;
      lb[f * 4 + 1][row] = vb.y;
      lb[f * 4 + 2][row] = vb.z;
      lb[f * 4 + 3][row] = vb.w;
    }
    __syncthreads();
#pragma unroll 4
    for (int kk = 0; kk < BK; ++kk) {
      const float4 a0 = *(const float4*)&la[kk][ty * 8];
      const float4 a1 = *(const float4*)&la[kk][ty * 8 + 4];
      const float4 b0 = *(const float4*)&lb[kk][tx * 8];
      const float4 b1 = *(const float4*)&lb[kk][tx * 8 + 4];
      const float av[8] = {a0.x, a0.y, a0.z, a0.w, a1.x, a1.y, a1.z, a1.w};
      const float bv[8] = {b0.x, b0.y, b0.z, b0.w, b1.x, b1.y, b1.z, b1.w};
#pragma unroll
      for (int i = 0; i < 8; ++i)
#pragma unroll
        for (int j = 0; j < 8; ++j)
          acc[i][j] = fmaf(av[i], bv[j], acc[i][j]);
    }
    __syncthreads();
  }

#pragma unroll
  for (int i = 0; i < 8; ++i) {
    float4* o = (float4*)&out[(size_t)(m0 + ty * 8 + i) * 512 + e0 + tx * 8];
    o[0] = make_float4(acc[i][0], acc[i][1], acc[i][2], acc[i][3]);
    o[1] = make_float4(acc[i][4], acc[i][5], acc[i][6], acc[i][7]);
  }
}

// ---------------------------------------------------------------------------
// Kernel 3: flash-style cross attention.
// grid (N/256, NH, B), 256 threads; each thread owns one q-row (64 floats in
// regs + 64-float out accumulator). K/V staged in LDS in 128-row chunks,
// broadcast reads. Online softmax with -1e30 masking (mask[:,0] always true).
// q,k,v laid out as (B*rows, 512) with head h occupying cols h*64..h*64+63.
// ---------------------------------------------------------------------------
__global__ __launch_bounds__(256) void attn_kernel(const float* __restrict__ q,
                                                   const float* __restrict__ k,
                                                   const float* __restrict__ v,
                                                   const int* __restrict__ mask,
                                                   float* __restrict__ o) {
  const int h = blockIdx.y, b = blockIdx.z;
  const int tid = threadIdx.x;
  const int n = blockIdx.x * 256 + tid;
  __shared__ float kl[128][64];
  __shared__ float vl[128][64];
  __shared__ float ml[128];
  const float scale = 0.125f;  // 1/sqrt(64)

  float4 qr[16];
  {
    const float4* qp = (const float4*)&q[((size_t)b * N_ + n) * C_ + h * HD_];
#pragma unroll
    for (int i = 0; i < 16; ++i) qr[i] = qp[i];
  }
  float acc[64] = {};
  float m_run = -1e30f, l_run = 0.f;

  for (int l0 = 0; l0 < L_; l0 += 128) {
    const int f = tid & 15, r0 = tid >> 4;
#pragma unroll
    for (int i = 0; i < 8; ++i) {
      const int l = r0 + i * 16;
      const float4* kp = (const float4*)&k[((size_t)b * L_ + l0 + l) * C_ + h * HD_];
      ((float4*)kl[l])[f] = kp[f];
      const float4* vp = (const float4*)&v[((size_t)b * L_ + l0 + l) * C_ + h * HD_];
      ((float4*)vl[l])[f] = vp[f];
    }
    if (tid < 128) ml[tid] = (mask[b * L_ + l0 + tid] != 0) ? 1.f : 0.f;
    __syncthreads();

    for (int s0 = 0; s0 < 128; s0 += 32) {
      float sc[32];
#pragma unroll
      for (int j = 0; j < 32; ++j) {
        const float4* kr = (const float4*)kl[s0 + j];
        float ss = 0.f;
#pragma unroll
        for (int d4 = 0; d4 < 16; ++d4) {
          const float4 k4 = kr[d4];
          ss = fmaf(qr[d4].x, k4.x, ss);
          ss = fmaf(qr[d4].y, k4.y, ss);
          ss = fmaf(qr[d4].z, k4.z, ss);
          ss = fmaf(qr[d4].w, k4.w, ss);
        }
        sc[j] = (ml[s0 + j] > 0.f) ? ss * scale : -1e30f;
      }
      float mx = m_run;
#pragma unroll
      for (int j = 0; j < 32; ++j) mx = fmaxf(mx, sc[j]);
      const float corr = __expf(m_run - mx);
      m_run = mx;
      l_run *= corr;
#pragma unroll
      for (int d = 0; d < 64; ++d) acc[d] *= corr;
#pragma unroll
      for (int j = 0; j < 32; ++j) {
        const float p = __expf(sc[j] - m_run);
        l_run += p;
        const float4* vr = (const float4*)vl[s0 + j];
#pragma unroll
        for (int d4 = 0; d4 < 16; ++d4) {
          const float4 v4 = vr[d4];
          acc[d4 * 4 + 0] = fmaf(p, v4.x, acc[d4 * 4 + 0]);
          acc[d4 * 4 + 1] = fmaf(p, v4.y, acc[d4 * 4 + 1]);
          acc[d4 * 4 + 2] = fmaf(p, v4.z, acc[d4 * 4 + 2]);
          acc[d4 * 4 + 3] = fmaf(p, v4.w, acc[d4 * 4 + 3]);
        }
      }
    }
    __syncthreads();
  }

  const float inv = 1.f / l_run;
  float4* op = (float4*)&o[((size_t)b * N_ + n) * C_ + h * HD_];
#pragma unroll
  for (int i = 0; i < 16; ++i)
    op[i] = make_float4(acc[i * 4 + 0] * inv, acc[i * 4 + 1] * inv,
                        acc[i * 4 + 2] * inv, acc[i * 4 + 3] * inv);
}

// ---------------------------------------------------------------------------
// Kernel 4: transpose + residual:  out[b][c][n] = O[(b*N+n)*C + c] + x[b][c][n]
// grid (N/64, C/64, B), 256 threads.
// ---------------------------------------------------------------------------
__global__ __launch_bounds__(256) void trans_res_kernel(const float* __restrict__ O,
                                                        const float* __restrict__ x,
                                                        float* __restrict__ out) {
  const int n0 = blockIdx.x * 64, c0 = blockIdx.y * 64, b = blockIdx.z;
  __shared__ float t[64][65];
  const int tid = threadIdx.x;
  const int cx = tid & 63, g = tid >> 6;
  for (int ny = g; ny < 64; ny += 4)
    t[ny][cx] = O[((size_t)b * N_ + n0 + ny) * C_ + c0 + cx];
  __syncthreads();
  const int nx = tid & 63;
  for (int cy = g; cy < 64; cy += 4) {
    const size_t idx = (size_t)b * C_ * N_ + (size_t)(c0 + cy) * N_ + n0 + nx;
    out[idx] = t[nx][cy] + x[idx];
  }
}

// ---------------------------------------------------------------------------
// Launch
// ---------------------------------------------------------------------------
extern "C" void kernel_launch(void* const* d_in, const int* in_sizes, int n_in,
                              void* d_out, int out_size, void* d_ws, size_t ws_size,
                              hipStream_t stream) {
  (void)in_sizes; (void)n_in; (void)out_size; (void)ws_size;
  const float* x       = (const float*)d_in[0];
  const float* context = (const float*)d_in[1];
  const int*   mask    = (const int*)d_in[2];
  const float* ln_w    = (const float*)d_in[3];
  const float* ln_b    = (const float*)d_in[4];
  const float* Wq      = (const float*)d_in[5];
  const float* Wk      = (const float*)d_in[6];
  const float* Wv      = (const float*)d_in[7];
  const float* Wo      = (const float*)d_in[8];
  const float* Wctx    = (const float*)d_in[9];

  float* ws = (float*)d_ws;
  // Workspace layout (floats). Total 29,360,128 floats = 112 MB.
  float* qb   = ws;              // 16384x512
  float* kb   = ws + 8388608;    //  8192x512
  float* vb   = ws + 12582912;   //  8192x512
  float* hn   = ws + 16777216;   // 16384x512 (layernormed hidden)
  float* ctx  = ws + 25165824;   //  8192x512
  float* atto = hn;              // reuse: hn dead after q-projection
  float* Ob   = qb;              // reuse: q dead after attention

  // 1. LayerNorm + transpose
  ln_kernel<<<dim3(B_, N_ / 64), 256, 0, stream>>>(x, ln_w, ln_b, hn);
  // 2. ctx = context @ Wctx^T   (M=8192, K=768)
  gemm_kernel<<<dim3(8192 / BM, 512 / BE), 256, 0, stream>>>(context, Wctx, ctx, 8192, CTX_);
  // 3. k = ctx @ Wk^T, v = ctx @ Wv^T   (M=8192, K=512)
  gemm_kernel<<<dim3(8192 / BM, 512 / BE), 256, 0, stream>>>(ctx, Wk, kb, 8192, C_);
  gemm_kernel<<<dim3(8192 / BM, 512 / BE), 256, 0, stream>>>(ctx, Wv, vb, 8192, C_);
  // 4. q = hn @ Wq^T   (M=16384, K=512)
  gemm_kernel<<<dim3(16384 / BM, 512 / BE), 256, 0, stream>>>(hn, Wq, qb, 16384, C_);
  // 5. attention
  attn_kernel<<<dim3(N_ / 256, NH_, B_), 256, 0, stream>>>(qb, kb, vb, mask, atto);
  // 6. O = atto @ Wo^T   (M=16384, K=512)
  gemm_kernel<<<dim3(16384 / BM, 512 / BE), 256, 0, stream>>>(atto, Wo, Ob, 16384, C_);
  // 7. transpose + residual -> (B,C,H,W)
  trans_res_kernel<<<dim3(N_ / 64, C_ / 64, B_), 256, 0, stream>>>(Ob, x, (float*)d_out);
}

// Round 5
// 259.065 us; speedup vs baseline: 4.1390x; 4.1390x over previous
//
#include <hip/hip_runtime.h>

// Problem constants
#define B_   16
#define C_   512
#define N_   1024   // H*W
#define L_   512
#define CTX_ 768
#define NH_  8
#define HD_  64
#define EPS_ 1e-5f

typedef short bfrag __attribute__((ext_vector_type(8)));   // 8 x bf16 bits
typedef float f32x4 __attribute__((ext_vector_type(4)));

__device__ __forceinline__ ushort f2bf(float f) {  // RNE f32->bf16 (finite inputs)
  union { float f; unsigned u; } v; v.f = f;
  unsigned r = v.u + 0x7fffu + ((v.u >> 16) & 1u);
  return (ushort)(r >> 16);
}

__device__ __forceinline__ f32x4 mfma16(bfrag a, bfrag b, f32x4 c) {
  return __builtin_amdgcn_mfma_f32_16x16x32_bf16(a, b, c, 0, 0, 0);
}

// ---------------------------------------------------------------------------
// cast fp32 -> bf16, 4 elems/thread
// ---------------------------------------------------------------------------
__global__ __launch_bounds__(256) void cast_kernel(const float* __restrict__ in,
                                                   ushort* __restrict__ out, int n4) {
  int i = blockIdx.x * 256 + threadIdx.x;
  if (i < n4) {
    float4 vv = ((const float4*)in)[i];
    ushort4 o;
    o.x = f2bf(vv.x); o.y = f2bf(vv.y); o.z = f2bf(vv.z); o.w = f2bf(vv.w);
    ((ushort4*)out)[i] = o;
  }
}

// ---------------------------------------------------------------------------
// LayerNorm over C with transpose (B,C,N) -> bf16 hn[(b*N+n)*C + c]
// ---------------------------------------------------------------------------
__global__ __launch_bounds__(256) void ln_kernel(const float* __restrict__ x,
                                                 const float* __restrict__ w,
                                                 const float* __restrict__ bia,
                                                 ushort* __restrict__ hn) {
  const int b  = blockIdx.x;
  const int n0 = blockIdx.y * 64;
  const int tid = threadIdx.x;
  const int nx = tid & 63, cg = tid >> 6;
  const float* xb = x + (size_t)b * C_ * N_;

  float s = 0.f, s2 = 0.f;
  for (int c = cg; c < C_; c += 4) {
    float v = xb[(size_t)c * N_ + n0 + nx];
    s += v; s2 += v * v;
  }
  __shared__ float red[2][4][64];
  __shared__ float mean[64], rstd[64];
  red[0][cg][nx] = s; red[1][cg][nx] = s2;
  __syncthreads();
  if (cg == 0) {
    float ss  = red[0][0][nx] + red[0][1][nx] + red[0][2][nx] + red[0][3][nx];
    float ss2 = red[1][0][nx] + red[1][1][nx] + red[1][2][nx] + red[1][3][nx];
    float mu  = ss * (1.f / C_);
    float var = ss2 * (1.f / C_) - mu * mu;
    mean[nx] = mu;
    rstd[nx] = rsqrtf(var + EPS_);
  }
  __syncthreads();

  __shared__ float tile[64][65];
  for (int ct = 0; ct < 8; ++ct) {
    const int c0 = ct * 64;
    for (int cy = cg; cy < 64; cy += 4)
      tile[cy][nx] = xb[(size_t)(c0 + cy) * N_ + n0 + nx];
    __syncthreads();
    const int cx = tid & 63, ng = tid >> 6;
    const float wv = w[c0 + cx], bv = bia[c0 + cx];
    for (int ny = ng; ny < 64; ny += 4) {
      float val = (tile[cx][ny] - mean[ny]) * rstd[ny] * wv + bv;
      hn[((size_t)b * N_ + n0 + ny) * C_ + c0 + cx] = f2bf(val);
    }
    __syncthreads();
  }
}

// ---------------------------------------------------------------------------
// bf16 MFMA GEMM: out[m][e] = sum_k A[m][k]*W[e][k], E=512. 128x128x32 tile,
// 4 waves each 64x64 (4x4 frags of 16x16x32). LDS rows padded to 40 bf16
// (80B stride). fp32 accum.
// Staging: 2 threads/row, each thread writes 2x int4 (32B) per matrix so the
// full 32-element k-row is covered (round-4 bug: only 16 elems were staged).
// ---------------------------------------------------------------------------
template <bool OUTF32>
__global__ __launch_bounds__(256) void gemm_mfma(const ushort* __restrict__ A,
                                                 const ushort* __restrict__ W,
                                                 void* __restrict__ outp,
                                                 int M, int K) {
  __shared__ ushort la[128 * 40];
  __shared__ ushort lb[128 * 40];
  const int m0 = blockIdx.x * 128, e0 = blockIdx.y * 128;
  const int tid = threadIdx.x, lane = tid & 63, w = tid >> 6;
  const int wm = (w >> 1) * 64, we = (w & 1) * 64;
  const int col = lane & 15, rg = lane >> 4;
  const int srow = tid >> 1, sh = (tid & 1) * 16;   // 2 threads/row, 16 elems each

  f32x4 acc[4][4] = {};

  for (int k0 = 0; k0 < K; k0 += 32) {
    {
      const ushort* ap = &A[(size_t)(m0 + srow) * K + k0 + sh];
      const ushort* wp = &W[(size_t)(e0 + srow) * K + k0 + sh];
      *(int4*)&la[srow * 40 + sh]     = *(const int4*)ap;
      *(int4*)&la[srow * 40 + sh + 8] = *(const int4*)(ap + 8);
      *(int4*)&lb[srow * 40 + sh]     = *(const int4*)wp;
      *(int4*)&lb[srow * 40 + sh + 8] = *(const int4*)(wp + 8);
    }
    __syncthreads();
    bfrag af[4], bf[4];
#pragma unroll
    for (int i = 0; i < 4; ++i) {
      af[i] = *(const bfrag*)&la[(wm + i * 16 + col) * 40 + rg * 8];
      bf[i] = *(const bfrag*)&lb[(we + i * 16 + col) * 40 + rg * 8];
    }
#pragma unroll
    for (int i = 0; i < 4; ++i)
#pragma unroll
      for (int j = 0; j < 4; ++j)
        acc[i][j] = mfma16(af[i], bf[j], acc[i][j]);
    __syncthreads();
  }

  // C/D layout (verified m89/m91): col=lane&15, row=(lane>>4)*4+reg
#pragma unroll
  for (int i = 0; i < 4; ++i)
#pragma unroll
    for (int j = 0; j < 4; ++j)
#pragma unroll
      for (int r = 0; r < 4; ++r) {
        const size_t off =
            (size_t)(m0 + wm + i * 16 + rg * 4 + r) * 512 + e0 + we + j * 16 + col;
        if (OUTF32) ((float*)outp)[off] = acc[i][j][r];
        else        ((ushort*)outp)[off] = f2bf(acc[i][j][r]);
      }
}

// ---------------------------------------------------------------------------
// MFMA flash cross-attention, bf16 operands / fp32 softmax+accum.
// grid (N/128, NH, B), 256 thr = 4 waves; wave owns 32 q-rows. K/V in 64-key
// LDS chunks (V transposed for PV B-frags); P via per-wave LDS; online
// softmax wave-parallel (16-lane shfl groups). mask[:,0] always true.
// ---------------------------------------------------------------------------
__global__ __launch_bounds__(256) void attn_mfma(const ushort* __restrict__ q,
                                                 const ushort* __restrict__ k,
                                                 const ushort* __restrict__ v,
                                                 const int* __restrict__ mask,
                                                 ushort* __restrict__ o) {
  __shared__ ushort Kl[64 * 72];      // [key][72] (144B stride)
  __shared__ ushort Vt[64 * 72];      // [d][72]
  __shared__ ushort Pw[4][32 * 72];   // per-wave P [qrow][72]
  __shared__ float mlb[64];

  const int h = blockIdx.y, b = blockIdx.z;
  const int q0 = blockIdx.x * 128;
  const int tid = threadIdx.x, lane = tid & 63, w = tid >> 6;
  const int col = lane & 15, rg = lane >> 4;
  const int wq = w * 32;

  bfrag qf[2][2];
#pragma unroll
  for (int mi = 0; mi < 2; ++mi)
#pragma unroll
    for (int kc = 0; kc < 2; ++kc)
      qf[mi][kc] = *(const bfrag*)
          &q[((size_t)b * N_ + q0 + wq + mi * 16 + col) * C_ + h * HD_ + kc * 32 + rg * 8];

  f32x4 oa[2][4] = {};
  float m_run[2][4], l_run[2][4];
#pragma unroll
  for (int mi = 0; mi < 2; ++mi)
#pragma unroll
    for (int r = 0; r < 4; ++r) { m_run[mi][r] = -1e30f; l_run[mi][r] = 0.f; }

  for (int l0 = 0; l0 < L_; l0 += 64) {
#pragma unroll
    for (int it = 0; it < 2; ++it) {     // K: 64 keys x 128B
      const int idx = it * 256 + tid;
      const int key = idx >> 3, part = idx & 7;
      *(int4*)&Kl[key * 72 + part * 8] =
          *(const int4*)&k[((size_t)b * L_ + l0 + key) * C_ + h * HD_ + part * 8];
    }
#pragma unroll
    for (int it = 0; it < 4; ++it) {     // V transposed: Vt[d][key]
      const int idx = it * 256 + tid;
      const int key = idx & 63, d0 = (idx >> 6) * 4;
      ushort4 vv = *(const ushort4*)&v[((size_t)b * L_ + l0 + key) * C_ + h * HD_ + d0];
      Vt[(d0 + 0) * 72 + key] = vv.x;
      Vt[(d0 + 1) * 72 + key] = vv.y;
      Vt[(d0 + 2) * 72 + key] = vv.z;
      Vt[(d0 + 3) * 72 + key] = vv.w;
    }
    if (tid < 64) mlb[tid] = mask[b * L_ + l0 + tid] ? 0.f : -1e30f;
    __syncthreads();

    // S = Q K^T  (B-frag: col=key, k=d)
    f32x4 s[2][4] = {};
#pragma unroll
    for (int kc = 0; kc < 2; ++kc) {
      bfrag kf[4];
#pragma unroll
      for (int ni = 0; ni < 4; ++ni)
        kf[ni] = *(const bfrag*)&Kl[(ni * 16 + col) * 72 + kc * 32 + rg * 8];
#pragma unroll
      for (int mi = 0; mi < 2; ++mi)
#pragma unroll
        for (int ni = 0; ni < 4; ++ni)
          s[mi][ni] = mfma16(qf[mi][kc], kf[ni], s[mi][ni]);
    }
    // scale + mask (additive bias per key-column)
#pragma unroll
    for (int ni = 0; ni < 4; ++ni) {
      const float bias = mlb[ni * 16 + col];
#pragma unroll
      for (int mi = 0; mi < 2; ++mi)
#pragma unroll
        for (int r = 0; r < 4; ++r)
          s[mi][ni][r] = s[mi][ni][r] * 0.125f + bias;
    }
    // online softmax per q-row (row lives on 16 lanes sharing rg)
#pragma unroll
    for (int mi = 0; mi < 2; ++mi) {
#pragma unroll
      for (int r = 0; r < 4; ++r) {
        float mx = fmaxf(fmaxf(s[mi][0][r], s[mi][1][r]), fmaxf(s[mi][2][r], s[mi][3][r]));
        mx = fmaxf(mx, __shfl_xor(mx, 1));
        mx = fmaxf(mx, __shfl_xor(mx, 2));
        mx = fmaxf(mx, __shfl_xor(mx, 4));
        mx = fmaxf(mx, __shfl_xor(mx, 8));
        const float m_new = fmaxf(m_run[mi][r], mx);
        const float corr = __expf(m_run[mi][r] - m_new);
        m_run[mi][r] = m_new;
        float rs = 0.f;
#pragma unroll
        for (int ni = 0; ni < 4; ++ni) {
          const float p = __expf(s[mi][ni][r] - m_new);
          s[mi][ni][r] = p;
          rs += p;
        }
        rs += __shfl_xor(rs, 1);
        rs += __shfl_xor(rs, 2);
        rs += __shfl_xor(rs, 4);
        rs += __shfl_xor(rs, 8);
        l_run[mi][r] = l_run[mi][r] * corr + rs;
#pragma unroll
        for (int di = 0; di < 4; ++di)
          oa[mi][di][r] *= corr;
      }
    }
    // P (C-layout) -> per-wave LDS as bf16
#pragma unroll
    for (int mi = 0; mi < 2; ++mi)
#pragma unroll
      for (int ni = 0; ni < 4; ++ni)
#pragma unroll
        for (int r = 0; r < 4; ++r)
          Pw[w][(mi * 16 + rg * 4 + r) * 72 + ni * 16 + col] = f2bf(s[mi][ni][r]);
    // PV: A-frag from Pw (row=q, k=key), B-frag from Vt (col=d, k=key)
#pragma unroll
    for (int kc = 0; kc < 2; ++kc) {
      bfrag pf[2], vf[4];
#pragma unroll
      for (int mi = 0; mi < 2; ++mi)
        pf[mi] = *(const bfrag*)&Pw[w][(mi * 16 + col) * 72 + kc * 32 + rg * 8];
#pragma unroll
      for (int di = 0; di < 4; ++di)
        vf[di] = *(const bfrag*)&Vt[(di * 16 + col) * 72 + kc * 32 + rg * 8];
#pragma unroll
      for (int mi = 0; mi < 2; ++mi)
#pragma unroll
        for (int di = 0; di < 4; ++di)
          oa[mi][di] = mfma16(pf[mi], vf[di], oa[mi][di]);
    }
    __syncthreads();
  }

#pragma unroll
  for (int mi = 0; mi < 2; ++mi) {
#pragma unroll
    for (int r = 0; r < 4; ++r) {
      const float inv = 1.f / l_run[mi][r];
      const size_t row = (size_t)b * N_ + q0 + wq + mi * 16 + rg * 4 + r;
#pragma unroll
      for (int di = 0; di < 4; ++di)
        o[row * C_ + h * HD_ + di * 16 + col] = f2bf(oa[mi][di][r] * inv);
    }
  }
}

// ---------------------------------------------------------------------------
// transpose + residual: out[b][c][n] = O[(b*N+n)*C + c] + x[b][c][n]
// ---------------------------------------------------------------------------
__global__ __launch_bounds__(256) void trans_res_kernel(const float* __restrict__ O,
                                                        const float* __restrict__ x,
                                                        float* __restrict__ out) {
  const int n0 = blockIdx.x * 64, c0 = blockIdx.y * 64, b = blockIdx.z;
  __shared__ float t[64][65];
  const int tid = threadIdx.x;
  const int cx = tid & 63, g = tid >> 6;
  for (int ny = g; ny < 64; ny += 4)
    t[ny][cx] = O[((size_t)b * N_ + n0 + ny) * C_ + c0 + cx];
  __syncthreads();
  const int nx = tid & 63;
  for (int cy = g; cy < 64; cy += 4) {
    const size_t idx = (size_t)b * C_ * N_ + (size_t)(c0 + cy) * N_ + n0 + nx;
    out[idx] = t[nx][cy] + x[idx];
  }
}

// ---------------------------------------------------------------------------
// Launch
// ---------------------------------------------------------------------------
extern "C" void kernel_launch(void* const* d_in, const int* in_sizes, int n_in,
                              void* d_out, int out_size, void* d_ws, size_t ws_size,
                              hipStream_t stream) {
  (void)in_sizes; (void)n_in; (void)out_size; (void)ws_size;
  const float* x       = (const float*)d_in[0];
  const float* context = (const float*)d_in[1];
  const int*   mask    = (const int*)d_in[2];
  const float* ln_w    = (const float*)d_in[3];
  const float* ln_b    = (const float*)d_in[4];
  const float* Wq      = (const float*)d_in[5];
  const float* Wk      = (const float*)d_in[6];
  const float* Wv      = (const float*)d_in[7];
  const float* Wo      = (const float*)d_in[8];
  const float* Wctx    = (const float*)d_in[9];

  char* wsb = (char*)d_ws;
  // byte offsets; total ~74 MB
  ushort* qb    = (ushort*)(wsb + 0);          // 16384x512 bf16
  ushort* kb    = (ushort*)(wsb + 16777216);   //  8192x512
  ushort* vb    = (ushort*)(wsb + 25165824);   //  8192x512
  ushort* hn    = (ushort*)(wsb + 33554432);   // 16384x512 (later atto)
  ushort* ctx   = (ushort*)(wsb + 50331648);   //  8192x512
  ushort* ctxb  = (ushort*)(wsb + 58720256);   //  8192x768
  ushort* wctxb = (ushort*)(wsb + 71303168);   //   512x768
  ushort* wqb   = (ushort*)(wsb + 72089600);
  ushort* wkb   = (ushort*)(wsb + 72613888);
  ushort* wvb   = (ushort*)(wsb + 73138176);
  ushort* wob   = (ushort*)(wsb + 73662464);
  float*  Ob    = (float*)(wsb + 0);           // aliases qb..vb (dead after attn)

  cast_kernel<<<6144, 256, 0, stream>>>(context, ctxb, 1572864);
  cast_kernel<<<384, 256, 0, stream>>>(Wctx, wctxb, 98304);
  cast_kernel<<<256, 256, 0, stream>>>(Wq, wqb, 65536);
  cast_kernel<<<256, 256, 0, stream>>>(Wk, wkb, 65536);
  cast_kernel<<<256, 256, 0, stream>>>(Wv, wvb, 65536);
  cast_kernel<<<256, 256, 0, stream>>>(Wo, wob, 65536);
  ln_kernel<<<dim3(B_, N_ / 64), 256, 0, stream>>>(x, ln_w, ln_b, hn);
  gemm_mfma<false><<<dim3(64, 4), 256, 0, stream>>>(ctxb, wctxb, ctx, 8192, CTX_);
  gemm_mfma<false><<<dim3(64, 4), 256, 0, stream>>>(ctx, wkb, kb, 8192, C_);
  gemm_mfma<false><<<dim3(64, 4), 256, 0, stream>>>(ctx, wvb, vb, 8192, C_);
  gemm_mfma<false><<<dim3(128, 4), 256, 0, stream>>>(hn, wqb, qb, 16384, C_);
  attn_mfma<<<dim3(N_ / 128, NH_, B_), 256, 0, stream>>>(qb, kb, vb, mask, hn);
  gemm_mfma<true><<<dim3(128, 4), 256, 0, stream>>>(hn, wob, Ob, 16384, C_);
  trans_res_kernel<<<dim3(N_ / 64, C_ / 64, B_), 256, 0, stream>>>(Ob, x, (float*)d_out);
}

// Round 6
// 227.587 us; speedup vs baseline: 4.7115x; 1.1383x over previous
//
#include <hip/hip_runtime.h>

// Problem constants
#define B_   16
#define C_   512
#define N_   1024   // H*W
#define L_   512
#define CTX_ 768
#define NH_  8
#define HD_  64
#define EPS_ 1e-5f

typedef short bfrag __attribute__((ext_vector_type(8)));   // 8 x bf16 bits
typedef float f32x4 __attribute__((ext_vector_type(4)));

__device__ __forceinline__ ushort f2bf(float f) {  // RNE f32->bf16 (finite inputs)
  union { float f; unsigned u; } v; v.f = f;
  unsigned r = v.u + 0x7fffu + ((v.u >> 16) & 1u);
  return (ushort)(r >> 16);
}

__device__ __forceinline__ f32x4 mfma16(bfrag a, bfrag b, f32x4 c) {
  return __builtin_amdgcn_mfma_f32_16x16x32_bf16(a, b, c, 0, 0, 0);
}

// ---------------------------------------------------------------------------
// cast fp32 -> bf16, 4 elems/thread
// ---------------------------------------------------------------------------
__global__ __launch_bounds__(256) void cast_kernel(const float* __restrict__ in,
                                                   ushort* __restrict__ out, int n4) {
  int i = blockIdx.x * 256 + threadIdx.x;
  if (i < n4) {
    float4 vv = ((const float4*)in)[i];
    ushort4 o;
    o.x = f2bf(vv.x); o.y = f2bf(vv.y); o.z = f2bf(vv.z); o.w = f2bf(vv.w);
    ((ushort4*)out)[i] = o;
  }
}

// ---------------------------------------------------------------------------
// LayerNorm over C with transpose (B,C,N) -> bf16 hn[(b*N+n)*C + c]
// 1024 threads (16 waves/block): round-5 profile showed 256-thread version was
// occupancy-bound (9% occ, VALUBusy 4.8%, HBM 7%). Same structure otherwise.
// ---------------------------------------------------------------------------
__global__ __launch_bounds__(1024) void ln_kernel(const float* __restrict__ x,
                                                  const float* __restrict__ w,
                                                  const float* __restrict__ bia,
                                                  ushort* __restrict__ hn) {
  const int b  = blockIdx.x;
  const int n0 = blockIdx.y * 64;
  const int tid = threadIdx.x;
  const int nx = tid & 63, cg = tid >> 6;   // cg 0..15
  const float* xb = x + (size_t)b * C_ * N_;

  float s = 0.f, s2 = 0.f;
  for (int c = cg; c < C_; c += 16) {       // 32 iters
    float v = xb[(size_t)c * N_ + n0 + nx];
    s += v; s2 += v * v;
  }
  __shared__ float red[2][16][64];
  __shared__ float mean[64], rstd[64];
  red[0][cg][nx] = s; red[1][cg][nx] = s2;
  __syncthreads();
  if (cg == 0) {
    float ss = 0.f, ss2 = 0.f;
#pragma unroll
    for (int i = 0; i < 16; ++i) { ss += red[0][i][nx]; ss2 += red[1][i][nx]; }
    float mu  = ss * (1.f / C_);
    float var = ss2 * (1.f / C_) - mu * mu;
    mean[nx] = mu;
    rstd[nx] = rsqrtf(var + EPS_);
  }
  __syncthreads();

  __shared__ float tile[64][65];
  for (int ct = 0; ct < 8; ++ct) {
    const int c0 = ct * 64;
    for (int cy = cg; cy < 64; cy += 16)    // 4 iters
      tile[cy][nx] = xb[(size_t)(c0 + cy) * N_ + n0 + nx];
    __syncthreads();
    const int cx = tid & 63, ng = tid >> 6;
    const float wv = w[c0 + cx], bv = bia[c0 + cx];
    for (int ny = ng; ny < 64; ny += 16) {  // 4 iters
      float val = (tile[cx][ny] - mean[ny]) * rstd[ny] * wv + bv;
      hn[((size_t)b * N_ + n0 + ny) * C_ + c0 + cx] = f2bf(val);
    }
    __syncthreads();
  }
}

// ---------------------------------------------------------------------------
// bf16 MFMA GEMM: out[m][e] = sum_k A[m][k]*W[e][k], E=512. 128x128x32 tile,
// 4 waves each 64x64 (4x4 frags of 16x16x32). LDS rows padded to 40 bf16
// (80B stride). fp32 accum. Staging: 2 threads/row, 2x int4 each per matrix.
// ---------------------------------------------------------------------------
template <bool OUTF32>
__global__ __launch_bounds__(256) void gemm_mfma(const ushort* __restrict__ A,
                                                 const ushort* __restrict__ W,
                                                 void* __restrict__ outp,
                                                 int M, int K) {
  __shared__ ushort la[128 * 40];
  __shared__ ushort lb[128 * 40];
  const int m0 = blockIdx.x * 128, e0 = blockIdx.y * 128;
  const int tid = threadIdx.x, lane = tid & 63, w = tid >> 6;
  const int wm = (w >> 1) * 64, we = (w & 1) * 64;
  const int col = lane & 15, rg = lane >> 4;
  const int srow = tid >> 1, sh = (tid & 1) * 16;   // 2 threads/row, 16 elems each

  f32x4 acc[4][4] = {};

  for (int k0 = 0; k0 < K; k0 += 32) {
    {
      const ushort* ap = &A[(size_t)(m0 + srow) * K + k0 + sh];
      const ushort* wp = &W[(size_t)(e0 + srow) * K + k0 + sh];
      *(int4*)&la[srow * 40 + sh]     = *(const int4*)ap;
      *(int4*)&la[srow * 40 + sh + 8] = *(const int4*)(ap + 8);
      *(int4*)&lb[srow * 40 + sh]     = *(const int4*)wp;
      *(int4*)&lb[srow * 40 + sh + 8] = *(const int4*)(wp + 8);
    }
    __syncthreads();
    bfrag af[4], bf[4];
#pragma unroll
    for (int i = 0; i < 4; ++i) {
      af[i] = *(const bfrag*)&la[(wm + i * 16 + col) * 40 + rg * 8];
      bf[i] = *(const bfrag*)&lb[(we + i * 16 + col) * 40 + rg * 8];
    }
#pragma unroll
    for (int i = 0; i < 4; ++i)
#pragma unroll
      for (int j = 0; j < 4; ++j)
        acc[i][j] = mfma16(af[i], bf[j], acc[i][j]);
    __syncthreads();
  }

  // C/D layout (verified m89/m91): col=lane&15, row=(lane>>4)*4+reg
#pragma unroll
  for (int i = 0; i < 4; ++i)
#pragma unroll
    for (int j = 0; j < 4; ++j)
#pragma unroll
      for (int r = 0; r < 4; ++r) {
        const size_t off =
            (size_t)(m0 + wm + i * 16 + rg * 4 + r) * 512 + e0 + we + j * 16 + col;
        if (OUTF32) ((float*)outp)[off] = acc[i][j][r];
        else        ((ushort*)outp)[off] = f2bf(acc[i][j][r]);
      }
}

// ---------------------------------------------------------------------------
// MFMA flash cross-attention, bf16 operands / fp32 softmax+accum.
// grid (N/128, NH, B), 256 thr = 4 waves; wave owns 32 q-rows. K/V in 64-key
// LDS chunks (V transposed for PV B-frags); P via per-wave LDS; online
// softmax wave-parallel (16-lane shfl groups). mask[:,0] always true.
// ---------------------------------------------------------------------------
__global__ __launch_bounds__(256) void attn_mfma(const ushort* __restrict__ q,
                                                 const ushort* __restrict__ k,
                                                 const ushort* __restrict__ v,
                                                 const int* __restrict__ mask,
                                                 ushort* __restrict__ o) {
  __shared__ ushort Kl[64 * 72];      // [key][72] (144B stride)
  __shared__ ushort Vt[64 * 72];      // [d][72]
  __shared__ ushort Pw[4][32 * 72];   // per-wave P [qrow][72]
  __shared__ float mlb[64];

  const int h = blockIdx.y, b = blockIdx.z;
  const int q0 = blockIdx.x * 128;
  const int tid = threadIdx.x, lane = tid & 63, w = tid >> 6;
  const int col = lane & 15, rg = lane >> 4;
  const int wq = w * 32;

  bfrag qf[2][2];
#pragma unroll
  for (int mi = 0; mi < 2; ++mi)
#pragma unroll
    for (int kc = 0; kc < 2; ++kc)
      qf[mi][kc] = *(const bfrag*)
          &q[((size_t)b * N_ + q0 + wq + mi * 16 + col) * C_ + h * HD_ + kc * 32 + rg * 8];

  f32x4 oa[2][4] = {};
  float m_run[2][4], l_run[2][4];
#pragma unroll
  for (int mi = 0; mi < 2; ++mi)
#pragma unroll
    for (int r = 0; r < 4; ++r) { m_run[mi][r] = -1e30f; l_run[mi][r] = 0.f; }

  for (int l0 = 0; l0 < L_; l0 += 64) {
#pragma unroll
    for (int it = 0; it < 2; ++it) {     // K: 64 keys x 128B
      const int idx = it * 256 + tid;
      const int key = idx >> 3, part = idx & 7;
      *(int4*)&Kl[key * 72 + part * 8] =
          *(const int4*)&k[((size_t)b * L_ + l0 + key) * C_ + h * HD_ + part * 8];
    }
#pragma unroll
    for (int it = 0; it < 4; ++it) {     // V transposed: Vt[d][key]
      const int idx = it * 256 + tid;
      const int key = idx & 63, d0 = (idx >> 6) * 4;
      ushort4 vv = *(const ushort4*)&v[((size_t)b * L_ + l0 + key) * C_ + h * HD_ + d0];
      Vt[(d0 + 0) * 72 + key] = vv.x;
      Vt[(d0 + 1) * 72 + key] = vv.y;
      Vt[(d0 + 2) * 72 + key] = vv.z;
      Vt[(d0 + 3) * 72 + key] = vv.w;
    }
    if (tid < 64) mlb[tid] = mask[b * L_ + l0 + tid] ? 0.f : -1e30f;
    __syncthreads();

    // S = Q K^T  (B-frag: col=key, k=d)
    f32x4 s[2][4] = {};
#pragma unroll
    for (int kc = 0; kc < 2; ++kc) {
      bfrag kf[4];
#pragma unroll
      for (int ni = 0; ni < 4; ++ni)
        kf[ni] = *(const bfrag*)&Kl[(ni * 16 + col) * 72 + kc * 32 + rg * 8];
#pragma unroll
      for (int mi = 0; mi < 2; ++mi)
#pragma unroll
        for (int ni = 0; ni < 4; ++ni)
          s[mi][ni] = mfma16(qf[mi][kc], kf[ni], s[mi][ni]);
    }
    // scale + mask (additive bias per key-column)
#pragma unroll
    for (int ni = 0; ni < 4; ++ni) {
      const float bias = mlb[ni * 16 + col];
#pragma unroll
      for (int mi = 0; mi < 2; ++mi)
#pragma unroll
        for (int r = 0; r < 4; ++r)
          s[mi][ni][r] = s[mi][ni][r] * 0.125f + bias;
    }
    // online softmax per q-row (row lives on 16 lanes sharing rg)
#pragma unroll
    for (int mi = 0; mi < 2; ++mi) {
#pragma unroll
      for (int r = 0; r < 4; ++r) {
        float mx = fmaxf(fmaxf(s[mi][0][r], s[mi][1][r]), fmaxf(s[mi][2][r], s[mi][3][r]));
        mx = fmaxf(mx, __shfl_xor(mx, 1));
        mx = fmaxf(mx, __shfl_xor(mx, 2));
        mx = fmaxf(mx, __shfl_xor(mx, 4));
        mx = fmaxf(mx, __shfl_xor(mx, 8));
        const float m_new = fmaxf(m_run[mi][r], mx);
        const float corr = __expf(m_run[mi][r] - m_new);
        m_run[mi][r] = m_new;
        float rs = 0.f;
#pragma unroll
        for (int ni = 0; ni < 4; ++ni) {
          const float p = __expf(s[mi][ni][r] - m_new);
          s[mi][ni][r] = p;
          rs += p;
        }
        rs += __shfl_xor(rs, 1);
        rs += __shfl_xor(rs, 2);
        rs += __shfl_xor(rs, 4);
        rs += __shfl_xor(rs, 8);
        l_run[mi][r] = l_run[mi][r] * corr + rs;
#pragma unroll
        for (int di = 0; di < 4; ++di)
          oa[mi][di][r] *= corr;
      }
    }
    // P (C-layout) -> per-wave LDS as bf16
#pragma unroll
    for (int mi = 0; mi < 2; ++mi)
#pragma unroll
      for (int ni = 0; ni < 4; ++ni)
#pragma unroll
        for (int r = 0; r < 4; ++r)
          Pw[w][(mi * 16 + rg * 4 + r) * 72 + ni * 16 + col] = f2bf(s[mi][ni][r]);
    // PV: A-frag from Pw (row=q, k=key), B-frag from Vt (col=d, k=key)
#pragma unroll
    for (int kc = 0; kc < 2; ++kc) {
      bfrag pf[2], vf[4];
#pragma unroll
      for (int mi = 0; mi < 2; ++mi)
        pf[mi] = *(const bfrag*)&Pw[w][(mi * 16 + col) * 72 + kc * 32 + rg * 8];
#pragma unroll
      for (int di = 0; di < 4; ++di)
        vf[di] = *(const bfrag*)&Vt[(di * 16 + col) * 72 + kc * 32 + rg * 8];
#pragma unroll
      for (int mi = 0; mi < 2; ++mi)
#pragma unroll
        for (int di = 0; di < 4; ++di)
          oa[mi][di] = mfma16(pf[mi], vf[di], oa[mi][di]);
    }
    __syncthreads();
  }

#pragma unroll
  for (int mi = 0; mi < 2; ++mi) {
#pragma unroll
    for (int r = 0; r < 4; ++r) {
      const float inv = 1.f / l_run[mi][r];
      const size_t row = (size_t)b * N_ + q0 + wq + mi * 16 + rg * 4 + r;
#pragma unroll
      for (int di = 0; di < 4; ++di)
        o[row * C_ + h * HD_ + di * 16 + col] = f2bf(oa[mi][di][r] * inv);
    }
  }
}

// ---------------------------------------------------------------------------
// transpose + residual: out[b][c][n] = O[(b*N+n)*C + c] + x[b][c][n]
// ---------------------------------------------------------------------------
__global__ __launch_bounds__(256) void trans_res_kernel(const float* __restrict__ O,
                                                        const float* __restrict__ x,
                                                        float* __restrict__ out) {
  const int n0 = blockIdx.x * 64, c0 = blockIdx.y * 64, b = blockIdx.z;
  __shared__ float t[64][65];
  const int tid = threadIdx.x;
  const int cx = tid & 63, g = tid >> 6;
  for (int ny = g; ny < 64; ny += 4)
    t[ny][cx] = O[((size_t)b * N_ + n0 + ny) * C_ + c0 + cx];
  __syncthreads();
  const int nx = tid & 63;
  for (int cy = g; cy < 64; cy += 4) {
    const size_t idx = (size_t)b * C_ * N_ + (size_t)(c0 + cy) * N_ + n0 + nx;
    out[idx] = t[nx][cy] + x[idx];
  }
}

// ---------------------------------------------------------------------------
// Launch
// ---------------------------------------------------------------------------
extern "C" void kernel_launch(void* const* d_in, const int* in_sizes, int n_in,
                              void* d_out, int out_size, void* d_ws, size_t ws_size,
                              hipStream_t stream) {
  (void)in_sizes; (void)n_in; (void)out_size; (void)ws_size;
  const float* x       = (const float*)d_in[0];
  const float* context = (const float*)d_in[1];
  const int*   mask    = (const int*)d_in[2];
  const float* ln_w    = (const float*)d_in[3];
  const float* ln_b    = (const float*)d_in[4];
  const float* Wq      = (const float*)d_in[5];
  const float* Wk      = (const float*)d_in[6];
  const float* Wv      = (const float*)d_in[7];
  const float* Wo      = (const float*)d_in[8];
  const float* Wctx    = (const float*)d_in[9];

  char* wsb = (char*)d_ws;
  // byte offsets; total ~74 MB
  ushort* qb    = (ushort*)(wsb + 0);          // 16384x512 bf16
  ushort* kb    = (ushort*)(wsb + 16777216);   //  8192x512
  ushort* vb    = (ushort*)(wsb + 25165824);   //  8192x512
  ushort* hn    = (ushort*)(wsb + 33554432);   // 16384x512 (later atto)
  ushort* ctx   = (ushort*)(wsb + 50331648);   //  8192x512
  ushort* ctxb  = (ushort*)(wsb + 58720256);   //  8192x768
  ushort* wctxb = (ushort*)(wsb + 71303168);   //   512x768
  ushort* wqb   = (ushort*)(wsb + 72089600);
  ushort* wkb   = (ushort*)(wsb + 72613888);
  ushort* wvb   = (ushort*)(wsb + 73138176);
  ushort* wob   = (ushort*)(wsb + 73662464);
  float*  Ob    = (float*)(wsb + 0);           // aliases qb..vb (dead after attn)

  cast_kernel<<<6144, 256, 0, stream>>>(context, ctxb, 1572864);
  cast_kernel<<<384, 256, 0, stream>>>(Wctx, wctxb, 98304);
  cast_kernel<<<256, 256, 0, stream>>>(Wq, wqb, 65536);
  cast_kernel<<<256, 256, 0, stream>>>(Wk, wkb, 65536);
  cast_kernel<<<256, 256, 0, stream>>>(Wv, wvb, 65536);
  cast_kernel<<<256, 256, 0, stream>>>(Wo, wob, 65536);
  ln_kernel<<<dim3(B_, N_ / 64), 1024, 0, stream>>>(x, ln_w, ln_b, hn);
  gemm_mfma<false><<<dim3(64, 4), 256, 0, stream>>>(ctxb, wctxb, ctx, 8192, CTX_);
  gemm_mfma<false><<<dim3(64, 4), 256, 0, stream>>>(ctx, wkb, kb, 8192, C_);
  gemm_mfma<false><<<dim3(64, 4), 256, 0, stream>>>(ctx, wvb, vb, 8192, C_);
  gemm_mfma<false><<<dim3(128, 4), 256, 0, stream>>>(hn, wqb, qb, 16384, C_);
  attn_mfma<<<dim3(N_ / 128, NH_, B_), 256, 0, stream>>>(qb, kb, vb, mask, hn);
  gemm_mfma<true><<<dim3(128, 4), 256, 0, stream>>>(hn, wob, Ob, 16384, C_);
  trans_res_kernel<<<dim3(N_ / 64, C_ / 64, B_), 256, 0, stream>>>(Ob, x, (float*)d_out);
}

// Round 7
// 202.730 us; speedup vs baseline: 5.2891x; 1.1226x over previous
//
#include <hip/hip_runtime.h>

// Problem constants
#define B_   16
#define C_   512
#define N_   1024   // H*W
#define L_   512
#define CTX_ 768
#define NH_  8
#define HD_  64
#define EPS_ 1e-5f

typedef short bfrag __attribute__((ext_vector_type(8)));   // 8 x bf16 bits
typedef float f32x4 __attribute__((ext_vector_type(4)));

__device__ __forceinline__ ushort f2bf(float f) {  // RNE f32->bf16 (finite inputs)
  union { float f; unsigned u; } v; v.f = f;
  unsigned r = v.u + 0x7fffu + ((v.u >> 16) & 1u);
  return (ushort)(r >> 16);
}

__device__ __forceinline__ f32x4 mfma16(bfrag a, bfrag b, f32x4 c) {
  return __builtin_amdgcn_mfma_f32_16x16x32_bf16(a, b, c, 0, 0, 0);
}

// ---------------------------------------------------------------------------
// cast fp32 -> bf16, 4 elems/thread
// ---------------------------------------------------------------------------
__global__ __launch_bounds__(256) void cast_kernel(const float* __restrict__ in,
                                                   ushort* __restrict__ out, int n4) {
  int i = blockIdx.x * 256 + threadIdx.x;
  if (i < n4) {
    float4 vv = ((const float4*)in)[i];
    ushort4 o;
    o.x = f2bf(vv.x); o.y = f2bf(vv.y); o.z = f2bf(vv.z); o.w = f2bf(vv.w);
    ((ushort4*)out)[i] = o;
  }
}

// ---------------------------------------------------------------------------
// fused weight casts: Wctx (98304 f4) + Wq/Wk/Wv/Wo (65536 f4 each) in ONE
// launch (round-6: 5 tiny launches ~2us overhead each).
// ---------------------------------------------------------------------------
__global__ __launch_bounds__(256) void cast5_kernel(
    const float* __restrict__ s0, const float* __restrict__ s1,
    const float* __restrict__ s2, const float* __restrict__ s3,
    const float* __restrict__ s4,
    ushort* __restrict__ d0, ushort* __restrict__ d1, ushort* __restrict__ d2,
    ushort* __restrict__ d3, ushort* __restrict__ d4) {
  int i = blockIdx.x * 256 + threadIdx.x;   // float4 index, total 360448
  const float* src; ushort* dst; int off;
  if      (i < 98304)  { src = s0; dst = d0; off = i; }
  else if (i < 163840) { src = s1; dst = d1; off = i - 98304; }
  else if (i < 229376) { src = s2; dst = d2; off = i - 163840; }
  else if (i < 294912) { src = s3; dst = d3; off = i - 229376; }
  else                 { src = s4; dst = d4; off = i - 294912; }
  float4 vv = ((const float4*)src)[off];
  ushort4 o;
  o.x = f2bf(vv.x); o.y = f2bf(vv.y); o.z = f2bf(vv.z); o.w = f2bf(vv.w);
  ((ushort4*)dst)[off] = o;
}

// ---------------------------------------------------------------------------
// LayerNorm over C with transpose (B,C,N) -> bf16 hn[(b*N+n)*C + c]
// 1024 threads (16 waves/block): 256-thread version was occupancy-bound.
// ---------------------------------------------------------------------------
__global__ __launch_bounds__(1024) void ln_kernel(const float* __restrict__ x,
                                                  const float* __restrict__ w,
                                                  const float* __restrict__ bia,
                                                  ushort* __restrict__ hn) {
  const int b  = blockIdx.x;
  const int n0 = blockIdx.y * 64;
  const int tid = threadIdx.x;
  const int nx = tid & 63, cg = tid >> 6;   // cg 0..15
  const float* xb = x + (size_t)b * C_ * N_;

  float s = 0.f, s2 = 0.f;
  for (int c = cg; c < C_; c += 16) {
    float v = xb[(size_t)c * N_ + n0 + nx];
    s += v; s2 += v * v;
  }
  __shared__ float red[2][16][64];
  __shared__ float mean[64], rstd[64];
  red[0][cg][nx] = s; red[1][cg][nx] = s2;
  __syncthreads();
  if (cg == 0) {
    float ss = 0.f, ss2 = 0.f;
#pragma unroll
    for (int i = 0; i < 16; ++i) { ss += red[0][i][nx]; ss2 += red[1][i][nx]; }
    float mu  = ss * (1.f / C_);
    float var = ss2 * (1.f / C_) - mu * mu;
    mean[nx] = mu;
    rstd[nx] = rsqrtf(var + EPS_);
  }
  __syncthreads();

  __shared__ float tile[64][65];
  for (int ct = 0; ct < 8; ++ct) {
    const int c0 = ct * 64;
    for (int cy = cg; cy < 64; cy += 16)
      tile[cy][nx] = xb[(size_t)(c0 + cy) * N_ + n0 + nx];
    __syncthreads();
    const int cx = tid & 63, ng = tid >> 6;
    const float wv = w[c0 + cx], bv = bia[c0 + cx];
    for (int ny = ng; ny < 64; ny += 16) {
      float val = (tile[cx][ny] - mean[ny]) * rstd[ny] * wv + bv;
      hn[((size_t)b * N_ + n0 + ny) * C_ + c0 + cx] = f2bf(val);
    }
    __syncthreads();
  }
}

// ---------------------------------------------------------------------------
// bf16 MFMA GEMM: out[m][e] = sum_k A[m][k]*W[e][k], E=512. 128x128x32 tile,
// 4 waves each 64x64 (4x4 frags of 16x16x32). LDS rows padded to 40 bf16.
// fp32 accum. Staging: 2 threads/row, 2x int4 each per matrix.
// ---------------------------------------------------------------------------
template <bool OUTF32>
__global__ __launch_bounds__(256) void gemm_mfma(const ushort* __restrict__ A,
                                                 const ushort* __restrict__ W,
                                                 void* __restrict__ outp,
                                                 int M, int K) {
  __shared__ ushort la[128 * 40];
  __shared__ ushort lb[128 * 40];
  const int m0 = blockIdx.x * 128, e0 = blockIdx.y * 128;
  const int tid = threadIdx.x, lane = tid & 63, w = tid >> 6;
  const int wm = (w >> 1) * 64, we = (w & 1) * 64;
  const int col = lane & 15, rg = lane >> 4;
  const int srow = tid >> 1, sh = (tid & 1) * 16;

  f32x4 acc[4][4] = {};

  for (int k0 = 0; k0 < K; k0 += 32) {
    {
      const ushort* ap = &A[(size_t)(m0 + srow) * K + k0 + sh];
      const ushort* wp = &W[(size_t)(e0 + srow) * K + k0 + sh];
      *(int4*)&la[srow * 40 + sh]     = *(const int4*)ap;
      *(int4*)&la[srow * 40 + sh + 8] = *(const int4*)(ap + 8);
      *(int4*)&lb[srow * 40 + sh]     = *(const int4*)wp;
      *(int4*)&lb[srow * 40 + sh + 8] = *(const int4*)(wp + 8);
    }
    __syncthreads();
    bfrag af[4], bf[4];
#pragma unroll
    for (int i = 0; i < 4; ++i) {
      af[i] = *(const bfrag*)&la[(wm + i * 16 + col) * 40 + rg * 8];
      bf[i] = *(const bfrag*)&lb[(we + i * 16 + col) * 40 + rg * 8];
    }
#pragma unroll
    for (int i = 0; i < 4; ++i)
#pragma unroll
      for (int j = 0; j < 4; ++j)
        acc[i][j] = mfma16(af[i], bf[j], acc[i][j]);
    __syncthreads();
  }

  // C/D layout (verified m89/m91): col=lane&15, row=(lane>>4)*4+reg
#pragma unroll
  for (int i = 0; i < 4; ++i)
#pragma unroll
    for (int j = 0; j < 4; ++j)
#pragma unroll
      for (int r = 0; r < 4; ++r) {
        const size_t off =
            (size_t)(m0 + wm + i * 16 + rg * 4 + r) * 512 + e0 + we + j * 16 + col;
        if (OUTF32) ((float*)outp)[off] = acc[i][j][r];
        else        ((ushort*)outp)[off] = f2bf(acc[i][j][r]);
      }
}

// ---------------------------------------------------------------------------
// MFMA flash cross-attention, bf16 operands / fp32 softmax+accum.
// Round-7 restructure: NO online softmax. Scores bounded (|s|<~30 even
// adversarially; exp safe in f32; masked keys -> exp(-1e30)=0), so use fixed
// max=0: p=exp(s), per-lane partial row sums, ONE shfl reduce at the end.
// Removes per-tile max-reduce/corr/oa-rescale (~300 VALU/thr/iter; round-6
// counters: VALUBusy 40% vs MfmaUtil 8.7%).
// Pw stride 76 (38 dwords): P-write rg-groups land on disjoint bank octets
// (stride 72 was ~8-way conflicted; 2.6M conflict cycles).
// ---------------------------------------------------------------------------
__global__ __launch_bounds__(256) void attn_mfma(const ushort* __restrict__ q,
                                                 const ushort* __restrict__ k,
                                                 const ushort* __restrict__ v,
                                                 const int* __restrict__ mask,
                                                 ushort* __restrict__ o) {
  __shared__ ushort Kl[64 * 72];      // [key][72]
  __shared__ ushort Vt[64 * 72];      // [d][72]
  __shared__ ushort Pw[4][32 * 76];   // per-wave P [qrow][76]
  __shared__ float mlb[64];

  const int h = blockIdx.y, b = blockIdx.z;
  const int q0 = blockIdx.x * 128;
  const int tid = threadIdx.x, lane = tid & 63, w = tid >> 6;
  const int col = lane & 15, rg = lane >> 4;
  const int wq = w * 32;

  bfrag qf[2][2];
#pragma unroll
  for (int mi = 0; mi < 2; ++mi)
#pragma unroll
    for (int kc = 0; kc < 2; ++kc)
      qf[mi][kc] = *(const bfrag*)
          &q[((size_t)b * N_ + q0 + wq + mi * 16 + col) * C_ + h * HD_ + kc * 32 + rg * 8];

  f32x4 oa[2][4] = {};
  float l_part[2][4] = {};   // per-lane partial softmax denominators

  for (int l0 = 0; l0 < L_; l0 += 64) {
#pragma unroll
    for (int it = 0; it < 2; ++it) {     // K: 64 keys x 128B
      const int idx = it * 256 + tid;
      const int key = idx >> 3, part = idx & 7;
      *(int4*)&Kl[key * 72 + part * 8] =
          *(const int4*)&k[((size_t)b * L_ + l0 + key) * C_ + h * HD_ + part * 8];
    }
#pragma unroll
    for (int it = 0; it < 4; ++it) {     // V transposed: Vt[d][key]
      const int idx = it * 256 + tid;
      const int key = idx & 63, d0 = (idx >> 6) * 4;
      ushort4 vv = *(const ushort4*)&v[((size_t)b * L_ + l0 + key) * C_ + h * HD_ + d0];
      Vt[(d0 + 0) * 72 + key] = vv.x;
      Vt[(d0 + 1) * 72 + key] = vv.y;
      Vt[(d0 + 2) * 72 + key] = vv.z;
      Vt[(d0 + 3) * 72 + key] = vv.w;
    }
    if (tid < 64) mlb[tid] = mask[b * L_ + l0 + tid] ? 0.f : -1e30f;
    __syncthreads();

    // S = Q K^T  (B-frag: col=key, k=d)
    f32x4 s[2][4] = {};
#pragma unroll
    for (int kc = 0; kc < 2; ++kc) {
      bfrag kf[4];
#pragma unroll
      for (int ni = 0; ni < 4; ++ni)
        kf[ni] = *(const bfrag*)&Kl[(ni * 16 + col) * 72 + kc * 32 + rg * 8];
#pragma unroll
      for (int mi = 0; mi < 2; ++mi)
#pragma unroll
        for (int ni = 0; ni < 4; ++ni)
          s[mi][ni] = mfma16(qf[mi][kc], kf[ni], s[mi][ni]);
    }
    // p = exp(s*scale + maskbias); accumulate per-lane row sums
#pragma unroll
    for (int ni = 0; ni < 4; ++ni) {
      const float bias = mlb[ni * 16 + col];
#pragma unroll
      for (int mi = 0; mi < 2; ++mi)
#pragma unroll
        for (int r = 0; r < 4; ++r) {
          const float p = __expf(s[mi][ni][r] * 0.125f + bias);
          s[mi][ni][r] = p;
          l_part[mi][r] += p;
        }
    }
    // P (C-layout) -> per-wave LDS as bf16
#pragma unroll
    for (int mi = 0; mi < 2; ++mi)
#pragma unroll
      for (int ni = 0; ni < 4; ++ni)
#pragma unroll
        for (int r = 0; r < 4; ++r)
          Pw[w][(mi * 16 + rg * 4 + r) * 76 + ni * 16 + col] = f2bf(s[mi][ni][r]);
    // PV: A-frag from Pw (row=q, k=key), B-frag from Vt (col=d, k=key)
#pragma unroll
    for (int kc = 0; kc < 2; ++kc) {
      bfrag pf[2], vf[4];
#pragma unroll
      for (int mi = 0; mi < 2; ++mi)
        pf[mi] = *(const bfrag*)&Pw[w][(mi * 16 + col) * 76 + kc * 32 + rg * 8];
#pragma unroll
      for (int di = 0; di < 4; ++di)
        vf[di] = *(const bfrag*)&Vt[(di * 16 + col) * 72 + kc * 32 + rg * 8];
#pragma unroll
      for (int mi = 0; mi < 2; ++mi)
#pragma unroll
        for (int di = 0; di < 4; ++di)
          oa[mi][di] = mfma16(pf[mi], vf[di], oa[mi][di]);
    }
    __syncthreads();
  }

  // final denominator reduce across the 16 lanes sharing rg, then write
#pragma unroll
  for (int mi = 0; mi < 2; ++mi) {
#pragma unroll
    for (int r = 0; r < 4; ++r) {
      float l = l_part[mi][r];
      l += __shfl_xor(l, 1);
      l += __shfl_xor(l, 2);
      l += __shfl_xor(l, 4);
      l += __shfl_xor(l, 8);
      const float inv = 1.f / l;
      const size_t row = (size_t)b * N_ + q0 + wq + mi * 16 + rg * 4 + r;
#pragma unroll
      for (int di = 0; di < 4; ++di)
        o[row * C_ + h * HD_ + di * 16 + col] = f2bf(oa[mi][di][r] * inv);
    }
  }
}

// ---------------------------------------------------------------------------
// transpose + residual: out[b][c][n] = O[(b*N+n)*C + c] + x[b][c][n]
// ---------------------------------------------------------------------------
__global__ __launch_bounds__(256) void trans_res_kernel(const float* __restrict__ O,
                                                        const float* __restrict__ x,
                                                        float* __restrict__ out) {
  const int n0 = blockIdx.x * 64, c0 = blockIdx.y * 64, b = blockIdx.z;
  __shared__ float t[64][65];
  const int tid = threadIdx.x;
  const int cx = tid & 63, g = tid >> 6;
  for (int ny = g; ny < 64; ny += 4)
    t[ny][cx] = O[((size_t)b * N_ + n0 + ny) * C_ + c0 + cx];
  __syncthreads();
  const int nx = tid & 63;
  for (int cy = g; cy < 64; cy += 4) {
    const size_t idx = (size_t)b * C_ * N_ + (size_t)(c0 + cy) * N_ + n0 + nx;
    out[idx] = t[nx][cy] + x[idx];
  }
}

// ---------------------------------------------------------------------------
// Launch
// ---------------------------------------------------------------------------
extern "C" void kernel_launch(void* const* d_in, const int* in_sizes, int n_in,
                              void* d_out, int out_size, void* d_ws, size_t ws_size,
                              hipStream_t stream) {
  (void)in_sizes; (void)n_in; (void)out_size; (void)ws_size;
  const float* x       = (const float*)d_in[0];
  const float* context = (const float*)d_in[1];
  const int*   mask    = (const int*)d_in[2];
  const float* ln_w    = (const float*)d_in[3];
  const float* ln_b    = (const float*)d_in[4];
  const float* Wq      = (const float*)d_in[5];
  const float* Wk      = (const float*)d_in[6];
  const float* Wv      = (const float*)d_in[7];
  const float* Wo      = (const float*)d_in[8];
  const float* Wctx    = (const float*)d_in[9];

  char* wsb = (char*)d_ws;
  // byte offsets; total ~74 MB
  ushort* qb    = (ushort*)(wsb + 0);          // 16384x512 bf16
  ushort* kb    = (ushort*)(wsb + 16777216);   //  8192x512
  ushort* vb    = (ushort*)(wsb + 25165824);   //  8192x512
  ushort* hn    = (ushort*)(wsb + 33554432);   // 16384x512 (later atto)
  ushort* ctx   = (ushort*)(wsb + 50331648);   //  8192x512
  ushort* ctxb  = (ushort*)(wsb + 58720256);   //  8192x768
  ushort* wctxb = (ushort*)(wsb + 71303168);   //   512x768
  ushort* wqb   = (ushort*)(wsb + 72089600);
  ushort* wkb   = (ushort*)(wsb + 72613888);
  ushort* wvb   = (ushort*)(wsb + 73138176);
  ushort* wob   = (ushort*)(wsb + 73662464);
  float*  Ob    = (float*)(wsb + 0);           // aliases qb..vb (dead after attn)

  cast_kernel<<<6144, 256, 0, stream>>>(context, ctxb, 1572864);
  cast5_kernel<<<1408, 256, 0, stream>>>(Wctx, Wq, Wk, Wv, Wo,
                                         wctxb, wqb, wkb, wvb, wob);
  ln_kernel<<<dim3(B_, N_ / 64), 1024, 0, stream>>>(x, ln_w, ln_b, hn);
  gemm_mfma<false><<<dim3(64, 4), 256, 0, stream>>>(ctxb, wctxb, ctx, 8192, CTX_);
  gemm_mfma<false><<<dim3(64, 4), 256, 0, stream>>>(ctx, wkb, kb, 8192, C_);
  gemm_mfma<false><<<dim3(64, 4), 256, 0, stream>>>(ctx, wvb, vb, 8192, C_);
  gemm_mfma<false><<<dim3(128, 4), 256, 0, stream>>>(hn, wqb, qb, 16384, C_);
  attn_mfma<<<dim3(N_ / 128, NH_, B_), 256, 0, stream>>>(qb, kb, vb, mask, hn);
  gemm_mfma<true><<<dim3(128, 4), 256, 0, stream>>>(hn, wob, Ob, 16384, C_);
  trans_res_kernel<<<dim3(N_ / 64, C_ / 64, B_), 256, 0, stream>>>(Ob, x, (float*)d_out);
}

// Round 9
// 187.291 us; speedup vs baseline: 5.7251x; 1.0824x over previous
//
#include <hip/hip_runtime.h>
#include <hip/hip_bf16.h>

// Problem constants
#define B_   16
#define C_   512
#define N_   1024   // H*W
#define L_   512
#define CTX_ 768
#define NH_  8
#define HD_  64
#define EPS_ 1e-5f

typedef short bfrag __attribute__((ext_vector_type(8)));   // 8 x bf16 bits
typedef float f32x4 __attribute__((ext_vector_type(4)));

// native f32->bf16 (RNE); round-7 profile: manual bit-twiddle was ~5 VALU ops
// per element, 32/iter/thread in the attn hot loop.
__device__ __forceinline__ ushort f2bf(float f) {
  union { __hip_bfloat16 h; ushort u; } cv;
  cv.h = __float2bfloat16(f);
  return cv.u;
}

__device__ __forceinline__ f32x4 mfma16(bfrag a, bfrag b, f32x4 c) {
  return __builtin_amdgcn_mfma_f32_16x16x32_bf16(a, b, c, 0, 0, 0);
}

// ---------------------------------------------------------------------------
// fused weight casts: Wctx (98304 f4) + Wq/Wk/Wv/Wo (65536 f4 each), ONE launch
// ---------------------------------------------------------------------------
__global__ __launch_bounds__(256) void cast5_kernel(
    const float* __restrict__ s0, const float* __restrict__ s1,
    const float* __restrict__ s2, const float* __restrict__ s3,
    const float* __restrict__ s4,
    ushort* __restrict__ d0, ushort* __restrict__ d1, ushort* __restrict__ d2,
    ushort* __restrict__ d3, ushort* __restrict__ d4) {
  int i = blockIdx.x * 256 + threadIdx.x;   // float4 index, total 360448
  const float* src; ushort* dst; int off;
  if      (i < 98304)  { src = s0; dst = d0; off = i; }
  else if (i < 163840) { src = s1; dst = d1; off = i - 98304; }
  else if (i < 229376) { src = s2; dst = d2; off = i - 163840; }
  else if (i < 294912) { src = s3; dst = d3; off = i - 229376; }
  else                 { src = s4; dst = d4; off = i - 294912; }
  float4 vv = ((const float4*)src)[off];
  ushort4 o;
  o.x = f2bf(vv.x); o.y = f2bf(vv.y); o.z = f2bf(vv.z); o.w = f2bf(vv.w);
  ((ushort4*)dst)[off] = o;
}

// ---------------------------------------------------------------------------
// LayerNorm over C with transpose (B,C,N) -> bf16 hn[(b*N+n)*C + c]
// 1024 threads (16 waves/block).
// ---------------------------------------------------------------------------
__global__ __launch_bounds__(1024) void ln_kernel(const float* __restrict__ x,
                                                  const float* __restrict__ w,
                                                  const float* __restrict__ bia,
                                                  ushort* __restrict__ hn) {
  const int b  = blockIdx.x;
  const int n0 = blockIdx.y * 64;
  const int tid = threadIdx.x;
  const int nx = tid & 63, cg = tid >> 6;   // cg 0..15
  const float* xb = x + (size_t)b * C_ * N_;

  float s = 0.f, s2 = 0.f;
  for (int c = cg; c < C_; c += 16) {
    float v = xb[(size_t)c * N_ + n0 + nx];
    s += v; s2 += v * v;
  }
  __shared__ float red[2][16][64];
  __shared__ float mean[64], rstd[64];
  red[0][cg][nx] = s; red[1][cg][nx] = s2;
  __syncthreads();
  if (cg == 0) {
    float ss = 0.f, ss2 = 0.f;
#pragma unroll
    for (int i = 0; i < 16; ++i) { ss += red[0][i][nx]; ss2 += red[1][i][nx]; }
    float mu  = ss * (1.f / C_);
    float var = ss2 * (1.f / C_) - mu * mu;
    mean[nx] = mu;
    rstd[nx] = rsqrtf(var + EPS_);
  }
  __syncthreads();

  __shared__ float tile[64][65];
  for (int ct = 0; ct < 8; ++ct) {
    const int c0 = ct * 64;
    for (int cy = cg; cy < 64; cy += 16)
      tile[cy][nx] = xb[(size_t)(c0 + cy) * N_ + n0 + nx];
    __syncthreads();
    const int cx = tid & 63, ng = tid >> 6;
    const float wv = w[c0 + cx], bv = bia[c0 + cx];
    for (int ny = ng; ny < 64; ny += 16) {
      float val = (tile[cx][ny] - mean[ny]) * rstd[ny] * wv + bv;
      hn[((size_t)b * N_ + n0 + ny) * C_ + c0 + cx] = f2bf(val);
    }
    __syncthreads();
  }
}

// ---------------------------------------------------------------------------
// bf16 MFMA GEMM: out[m][e] = sum_k A[m][k]*W[e][k], E=512. 128x128x32 tile,
// 4 waves each 64x64 (4x4 frags). LDS rows padded to 40 bf16. fp32 accum.
// AF32: A is fp32, converted in-reg during staging (kills the context cast
// dispatch + 72MB traffic).
// ---------------------------------------------------------------------------
template <bool AF32, bool OUTF32>
__global__ __launch_bounds__(256) void gemm_mfma(const void* __restrict__ Ap,
                                                 const ushort* __restrict__ W,
                                                 void* __restrict__ outp,
                                                 int M, int K) {
  __shared__ ushort la[128 * 40];
  __shared__ ushort lb[128 * 40];
  const int m0 = blockIdx.x * 128, e0 = blockIdx.y * 128;
  const int tid = threadIdx.x, lane = tid & 63, w = tid >> 6;
  const int wm = (w >> 1) * 64, we = (w & 1) * 64;
  const int col = lane & 15, rg = lane >> 4;
  const int srow = tid >> 1, sh = (tid & 1) * 16;

  f32x4 acc[4][4] = {};

  for (int k0 = 0; k0 < K; k0 += 32) {
    if constexpr (AF32) {
      const float* ap = &((const float*)Ap)[(size_t)(m0 + srow) * K + k0 + sh];
      float4 f0 = ((const float4*)ap)[0];
      float4 f1 = ((const float4*)ap)[1];
      float4 f2 = ((const float4*)ap)[2];
      float4 f3 = ((const float4*)ap)[3];
      union { int4 v; ushort u[8]; } p0, p1;
      p0.u[0] = f2bf(f0.x); p0.u[1] = f2bf(f0.y); p0.u[2] = f2bf(f0.z); p0.u[3] = f2bf(f0.w);
      p0.u[4] = f2bf(f1.x); p0.u[5] = f2bf(f1.y); p0.u[6] = f2bf(f1.z); p0.u[7] = f2bf(f1.w);
      p1.u[0] = f2bf(f2.x); p1.u[1] = f2bf(f2.y); p1.u[2] = f2bf(f2.z); p1.u[3] = f2bf(f2.w);
      p1.u[4] = f2bf(f3.x); p1.u[5] = f2bf(f3.y); p1.u[6] = f2bf(f3.z); p1.u[7] = f2bf(f3.w);
      *(int4*)&la[srow * 40 + sh]     = p0.v;
      *(int4*)&la[srow * 40 + sh + 8] = p1.v;
    } else {
      const ushort* ap = &((const ushort*)Ap)[(size_t)(m0 + srow) * K + k0 + sh];
      *(int4*)&la[srow * 40 + sh]     = *(const int4*)ap;
      *(int4*)&la[srow * 40 + sh + 8] = *(const int4*)(ap + 8);
    }
    {
      const ushort* wp = &W[(size_t)(e0 + srow) * K + k0 + sh];
      *(int4*)&lb[srow * 40 + sh]     = *(const int4*)wp;
      *(int4*)&lb[srow * 40 + sh + 8] = *(const int4*)(wp + 8);
    }
    __syncthreads();
    bfrag af[4], bf[4];
#pragma unroll
    for (int i = 0; i < 4; ++i) {
      af[i] = *(const bfrag*)&la[(wm + i * 16 + col) * 40 + rg * 8];
      bf[i] = *(const bfrag*)&lb[(we + i * 16 + col) * 40 + rg * 8];
    }
#pragma unroll
    for (int i = 0; i < 4; ++i)
#pragma unroll
      for (int j = 0; j < 4; ++j)
        acc[i][j] = mfma16(af[i], bf[j], acc[i][j]);
    __syncthreads();
  }

  // C/D layout (verified m89/m91): col=lane&15, row=(lane>>4)*4+reg
#pragma unroll
  for (int i = 0; i < 4; ++i)
#pragma unroll
    for (int j = 0; j < 4; ++j)
#pragma unroll
      for (int r = 0; r < 4; ++r) {
        const size_t off =
            (size_t)(m0 + wm + i * 16 + rg * 4 + r) * 512 + e0 + we + j * 16 + col;
        if (OUTF32) ((float*)outp)[off] = acc[i][j][r];
        else        ((ushort*)outp)[off] = f2bf(acc[i][j][r]);
      }
}

// ---------------------------------------------------------------------------
// fused K+V projection: A=ctx (8192x512); blockIdx.y<4 -> K-proj, else V-proj.
// Grid 512 blocks = 2/CU (round-7: separate 256-block launches = 1/CU each).
// ---------------------------------------------------------------------------
__global__ __launch_bounds__(256) void gemm_kv(const ushort* __restrict__ A,
                                               const ushort* __restrict__ Wk,
                                               const ushort* __restrict__ Wv,
                                               ushort* __restrict__ Ko,
                                               ushort* __restrict__ Vo) {
  __shared__ ushort la[128 * 40];
  __shared__ ushort lb[128 * 40];
  const int isv = blockIdx.y >> 2;
  const ushort* W = isv ? Wv : Wk;
  ushort* out = isv ? Vo : Ko;
  const int m0 = blockIdx.x * 128, e0 = (blockIdx.y & 3) * 128;
  const int tid = threadIdx.x, lane = tid & 63, w = tid >> 6;
  const int wm = (w >> 1) * 64, we = (w & 1) * 64;
  const int col = lane & 15, rg = lane >> 4;
  const int srow = tid >> 1, sh = (tid & 1) * 16;

  f32x4 acc[4][4] = {};

  for (int k0 = 0; k0 < C_; k0 += 32) {
    const ushort* ap = &A[(size_t)(m0 + srow) * C_ + k0 + sh];
    const ushort* wp = &W[(size_t)(e0 + srow) * C_ + k0 + sh];
    *(int4*)&la[srow * 40 + sh]     = *(const int4*)ap;
    *(int4*)&la[srow * 40 + sh + 8] = *(const int4*)(ap + 8);
    *(int4*)&lb[srow * 40 + sh]     = *(const int4*)wp;
    *(int4*)&lb[srow * 40 + sh + 8] = *(const int4*)(wp + 8);
    __syncthreads();
    bfrag af[4], bf[4];
#pragma unroll
    for (int i = 0; i < 4; ++i) {
      af[i] = *(const bfrag*)&la[(wm + i * 16 + col) * 40 + rg * 8];
      bf[i] = *(const bfrag*)&lb[(we + i * 16 + col) * 40 + rg * 8];
    }
#pragma unroll
    for (int i = 0; i < 4; ++i)
#pragma unroll
      for (int j = 0; j < 4; ++j)
        acc[i][j] = mfma16(af[i], bf[j], acc[i][j]);
    __syncthreads();
  }

#pragma unroll
  for (int i = 0; i < 4; ++i)
#pragma unroll
    for (int j = 0; j < 4; ++j)
#pragma unroll
      for (int r = 0; r < 4; ++r)
        out[(size_t)(m0 + wm + i * 16 + rg * 4 + r) * 512 + e0 + we + j * 16 + col] =
            f2bf(acc[i][j][r]);
}

// ---------------------------------------------------------------------------
// o-projection + transposed residual epilogue: out[b][c][n] = (atto@Wo^T) + x.
// Kills the trans_res dispatch and the 128MB Ob fp32 round-trip. Per 16-col
// group: owning waves dump acc quadrants into LDS T (b128, rows contiguous),
// all threads read transposed and write coalesced 512B runs along n.
// ---------------------------------------------------------------------------
__global__ __launch_bounds__(256) void gemm_res(const ushort* __restrict__ A,
                                                const ushort* __restrict__ W,
                                                const float* __restrict__ x,
                                                float* __restrict__ out) {
  __shared__ ushort la[128 * 40];
  __shared__ ushort lb[128 * 40];
  __shared__ float T[16][132];
  const int m0 = blockIdx.x * 128, e0 = blockIdx.y * 128;
  const int tid = threadIdx.x, lane = tid & 63, w = tid >> 6;
  const int wm = (w >> 1) * 64, we = (w & 1) * 64;
  const int col = lane & 15, rg = lane >> 4;
  const int srow = tid >> 1, sh = (tid & 1) * 16;

  f32x4 acc[4][4] = {};

  for (int k0 = 0; k0 < C_; k0 += 32) {
    const ushort* ap = &A[(size_t)(m0 + srow) * C_ + k0 + sh];
    const ushort* wp = &W[(size_t)(e0 + srow) * C_ + k0 + sh];
    *(int4*)&la[srow * 40 + sh]     = *(const int4*)ap;
    *(int4*)&la[srow * 40 + sh + 8] = *(const int4*)(ap + 8);
    *(int4*)&lb[srow * 40 + sh]     = *(const int4*)wp;
    *(int4*)&lb[srow * 40 + sh + 8] = *(const int4*)(wp + 8);
    __syncthreads();
    bfrag af[4], bf[4];
#pragma unroll
    for (int i = 0; i < 4; ++i) {
      af[i] = *(const bfrag*)&la[(wm + i * 16 + col) * 40 + rg * 8];
      bf[i] = *(const bfrag*)&lb[(we + i * 16 + col) * 40 + rg * 8];
    }
#pragma unroll
    for (int i = 0; i < 4; ++i)
#pragma unroll
      for (int j = 0; j < 4; ++j)
        acc[i][j] = mfma16(af[i], bf[j], acc[i][j]);
    __syncthreads();
  }

  const int b = m0 >> 10, n0l = m0 & 1023;
#pragma unroll
  for (int g = 0; g < 8; ++g) {
    if ((w & 1) == (g >> 2)) {          // wave-uniform: we-half owns this group
      const int j = g & 3;
#pragma unroll
      for (int i = 0; i < 4; ++i)
        *(f32x4*)&T[col][wm + i * 16 + rg * 4] = acc[i][j];
    }
    __syncthreads();
    const int n = tid & 127;
    for (int cc = tid >> 7; cc < 16; cc += 2) {
      const int c = e0 + g * 16 + cc;
      const size_t idx = (size_t)b * C_ * N_ + (size_t)c * N_ + n0l + n;
      out[idx] = T[cc][n] + x[idx];
    }
    __syncthreads();
  }
}

// ---------------------------------------------------------------------------
// MFMA flash cross-attention, bf16 operands / fp32 softmax+accum.
// Fixed-max softmax (scores bounded, masked -> exp2(-1e30)=0). Round-8:
// exp2f with scale+log2e+bias folded into ONE fma; native f2bf.
// ---------------------------------------------------------------------------
__global__ __launch_bounds__(256) void attn_mfma(const ushort* __restrict__ q,
                                                 const ushort* __restrict__ k,
                                                 const ushort* __restrict__ v,
                                                 const int* __restrict__ mask,
                                                 ushort* __restrict__ o) {
  __shared__ ushort Kl[64 * 72];      // [key][72]
  __shared__ ushort Vt[64 * 72];      // [d][72]
  __shared__ ushort Pw[4][32 * 76];   // per-wave P [qrow][76]
  __shared__ float mlb[64];

  const int h = blockIdx.y, b = blockIdx.z;
  const int q0 = blockIdx.x * 128;
  const int tid = threadIdx.x, lane = tid & 63, w = tid >> 6;
  const int col = lane & 15, rg = lane >> 4;
  const int wq = w * 32;
  const float C1 = 0.18033688011112042f;  // 0.125 * log2(e)

  bfrag qf[2][2];
#pragma unroll
  for (int mi = 0; mi < 2; ++mi)
#pragma unroll
    for (int kc = 0; kc < 2; ++kc)
      qf[mi][kc] = *(const bfrag*)
          &q[((size_t)b * N_ + q0 + wq + mi * 16 + col) * C_ + h * HD_ + kc * 32 + rg * 8];

  f32x4 oa[2][4] = {};
  float l_part[2][4] = {};   // per-lane partial softmax denominators

  for (int l0 = 0; l0 < L_; l0 += 64) {
#pragma unroll
    for (int it = 0; it < 2; ++it) {     // K: 64 keys x 128B
      const int idx = it * 256 + tid;
      const int key = idx >> 3, part = idx & 7;
      *(int4*)&Kl[key * 72 + part * 8] =
          *(const int4*)&k[((size_t)b * L_ + l0 + key) * C_ + h * HD_ + part * 8];
    }
#pragma unroll
    for (int it = 0; it < 4; ++it) {     // V transposed: Vt[d][key]
      const int idx = it * 256 + tid;
      const int key = idx & 63, d0 = (idx >> 6) * 4;
      ushort4 vv = *(const ushort4*)&v[((size_t)b * L_ + l0 + key) * C_ + h * HD_ + d0];
      Vt[(d0 + 0) * 72 + key] = vv.x;
      Vt[(d0 + 1) * 72 + key] = vv.y;
      Vt[(d0 + 2) * 72 + key] = vv.z;
      Vt[(d0 + 3) * 72 + key] = vv.w;
    }
    if (tid < 64) mlb[tid] = mask[b * L_ + l0 + tid] ? 0.f : -1e30f;
    __syncthreads();

    // S = Q K^T  (B-frag: col=key, k=d)
    f32x4 s[2][4] = {};
#pragma unroll
    for (int kc = 0; kc < 2; ++kc) {
      bfrag kf[4];
#pragma unroll
      for (int ni = 0; ni < 4; ++ni)
        kf[ni] = *(const bfrag*)&Kl[(ni * 16 + col) * 72 + kc * 32 + rg * 8];
#pragma unroll
      for (int mi = 0; mi < 2; ++mi)
#pragma unroll
        for (int ni = 0; ni < 4; ++ni)
          s[mi][ni] = mfma16(qf[mi][kc], kf[ni], s[mi][ni]);
    }
    // p = exp2(s*C1 + bias); accumulate per-lane row sums
#pragma unroll
    for (int ni = 0; ni < 4; ++ni) {
      const float bias = mlb[ni * 16 + col];
#pragma unroll
      for (int mi = 0; mi < 2; ++mi)
#pragma unroll
        for (int r = 0; r < 4; ++r) {
          const float p = exp2f(fmaf(s[mi][ni][r], C1, bias));
          s[mi][ni][r] = p;
          l_part[mi][r] += p;
        }
    }
    // P (C-layout) -> per-wave LDS as bf16
#pragma unroll
    for (int mi = 0; mi < 2; ++mi)
#pragma unroll
      for (int ni = 0; ni < 4; ++ni)
#pragma unroll
        for (int r = 0; r < 4; ++r)
          Pw[w][(mi * 16 + rg * 4 + r) * 76 + ni * 16 + col] = f2bf(s[mi][ni][r]);
    // PV: A-frag from Pw (row=q, k=key), B-frag from Vt (col=d, k=key)
#pragma unroll
    for (int kc = 0; kc < 2; ++kc) {
      bfrag pf[2], vf[4];
#pragma unroll
      for (int mi = 0; mi < 2; ++mi)
        pf[mi] = *(const bfrag*)&Pw[w][(mi * 16 + col) * 76 + kc * 32 + rg * 8];
#pragma unroll
      for (int di = 0; di < 4; ++di)
        vf[di] = *(const bfrag*)&Vt[(di * 16 + col) * 72 + kc * 32 + rg * 8];
#pragma unroll
      for (int mi = 0; mi < 2; ++mi)
#pragma unroll
        for (int di = 0; di < 4; ++di)
          oa[mi][di] = mfma16(pf[mi], vf[di], oa[mi][di]);
    }
    __syncthreads();
  }

  // final denominator reduce across the 16 lanes sharing rg, then write
#pragma unroll
  for (int mi = 0; mi < 2; ++mi) {
#pragma unroll
    for (int r = 0; r < 4; ++r) {
      float l = l_part[mi][r];
      l += __shfl_xor(l, 1);
      l += __shfl_xor(l, 2);
      l += __shfl_xor(l, 4);
      l += __shfl_xor(l, 8);
      const float inv = 1.f / l;
      const size_t row = (size_t)b * N_ + q0 + wq + mi * 16 + rg * 4 + r;
#pragma unroll
      for (int di = 0; di < 4; ++di)
        o[row * C_ + h * HD_ + di * 16 + col] = f2bf(oa[mi][di][r] * inv);
    }
  }
}

// ---------------------------------------------------------------------------
// Launch
// ---------------------------------------------------------------------------
extern "C" void kernel_launch(void* const* d_in, const int* in_sizes, int n_in,
                              void* d_out, int out_size, void* d_ws, size_t ws_size,
                              hipStream_t stream) {
  (void)in_sizes; (void)n_in; (void)out_size; (void)ws_size;
  const float* x       = (const float*)d_in[0];
  const float* context = (const float*)d_in[1];
  const int*   mask    = (const int*)d_in[2];
  const float* ln_w    = (const float*)d_in[3];
  const float* ln_b    = (const float*)d_in[4];
  const float* Wq      = (const float*)d_in[5];
  const float* Wk      = (const float*)d_in[6];
  const float* Wv      = (const float*)d_in[7];
  const float* Wo      = (const float*)d_in[8];
  const float* Wctx    = (const float*)d_in[9];

  char* wsb = (char*)d_ws;
  ushort* qb    = (ushort*)(wsb + 0);          // 16384x512 bf16
  ushort* kb    = (ushort*)(wsb + 16777216);   //  8192x512
  ushort* vb    = (ushort*)(wsb + 25165824);   //  8192x512
  ushort* hn    = (ushort*)(wsb + 33554432);   // 16384x512 (later atto)
  ushort* ctx   = (ushort*)(wsb + 50331648);   //  8192x512
  ushort* wctxb = (ushort*)(wsb + 58720256);   //   512x768
  ushort* wqb   = (ushort*)(wsb + 59506688);   //   512x512 each
  ushort* wkb   = (ushort*)(wsb + 60030976);
  ushort* wvb   = (ushort*)(wsb + 60555264);
  ushort* wob   = (ushort*)(wsb + 61079552);

  cast5_kernel<<<1408, 256, 0, stream>>>(Wctx, Wq, Wk, Wv, Wo,
                                         wctxb, wqb, wkb, wvb, wob);
  ln_kernel<<<dim3(B_, N_ / 64), 1024, 0, stream>>>(x, ln_w, ln_b, hn);
  // ctx = context @ Wctx^T, fp32 A converted in staging
  gemm_mfma<true, false><<<dim3(64, 4), 256, 0, stream>>>(context, wctxb, ctx, 8192, CTX_);
  // k,v fused (512 blocks = 2/CU)
  gemm_kv<<<dim3(64, 8), 256, 0, stream>>>(ctx, wkb, wvb, kb, vb);
  // q = hn @ Wq^T
  gemm_mfma<false, false><<<dim3(128, 4), 256, 0, stream>>>(hn, wqb, qb, 16384, C_);
  attn_mfma<<<dim3(N_ / 128, NH_, B_), 256, 0, stream>>>(qb, kb, vb, mask, hn);
  // out = transpose(atto @ Wo^T) + x, fused epilogue
  gemm_res<<<dim3(128, 4), 256, 0, stream>>>(hn, wob, x, (float*)d_out);
}

// Round 10
// 180.780 us; speedup vs baseline: 5.9313x; 1.0360x over previous
//
#include <hip/hip_runtime.h>

// Problem constants
#define B_   16
#define C_   512
#define N_   1024   // H*W
#define L_   512
#define CTX_ 768
#define NH_  8
#define HD_  64
#define EPS_ 1e-5f

typedef short bfrag __attribute__((ext_vector_type(8)));   // 8 x bf16 bits
typedef float f32x4 __attribute__((ext_vector_type(4)));

// manual RNE f32->bf16 (finite inputs). Round-9 post-mortem: native
// __float2bfloat16 REGRESSED attn 57.6->61.9us (NaN-safe path, more VALU).
__device__ __forceinline__ ushort f2bf(float f) {
  union { float f; unsigned u; } v; v.f = f;
  unsigned r = v.u + 0x7fffu + ((v.u >> 16) & 1u);
  return (ushort)(r >> 16);
}

__device__ __forceinline__ f32x4 mfma16(bfrag a, bfrag b, f32x4 c) {
  return __builtin_amdgcn_mfma_f32_16x16x32_bf16(a, b, c, 0, 0, 0);
}

// async global->LDS, 16B/lane (m97 lever). dst must be wave-uniform.
__device__ __forceinline__ void g2l16(const ushort* g, ushort* l) {
  __builtin_amdgcn_global_load_lds(
      (const __attribute__((address_space(1))) void*)g,
      (__attribute__((address_space(3))) void*)l, 16, 0, 0);
}

// ---------------------------------------------------------------------------
// fused weight casts: Wctx (98304 f4) + Wq/Wk/Wv/Wo (65536 f4 each), ONE launch
// ---------------------------------------------------------------------------
__global__ __launch_bounds__(256) void cast5_kernel(
    const float* __restrict__ s0, const float* __restrict__ s1,
    const float* __restrict__ s2, const float* __restrict__ s3,
    const float* __restrict__ s4,
    ushort* __restrict__ d0, ushort* __restrict__ d1, ushort* __restrict__ d2,
    ushort* __restrict__ d3, ushort* __restrict__ d4) {
  int i = blockIdx.x * 256 + threadIdx.x;   // float4 index, total 360448
  const float* src; ushort* dst; int off;
  if      (i < 98304)  { src = s0; dst = d0; off = i; }
  else if (i < 163840) { src = s1; dst = d1; off = i - 98304; }
  else if (i < 229376) { src = s2; dst = d2; off = i - 163840; }
  else if (i < 294912) { src = s3; dst = d3; off = i - 229376; }
  else                 { src = s4; dst = d4; off = i - 294912; }
  float4 vv = ((const float4*)src)[off];
  ushort4 o;
  o.x = f2bf(vv.x); o.y = f2bf(vv.y); o.z = f2bf(vv.z); o.w = f2bf(vv.w);
  ((ushort4*)dst)[off] = o;
}

// ---------------------------------------------------------------------------
// LayerNorm over C with transpose (B,C,N) -> bf16 hn[(b*N+n)*C + c]
// ---------------------------------------------------------------------------
__global__ __launch_bounds__(1024) void ln_kernel(const float* __restrict__ x,
                                                  const float* __restrict__ w,
                                                  const float* __restrict__ bia,
                                                  ushort* __restrict__ hn) {
  const int b  = blockIdx.x;
  const int n0 = blockIdx.y * 64;
  const int tid = threadIdx.x;
  const int nx = tid & 63, cg = tid >> 6;   // cg 0..15
  const float* xb = x + (size_t)b * C_ * N_;

  float s = 0.f, s2 = 0.f;
  for (int c = cg; c < C_; c += 16) {
    float v = xb[(size_t)c * N_ + n0 + nx];
    s += v; s2 += v * v;
  }
  __shared__ float red[2][16][64];
  __shared__ float mean[64], rstd[64];
  red[0][cg][nx] = s; red[1][cg][nx] = s2;
  __syncthreads();
  if (cg == 0) {
    float ss = 0.f, ss2 = 0.f;
#pragma unroll
    for (int i = 0; i < 16; ++i) { ss += red[0][i][nx]; ss2 += red[1][i][nx]; }
    float mu  = ss * (1.f / C_);
    float var = ss2 * (1.f / C_) - mu * mu;
    mean[nx] = mu;
    rstd[nx] = rsqrtf(var + EPS_);
  }
  __syncthreads();

  __shared__ float tile[64][65];
  for (int ct = 0; ct < 8; ++ct) {
    const int c0 = ct * 64;
    for (int cy = cg; cy < 64; cy += 16)
      tile[cy][nx] = xb[(size_t)(c0 + cy) * N_ + n0 + nx];
    __syncthreads();
    const int cx = tid & 63, ng = tid >> 6;
    const float wv = w[c0 + cx], bv = bia[c0 + cx];
    for (int ny = ng; ny < 64; ny += 16) {
      float val = (tile[cx][ny] - mean[ny]) * rstd[ny] * wv + bv;
      hn[((size_t)b * N_ + n0 + ny) * C_ + c0 + cx] = f2bf(val);
    }
    __syncthreads();
  }
}

// ---------------------------------------------------------------------------
// Shared GEMM core (bf16 inputs): 128x128x32 tile, 4 waves, 4x4 frags.
// global_load_lds width-16 staging into LINEAR [128][32] LDS (8KB each),
// XOR-swizzled: source pre-swizzle part^=((row>>1)&3), read quad rg^((col>>1)&3)
// -> 2-way (free) bank pattern on ds_read_b128. A/W passed pre-offset to tile.
// ---------------------------------------------------------------------------
__device__ __forceinline__ void gemm_core(const ushort* __restrict__ A,
                                          const ushort* __restrict__ W,
                                          int K, ushort* la, ushort* lb,
                                          f32x4 acc[4][4],
                                          int tid, int wm, int we, int col, int rg) {
  const int lane = tid & 63, w = tid >> 6;
  const int rloc = lane >> 2, pt = lane & 3;
  const int pts = pt ^ ((rloc >> 1) & 3);       // source quad pre-swizzle
  const int qsel = (rg ^ ((col >> 1) & 3)) * 8; // read quad select (ushorts)

  for (int k0 = 0; k0 < K; k0 += 32) {
#pragma unroll
    for (int c = 0; c < 2; ++c) {
      const int chunk = w + c * 4;              // 16-row chunk, wave-uniform
      const int row = chunk * 16 + rloc;
      g2l16(A + (size_t)row * K + k0 + pts * 8, la + chunk * 512);
      g2l16(W + (size_t)row * K + k0 + pts * 8, lb + chunk * 512);
    }
    __syncthreads();   // compiler drains vmcnt before s_barrier
    bfrag af[4], bf[4];
#pragma unroll
    for (int i = 0; i < 4; ++i) {
      af[i] = *(const bfrag*)&la[(wm + i * 16 + col) * 32 + qsel];
      bf[i] = *(const bfrag*)&lb[(we + i * 16 + col) * 32 + qsel];
    }
#pragma unroll
    for (int i = 0; i < 4; ++i)
#pragma unroll
      for (int j = 0; j < 4; ++j)
        acc[i][j] = mfma16(af[i], bf[j], acc[i][j]);
    __syncthreads();
  }
}

// plain bf16-out GEMM (q-projection): out[m][e] = sum_k A[m][k]*W[e][k]
__global__ __launch_bounds__(256) void gemm_g(const ushort* __restrict__ A,
                                              const ushort* __restrict__ W,
                                              ushort* __restrict__ out, int K) {
  __shared__ ushort la[128 * 32];
  __shared__ ushort lb[128 * 32];
  const int m0 = blockIdx.x * 128, e0 = blockIdx.y * 128;
  const int tid = threadIdx.x, lane = tid & 63, w = tid >> 6;
  const int wm = (w >> 1) * 64, we = (w & 1) * 64;
  const int col = lane & 15, rg = lane >> 4;

  f32x4 acc[4][4] = {};
  gemm_core(A + (size_t)m0 * K, W + (size_t)e0 * K, K, la, lb, acc, tid, wm, we, col, rg);

#pragma unroll
  for (int i = 0; i < 4; ++i)
#pragma unroll
    for (int j = 0; j < 4; ++j)
#pragma unroll
      for (int r = 0; r < 4; ++r)
        out[(size_t)(m0 + wm + i * 16 + rg * 4 + r) * 512 + e0 + we + j * 16 + col] =
            f2bf(acc[i][j][r]);
}

// fused K+V projection: blockIdx.y<4 -> K-proj, else V-proj (512 blocks total)
__global__ __launch_bounds__(256) void gemm_kv(const ushort* __restrict__ A,
                                               const ushort* __restrict__ Wk,
                                               const ushort* __restrict__ Wv,
                                               ushort* __restrict__ Ko,
                                               ushort* __restrict__ Vo) {
  __shared__ ushort la[128 * 32];
  __shared__ ushort lb[128 * 32];
  const int isv = blockIdx.y >> 2;
  const ushort* W = isv ? Wv : Wk;
  ushort* out = isv ? Vo : Ko;
  const int m0 = blockIdx.x * 128, e0 = (blockIdx.y & 3) * 128;
  const int tid = threadIdx.x, lane = tid & 63, w = tid >> 6;
  const int wm = (w >> 1) * 64, we = (w & 1) * 64;
  const int col = lane & 15, rg = lane >> 4;

  f32x4 acc[4][4] = {};
  gemm_core(A + (size_t)m0 * C_, W + (size_t)e0 * C_, C_, la, lb, acc, tid, wm, we, col, rg);

#pragma unroll
  for (int i = 0; i < 4; ++i)
#pragma unroll
    for (int j = 0; j < 4; ++j)
#pragma unroll
      for (int r = 0; r < 4; ++r)
        out[(size_t)(m0 + wm + i * 16 + rg * 4 + r) * 512 + e0 + we + j * 16 + col] =
            f2bf(acc[i][j][r]);
}

// o-projection + transposed residual epilogue: out[b][c][n] = (A@Wo^T)+x
__global__ __launch_bounds__(256) void gemm_res(const ushort* __restrict__ A,
                                                const ushort* __restrict__ W,
                                                const float* __restrict__ x,
                                                float* __restrict__ out) {
  __shared__ ushort la[128 * 32];
  __shared__ ushort lb[128 * 32];
  __shared__ float T[16][132];
  const int m0 = blockIdx.x * 128, e0 = blockIdx.y * 128;
  const int tid = threadIdx.x, lane = tid & 63, w = tid >> 6;
  const int wm = (w >> 1) * 64, we = (w & 1) * 64;
  const int col = lane & 15, rg = lane >> 4;

  f32x4 acc[4][4] = {};
  gemm_core(A + (size_t)m0 * C_, W + (size_t)e0 * C_, C_, la, lb, acc, tid, wm, we, col, rg);

  const int b = m0 >> 10, n0l = m0 & 1023;
#pragma unroll
  for (int g = 0; g < 8; ++g) {
    if ((w & 1) == (g >> 2)) {          // wave-uniform: we-half owns this group
      const int j = g & 3;
#pragma unroll
      for (int i = 0; i < 4; ++i)
        *(f32x4*)&T[col][wm + i * 16 + rg * 4] = acc[i][j];
    }
    __syncthreads();
    const int n = tid & 127;
    for (int cc = tid >> 7; cc < 16; cc += 2) {
      const int c = e0 + g * 16 + cc;
      const size_t idx = (size_t)b * C_ * N_ + (size_t)c * N_ + n0l + n;
      out[idx] = T[cc][n] + x[idx];
    }
    __syncthreads();
  }
}

// ---------------------------------------------------------------------------
// ctx projection: A fp32 (converted in-reg during staging) -> keeps padded
// reg-staged path (global_load_lds can't convert). out bf16.
// ---------------------------------------------------------------------------
__global__ __launch_bounds__(256) void gemm_ctx(const float* __restrict__ Ap,
                                                const ushort* __restrict__ W,
                                                ushort* __restrict__ outp) {
  __shared__ ushort la[128 * 40];
  __shared__ ushort lb[128 * 40];
  const int m0 = blockIdx.x * 128, e0 = blockIdx.y * 128;
  const int tid = threadIdx.x, lane = tid & 63, w = tid >> 6;
  const int wm = (w >> 1) * 64, we = (w & 1) * 64;
  const int col = lane & 15, rg = lane >> 4;
  const int srow = tid >> 1, sh = (tid & 1) * 16;
  const int K = CTX_;

  f32x4 acc[4][4] = {};

  for (int k0 = 0; k0 < K; k0 += 32) {
    {
      const float* ap = &Ap[(size_t)(m0 + srow) * K + k0 + sh];
      float4 f0 = ((const float4*)ap)[0];
      float4 f1 = ((const float4*)ap)[1];
      float4 f2 = ((const float4*)ap)[2];
      float4 f3 = ((const float4*)ap)[3];
      union { int4 v; ushort u[8]; } p0, p1;
      p0.u[0] = f2bf(f0.x); p0.u[1] = f2bf(f0.y); p0.u[2] = f2bf(f0.z); p0.u[3] = f2bf(f0.w);
      p0.u[4] = f2bf(f1.x); p0.u[5] = f2bf(f1.y); p0.u[6] = f2bf(f1.z); p0.u[7] = f2bf(f1.w);
      p1.u[0] = f2bf(f2.x); p1.u[1] = f2bf(f2.y); p1.u[2] = f2bf(f2.z); p1.u[3] = f2bf(f2.w);
      p1.u[4] = f2bf(f3.x); p1.u[5] = f2bf(f3.y); p1.u[6] = f2bf(f3.z); p1.u[7] = f2bf(f3.w);
      *(int4*)&la[srow * 40 + sh]     = p0.v;
      *(int4*)&la[srow * 40 + sh + 8] = p1.v;
      const ushort* wp = &W[(size_t)(e0 + srow) * K + k0 + sh];
      *(int4*)&lb[srow * 40 + sh]     = *(const int4*)wp;
      *(int4*)&lb[srow * 40 + sh + 8] = *(const int4*)(wp + 8);
    }
    __syncthreads();
    bfrag af[4], bf[4];
#pragma unroll
    for (int i = 0; i < 4; ++i) {
      af[i] = *(const bfrag*)&la[(wm + i * 16 + col) * 40 + rg * 8];
      bf[i] = *(const bfrag*)&lb[(we + i * 16 + col) * 40 + rg * 8];
    }
#pragma unroll
    for (int i = 0; i < 4; ++i)
#pragma unroll
      for (int j = 0; j < 4; ++j)
        acc[i][j] = mfma16(af[i], bf[j], acc[i][j]);
    __syncthreads();
  }

#pragma unroll
  for (int i = 0; i < 4; ++i)
#pragma unroll
    for (int j = 0; j < 4; ++j)
#pragma unroll
      for (int r = 0; r < 4; ++r)
        outp[(size_t)(m0 + wm + i * 16 + rg * 4 + r) * 512 + e0 + we + j * 16 + col] =
            f2bf(acc[i][j][r]);
}

// ---------------------------------------------------------------------------
// MFMA flash cross-attention, bf16 operands / fp32 softmax+accum.
// Fixed-max softmax (scores bounded; masked -> exp2(-1e30)=0); exp2f with
// scale*log2e+bias folded into one fma; manual f2bf (round-9 lesson).
// ---------------------------------------------------------------------------
__global__ __launch_bounds__(256) void attn_mfma(const ushort* __restrict__ q,
                                                 const ushort* __restrict__ k,
                                                 const ushort* __restrict__ v,
                                                 const int* __restrict__ mask,
                                                 ushort* __restrict__ o) {
  __shared__ ushort Kl[64 * 72];      // [key][72]
  __shared__ ushort Vt[64 * 72];      // [d][72]
  __shared__ ushort Pw[4][32 * 76];   // per-wave P [qrow][76]
  __shared__ float mlb[64];

  const int h = blockIdx.y, b = blockIdx.z;
  const int q0 = blockIdx.x * 128;
  const int tid = threadIdx.x, lane = tid & 63, w = tid >> 6;
  const int col = lane & 15, rg = lane >> 4;
  const int wq = w * 32;
  const float C1 = 0.18033688011112042f;  // 0.125 * log2(e)

  bfrag qf[2][2];
#pragma unroll
  for (int mi = 0; mi < 2; ++mi)
#pragma unroll
    for (int kc = 0; kc < 2; ++kc)
      qf[mi][kc] = *(const bfrag*)
          &q[((size_t)b * N_ + q0 + wq + mi * 16 + col) * C_ + h * HD_ + kc * 32 + rg * 8];

  f32x4 oa[2][4] = {};
  float l_part[2][4] = {};   // per-lane partial softmax denominators

  for (int l0 = 0; l0 < L_; l0 += 64) {
#pragma unroll
    for (int it = 0; it < 2; ++it) {     // K: 64 keys x 128B
      const int idx = it * 256 + tid;
      const int key = idx >> 3, part = idx & 7;
      *(int4*)&Kl[key * 72 + part * 8] =
          *(const int4*)&k[((size_t)b * L_ + l0 + key) * C_ + h * HD_ + part * 8];
    }
#pragma unroll
    for (int it = 0; it < 4; ++it) {     // V transposed: Vt[d][key]
      const int idx = it * 256 + tid;
      const int key = idx & 63, d0 = (idx >> 6) * 4;
      ushort4 vv = *(const ushort4*)&v[((size_t)b * L_ + l0 + key) * C_ + h * HD_ + d0];
      Vt[(d0 + 0) * 72 + key] = vv.x;
      Vt[(d0 + 1) * 72 + key] = vv.y;
      Vt[(d0 + 2) * 72 + key] = vv.z;
      Vt[(d0 + 3) * 72 + key] = vv.w;
    }
    if (tid < 64) mlb[tid] = mask[b * L_ + l0 + tid] ? 0.f : -1e30f;
    __syncthreads();

    // S = Q K^T  (B-frag: col=key, k=d)
    f32x4 s[2][4] = {};
#pragma unroll
    for (int kc = 0; kc < 2; ++kc) {
      bfrag kf[4];
#pragma unroll
      for (int ni = 0; ni < 4; ++ni)
        kf[ni] = *(const bfrag*)&Kl[(ni * 16 + col) * 72 + kc * 32 + rg * 8];
#pragma unroll
      for (int mi = 0; mi < 2; ++mi)
#pragma unroll
        for (int ni = 0; ni < 4; ++ni)
          s[mi][ni] = mfma16(qf[mi][kc], kf[ni], s[mi][ni]);
    }
    // p = exp2(s*C1 + bias); accumulate per-lane row sums
#pragma unroll
    for (int ni = 0; ni < 4; ++ni) {
      const float bias = mlb[ni * 16 + col];
#pragma unroll
      for (int mi = 0; mi < 2; ++mi)
#pragma unroll
        for (int r = 0; r < 4; ++r) {
          const float p = exp2f(fmaf(s[mi][ni][r], C1, bias));
          s[mi][ni][r] = p;
          l_part[mi][r] += p;
        }
    }
    // P (C-layout) -> per-wave LDS as bf16
#pragma unroll
    for (int mi = 0; mi < 2; ++mi)
#pragma unroll
      for (int ni = 0; ni < 4; ++ni)
#pragma unroll
        for (int r = 0; r < 4; ++r)
          Pw[w][(mi * 16 + rg * 4 + r) * 76 + ni * 16 + col] = f2bf(s[mi][ni][r]);
    // PV: A-frag from Pw (row=q, k=key), B-frag from Vt (col=d, k=key)
#pragma unroll
    for (int kc = 0; kc < 2; ++kc) {
      bfrag pf[2], vf[4];
#pragma unroll
      for (int mi = 0; mi < 2; ++mi)
        pf[mi] = *(const bfrag*)&Pw[w][(mi * 16 + col) * 76 + kc * 32 + rg * 8];
#pragma unroll
      for (int di = 0; di < 4; ++di)
        vf[di] = *(const bfrag*)&Vt[(di * 16 + col) * 72 + kc * 32 + rg * 8];
#pragma unroll
      for (int mi = 0; mi < 2; ++mi)
#pragma unroll
        for (int di = 0; di < 4; ++di)
          oa[mi][di] = mfma16(pf[mi], vf[di], oa[mi][di]);
    }
    __syncthreads();
  }

  // final denominator reduce across the 16 lanes sharing rg, then write
#pragma unroll
  for (int mi = 0; mi < 2; ++mi) {
#pragma unroll
    for (int r = 0; r < 4; ++r) {
      float l = l_part[mi][r];
      l += __shfl_xor(l, 1);
      l += __shfl_xor(l, 2);
      l += __shfl_xor(l, 4);
      l += __shfl_xor(l, 8);
      const float inv = 1.f / l;
      const size_t row = (size_t)b * N_ + q0 + wq + mi * 16 + rg * 4 + r;
#pragma unroll
      for (int di = 0; di < 4; ++di)
        o[row * C_ + h * HD_ + di * 16 + col] = f2bf(oa[mi][di][r] * inv);
    }
  }
}

// ---------------------------------------------------------------------------
// Launch
// ---------------------------------------------------------------------------
extern "C" void kernel_launch(void* const* d_in, const int* in_sizes, int n_in,
                              void* d_out, int out_size, void* d_ws, size_t ws_size,
                              hipStream_t stream) {
  (void)in_sizes; (void)n_in; (void)out_size; (void)ws_size;
  const float* x       = (const float*)d_in[0];
  const float* context = (const float*)d_in[1];
  const int*   mask    = (const int*)d_in[2];
  const float* ln_w    = (const float*)d_in[3];
  const float* ln_b    = (const float*)d_in[4];
  const float* Wq      = (const float*)d_in[5];
  const float* Wk      = (const float*)d_in[6];
  const float* Wv      = (const float*)d_in[7];
  const float* Wo      = (const float*)d_in[8];
  const float* Wctx    = (const float*)d_in[9];

  char* wsb = (char*)d_ws;
  ushort* qb    = (ushort*)(wsb + 0);          // 16384x512 bf16
  ushort* kb    = (ushort*)(wsb + 16777216);   //  8192x512
  ushort* vb    = (ushort*)(wsb + 25165824);   //  8192x512
  ushort* hn    = (ushort*)(wsb + 33554432);   // 16384x512 (later atto)
  ushort* ctx   = (ushort*)(wsb + 50331648);   //  8192x512
  ushort* wctxb = (ushort*)(wsb + 58720256);   //   512x768
  ushort* wqb   = (ushort*)(wsb + 59506688);   //   512x512 each
  ushort* wkb   = (ushort*)(wsb + 60030976);
  ushort* wvb   = (ushort*)(wsb + 60555264);
  ushort* wob   = (ushort*)(wsb + 61079552);

  cast5_kernel<<<1408, 256, 0, stream>>>(Wctx, Wq, Wk, Wv, Wo,
                                         wctxb, wqb, wkb, wvb, wob);
  ln_kernel<<<dim3(B_, N_ / 64), 1024, 0, stream>>>(x, ln_w, ln_b, hn);
  // ctx = context @ Wctx^T, fp32 A converted in staging
  gemm_ctx<<<dim3(64, 4), 256, 0, stream>>>(context, wctxb, ctx);
  // k,v fused (512 blocks = 2/CU), global_load_lds staging
  gemm_kv<<<dim3(64, 8), 256, 0, stream>>>(ctx, wkb, wvb, kb, vb);
  // q = hn @ Wq^T, global_load_lds staging
  gemm_g<<<dim3(128, 4), 256, 0, stream>>>(hn, wqb, qb, C_);
  attn_mfma<<<dim3(N_ / 128, NH_, B_), 256, 0, stream>>>(qb, kb, vb, mask, hn);
  // out = transpose(atto @ Wo^T) + x, fused epilogue, global_load_lds staging
  gemm_res<<<dim3(128, 4), 256, 0, stream>>>(hn, wob, x, (float*)d_out);
}

// Round 11
// 174.427 us; speedup vs baseline: 6.1474x; 1.0364x over previous
//
#include <hip/hip_runtime.h>

// Problem constants
#define B_   16
#define C_   512
#define N_   1024   // H*W
#define L_   512
#define CTX_ 768
#define NH_  8
#define HD_  64
#define EPS_ 1e-5f

typedef short bfrag  __attribute__((ext_vector_type(8)));  // 8 x bf16 bits
typedef short bfrag4 __attribute__((ext_vector_type(4)));  // 4 x bf16 bits
typedef float f32x4  __attribute__((ext_vector_type(4)));

// manual RNE f32->bf16 (finite inputs). Round-10: manual vs native measured
// equal; keeping manual.
__device__ __forceinline__ ushort f2bf(float f) {
  union { float f; unsigned u; } v; v.f = f;
  unsigned r = v.u + 0x7fffu + ((v.u >> 16) & 1u);
  return (ushort)(r >> 16);
}

__device__ __forceinline__ f32x4 mfma16(bfrag a, bfrag b, f32x4 c) {
  return __builtin_amdgcn_mfma_f32_16x16x32_bf16(a, b, c, 0, 0, 0);
}
__device__ __forceinline__ f32x4 mfma16k16(bfrag4 a, bfrag4 b, f32x4 c) {
  return __builtin_amdgcn_mfma_f32_16x16x16bf16_1k(a, b, c, 0, 0, 0);
}
// pack 2 f32 -> 1 dword of 2 bf16 (lo in [15:0], hi in [31:16]), RNE
__device__ __forceinline__ unsigned cvt_pk_bf16(float lo, float hi) {
  unsigned d;
  asm("v_cvt_pk_bf16_f32 %0, %1, %2" : "=v"(d) : "v"(lo), "v"(hi));
  return d;
}

// async global->LDS, 16B/lane (m97 lever). dst must be wave-uniform.
__device__ __forceinline__ void g2l16(const ushort* g, ushort* l) {
  __builtin_amdgcn_global_load_lds(
      (const __attribute__((address_space(1))) void*)g,
      (__attribute__((address_space(3))) void*)l, 16, 0, 0);
}

// ---------------------------------------------------------------------------
// fused weight casts: Wctx (98304 f4) + Wq/Wk/Wv/Wo (65536 f4 each), ONE launch
// ---------------------------------------------------------------------------
__global__ __launch_bounds__(256) void cast5_kernel(
    const float* __restrict__ s0, const float* __restrict__ s1,
    const float* __restrict__ s2, const float* __restrict__ s3,
    const float* __restrict__ s4,
    ushort* __restrict__ d0, ushort* __restrict__ d1, ushort* __restrict__ d2,
    ushort* __restrict__ d3, ushort* __restrict__ d4) {
  int i = blockIdx.x * 256 + threadIdx.x;   // float4 index, total 360448
  const float* src; ushort* dst; int off;
  if      (i < 98304)  { src = s0; dst = d0; off = i; }
  else if (i < 163840) { src = s1; dst = d1; off = i - 98304; }
  else if (i < 229376) { src = s2; dst = d2; off = i - 163840; }
  else if (i < 294912) { src = s3; dst = d3; off = i - 229376; }
  else                 { src = s4; dst = d4; off = i - 294912; }
  float4 vv = ((const float4*)src)[off];
  ushort4 o;
  o.x = f2bf(vv.x); o.y = f2bf(vv.y); o.z = f2bf(vv.z); o.w = f2bf(vv.w);
  ((ushort4*)dst)[off] = o;
}

// ---------------------------------------------------------------------------
// LayerNorm over C with transpose (B,C,N) -> bf16 hn[(b*N+n)*C + c]
// ---------------------------------------------------------------------------
__global__ __launch_bounds__(1024) void ln_kernel(const float* __restrict__ x,
                                                  const float* __restrict__ w,
                                                  const float* __restrict__ bia,
                                                  ushort* __restrict__ hn) {
  const int b  = blockIdx.x;
  const int n0 = blockIdx.y * 64;
  const int tid = threadIdx.x;
  const int nx = tid & 63, cg = tid >> 6;   // cg 0..15
  const float* xb = x + (size_t)b * C_ * N_;

  float s = 0.f, s2 = 0.f;
  for (int c = cg; c < C_; c += 16) {
    float v = xb[(size_t)c * N_ + n0 + nx];
    s += v; s2 += v * v;
  }
  __shared__ float red[2][16][64];
  __shared__ float mean[64], rstd[64];
  red[0][cg][nx] = s; red[1][cg][nx] = s2;
  __syncthreads();
  if (cg == 0) {
    float ss = 0.f, ss2 = 0.f;
#pragma unroll
    for (int i = 0; i < 16; ++i) { ss += red[0][i][nx]; ss2 += red[1][i][nx]; }
    float mu  = ss * (1.f / C_);
    float var = ss2 * (1.f / C_) - mu * mu;
    mean[nx] = mu;
    rstd[nx] = rsqrtf(var + EPS_);
  }
  __syncthreads();

  __shared__ float tile[64][65];
  for (int ct = 0; ct < 8; ++ct) {
    const int c0 = ct * 64;
    for (int cy = cg; cy < 64; cy += 16)
      tile[cy][nx] = xb[(size_t)(c0 + cy) * N_ + n0 + nx];
    __syncthreads();
    const int cx = tid & 63, ng = tid >> 6;
    const float wv = w[c0 + cx], bv = bia[c0 + cx];
    for (int ny = ng; ny < 64; ny += 16) {
      float val = (tile[cx][ny] - mean[ny]) * rstd[ny] * wv + bv;
      hn[((size_t)b * N_ + n0 + ny) * C_ + c0 + cx] = f2bf(val);
    }
    __syncthreads();
  }
}

// ---------------------------------------------------------------------------
// Shared GEMM core (bf16 inputs): 128x128x32 tile, 4 waves, 4x4 frags.
// global_load_lds width-16 staging into LINEAR [128][32] LDS, XOR-swizzled
// source/read quad (both-sides involution).
// ---------------------------------------------------------------------------
__device__ __forceinline__ void gemm_core(const ushort* __restrict__ A,
                                          const ushort* __restrict__ W,
                                          int K, ushort* la, ushort* lb,
                                          f32x4 acc[4][4],
                                          int tid, int wm, int we, int col, int rg) {
  const int lane = tid & 63, w = tid >> 6;
  const int rloc = lane >> 2, pt = lane & 3;
  const int pts = pt ^ ((rloc >> 1) & 3);       // source quad pre-swizzle
  const int qsel = (rg ^ ((col >> 1) & 3)) * 8; // read quad select (ushorts)

  for (int k0 = 0; k0 < K; k0 += 32) {
#pragma unroll
    for (int c = 0; c < 2; ++c) {
      const int chunk = w + c * 4;              // 16-row chunk, wave-uniform
      const int row = chunk * 16 + rloc;
      g2l16(A + (size_t)row * K + k0 + pts * 8, la + chunk * 512);
      g2l16(W + (size_t)row * K + k0 + pts * 8, lb + chunk * 512);
    }
    __syncthreads();   // compiler drains vmcnt before s_barrier
    bfrag af[4], bf[4];
#pragma unroll
    for (int i = 0; i < 4; ++i) {
      af[i] = *(const bfrag*)&la[(wm + i * 16 + col) * 32 + qsel];
      bf[i] = *(const bfrag*)&lb[(we + i * 16 + col) * 32 + qsel];
    }
#pragma unroll
    for (int i = 0; i < 4; ++i)
#pragma unroll
      for (int j = 0; j < 4; ++j)
        acc[i][j] = mfma16(af[i], bf[j], acc[i][j]);
    __syncthreads();
  }
}

// plain bf16-out GEMM (q-projection): out[m][e] = sum_k A[m][k]*W[e][k]
__global__ __launch_bounds__(256) void gemm_g(const ushort* __restrict__ A,
                                              const ushort* __restrict__ W,
                                              ushort* __restrict__ out, int K) {
  __shared__ ushort la[128 * 32];
  __shared__ ushort lb[128 * 32];
  const int m0 = blockIdx.x * 128, e0 = blockIdx.y * 128;
  const int tid = threadIdx.x, lane = tid & 63, w = tid >> 6;
  const int wm = (w >> 1) * 64, we = (w & 1) * 64;
  const int col = lane & 15, rg = lane >> 4;

  f32x4 acc[4][4] = {};
  gemm_core(A + (size_t)m0 * K, W + (size_t)e0 * K, K, la, lb, acc, tid, wm, we, col, rg);

#pragma unroll
  for (int i = 0; i < 4; ++i)
#pragma unroll
    for (int j = 0; j < 4; ++j)
#pragma unroll
      for (int r = 0; r < 4; ++r)
        out[(size_t)(m0 + wm + i * 16 + rg * 4 + r) * 512 + e0 + we + j * 16 + col] =
            f2bf(acc[i][j][r]);
}

// fused K+V projection: blockIdx.y<4 -> K-proj, else V-proj (512 blocks total)
__global__ __launch_bounds__(256) void gemm_kv(const ushort* __restrict__ A,
                                               const ushort* __restrict__ Wk,
                                               const ushort* __restrict__ Wv,
                                               ushort* __restrict__ Ko,
                                               ushort* __restrict__ Vo) {
  __shared__ ushort la[128 * 32];
  __shared__ ushort lb[128 * 32];
  const int isv = blockIdx.y >> 2;
  const ushort* W = isv ? Wv : Wk;
  ushort* out = isv ? Vo : Ko;
  const int m0 = blockIdx.x * 128, e0 = (blockIdx.y & 3) * 128;
  const int tid = threadIdx.x, lane = tid & 63, w = tid >> 6;
  const int wm = (w >> 1) * 64, we = (w & 1) * 64;
  const int col = lane & 15, rg = lane >> 4;

  f32x4 acc[4][4] = {};
  gemm_core(A + (size_t)m0 * C_, W + (size_t)e0 * C_, C_, la, lb, acc, tid, wm, we, col, rg);

#pragma unroll
  for (int i = 0; i < 4; ++i)
#pragma unroll
    for (int j = 0; j < 4; ++j)
#pragma unroll
      for (int r = 0; r < 4; ++r)
        out[(size_t)(m0 + wm + i * 16 + rg * 4 + r) * 512 + e0 + we + j * 16 + col] =
            f2bf(acc[i][j][r]);
}

// o-projection + transposed residual epilogue: out[b][c][n] = (A@Wo^T)+x
__global__ __launch_bounds__(256) void gemm_res(const ushort* __restrict__ A,
                                                const ushort* __restrict__ W,
                                                const float* __restrict__ x,
                                                float* __restrict__ out) {
  __shared__ ushort la[128 * 32];
  __shared__ ushort lb[128 * 32];
  __shared__ float T[16][132];
  const int m0 = blockIdx.x * 128, e0 = blockIdx.y * 128;
  const int tid = threadIdx.x, lane = tid & 63, w = tid >> 6;
  const int wm = (w >> 1) * 64, we = (w & 1) * 64;
  const int col = lane & 15, rg = lane >> 4;

  f32x4 acc[4][4] = {};
  gemm_core(A + (size_t)m0 * C_, W + (size_t)e0 * C_, C_, la, lb, acc, tid, wm, we, col, rg);

  const int b = m0 >> 10, n0l = m0 & 1023;
#pragma unroll
  for (int g = 0; g < 8; ++g) {
    if ((w & 1) == (g >> 2)) {          // wave-uniform: we-half owns this group
      const int j = g & 3;
#pragma unroll
      for (int i = 0; i < 4; ++i)
        *(f32x4*)&T[col][wm + i * 16 + rg * 4] = acc[i][j];
    }
    __syncthreads();
    const int n = tid & 127;
    for (int cc = tid >> 7; cc < 16; cc += 2) {
      const int c = e0 + g * 16 + cc;
      const size_t idx = (size_t)b * C_ * N_ + (size_t)c * N_ + n0l + n;
      out[idx] = T[cc][n] + x[idx];
    }
    __syncthreads();
  }
}

// ---------------------------------------------------------------------------
// ctx projection: A fp32 (converted in-reg during staging), out bf16.
// ---------------------------------------------------------------------------
__global__ __launch_bounds__(256) void gemm_ctx(const float* __restrict__ Ap,
                                                const ushort* __restrict__ W,
                                                ushort* __restrict__ outp) {
  __shared__ ushort la[128 * 40];
  __shared__ ushort lb[128 * 40];
  const int m0 = blockIdx.x * 128, e0 = blockIdx.y * 128;
  const int tid = threadIdx.x, lane = tid & 63, w = tid >> 6;
  const int wm = (w >> 1) * 64, we = (w & 1) * 64;
  const int col = lane & 15, rg = lane >> 4;
  const int srow = tid >> 1, sh = (tid & 1) * 16;
  const int K = CTX_;

  f32x4 acc[4][4] = {};

  for (int k0 = 0; k0 < K; k0 += 32) {
    {
      const float* ap = &Ap[(size_t)(m0 + srow) * K + k0 + sh];
      float4 f0 = ((const float4*)ap)[0];
      float4 f1 = ((const float4*)ap)[1];
      float4 f2 = ((const float4*)ap)[2];
      float4 f3 = ((const float4*)ap)[3];
      union { int4 v; ushort u[8]; } p0, p1;
      p0.u[0] = f2bf(f0.x); p0.u[1] = f2bf(f0.y); p0.u[2] = f2bf(f0.z); p0.u[3] = f2bf(f0.w);
      p0.u[4] = f2bf(f1.x); p0.u[5] = f2bf(f1.y); p0.u[6] = f2bf(f1.z); p0.u[7] = f2bf(f1.w);
      p1.u[0] = f2bf(f2.x); p1.u[1] = f2bf(f2.y); p1.u[2] = f2bf(f2.z); p1.u[3] = f2bf(f2.w);
      p1.u[4] = f2bf(f3.x); p1.u[5] = f2bf(f3.y); p1.u[6] = f2bf(f3.z); p1.u[7] = f2bf(f3.w);
      *(int4*)&la[srow * 40 + sh]     = p0.v;
      *(int4*)&la[srow * 40 + sh + 8] = p1.v;
      const ushort* wp = &W[(size_t)(e0 + srow) * K + k0 + sh];
      *(int4*)&lb[srow * 40 + sh]     = *(const int4*)wp;
      *(int4*)&lb[srow * 40 + sh + 8] = *(const int4*)(wp + 8);
    }
    __syncthreads();
    bfrag af[4], bf[4];
#pragma unroll
    for (int i = 0; i < 4; ++i) {
      af[i] = *(const bfrag*)&la[(wm + i * 16 + col) * 40 + rg * 8];
      bf[i] = *(const bfrag*)&lb[(we + i * 16 + col) * 40 + rg * 8];
    }
#pragma unroll
    for (int i = 0; i < 4; ++i)
#pragma unroll
      for (int j = 0; j < 4; ++j)
        acc[i][j] = mfma16(af[i], bf[j], acc[i][j]);
    __syncthreads();
  }

#pragma unroll
  for (int i = 0; i < 4; ++i)
#pragma unroll
    for (int j = 0; j < 4; ++j)
#pragma unroll
      for (int r = 0; r < 4; ++r)
        outp[(size_t)(m0 + wm + i * 16 + rg * 4 + r) * 512 + e0 + we + j * 16 + col] =
            f2bf(acc[i][j][r]);
}

// ---------------------------------------------------------------------------
// MFMA flash cross-attention. Round-11 restructure (T12-style):
// SWAPPED QK^T: s2 = mfma(K, Q) -> S^T C-layout col=q, row=rg*4+r=key, which
// IS the 16x16x16 A-frag layout -> P never leaves registers. cvt_pk packs
// f32 pairs to bf16; PV = mfma_f32_16x16x16bf16_1k(pf, vf, oa) with vf as
// contiguous b64 reads from Vt. Pw LDS buffer deleted (38.4KB -> 18.7KB).
// Denominator: per-lane scalar (q=col), 2-shfl reduce, 8 end bpermutes to
// redistribute 1/l to oa's q=rg*4+r layout.
// ---------------------------------------------------------------------------
__global__ __launch_bounds__(256) void attn_mfma(const ushort* __restrict__ q,
                                                 const ushort* __restrict__ k,
                                                 const ushort* __restrict__ v,
                                                 const int* __restrict__ mask,
                                                 ushort* __restrict__ o) {
  __shared__ ushort Kl[64 * 72];      // [key][72]
  __shared__ ushort Vt[64 * 72];      // [d][72]
  __shared__ float mlb[64];

  const int h = blockIdx.y, b = blockIdx.z;
  const int q0 = blockIdx.x * 128;
  const int tid = threadIdx.x, lane = tid & 63, w = tid >> 6;
  const int col = lane & 15, rg = lane >> 4;
  const int wq = w * 32;
  const float C1 = 0.18033688011112042f;  // 0.125 * log2(e)

  bfrag qf[2][2];
#pragma unroll
  for (int mi = 0; mi < 2; ++mi)
#pragma unroll
    for (int kc = 0; kc < 2; ++kc)
      qf[mi][kc] = *(const bfrag*)
          &q[((size_t)b * N_ + q0 + wq + mi * 16 + col) * C_ + h * HD_ + kc * 32 + rg * 8];

  f32x4 oa[2][4] = {};
  float l_part[2] = {0.f, 0.f};   // per-lane denominator for q = col

  for (int l0 = 0; l0 < L_; l0 += 64) {
#pragma unroll
    for (int it = 0; it < 2; ++it) {     // K: 64 keys x 128B
      const int idx = it * 256 + tid;
      const int key = idx >> 3, part = idx & 7;
      *(int4*)&Kl[key * 72 + part * 8] =
          *(const int4*)&k[((size_t)b * L_ + l0 + key) * C_ + h * HD_ + part * 8];
    }
#pragma unroll
    for (int it = 0; it < 4; ++it) {     // V transposed: Vt[d][key]
      const int idx = it * 256 + tid;
      const int key = idx & 63, d0 = (idx >> 6) * 4;
      ushort4 vv = *(const ushort4*)&v[((size_t)b * L_ + l0 + key) * C_ + h * HD_ + d0];
      Vt[(d0 + 0) * 72 + key] = vv.x;
      Vt[(d0 + 1) * 72 + key] = vv.y;
      Vt[(d0 + 2) * 72 + key] = vv.z;
      Vt[(d0 + 3) * 72 + key] = vv.w;
    }
    if (tid < 64) mlb[tid] = mask[b * L_ + l0 + tid] ? 0.f : -1e30f;
    __syncthreads();

    // S^T = K Q^T : kf as A-frag (row=key), qf as B-frag (col=q). Same LDS
    // access pattern as before (A/B frag lane layouts coincide).
    f32x4 s2[2][4] = {};
#pragma unroll
    for (int kc = 0; kc < 2; ++kc) {
      bfrag kf[4];
#pragma unroll
      for (int ni = 0; ni < 4; ++ni)
        kf[ni] = *(const bfrag*)&Kl[(ni * 16 + col) * 72 + kc * 32 + rg * 8];
#pragma unroll
      for (int mi = 0; mi < 2; ++mi)
#pragma unroll
        for (int ni = 0; ni < 4; ++ni)
          s2[mi][ni] = mfma16(kf[ni], qf[mi][kc], s2[mi][ni]);
    }
    // p = exp2(s*C1 + bias[key]); key = ni*16 + rg*4 + r (bias vector-read);
    // accumulate per-lane (q=col) denominator; pack to PV A-frags in-register.
    bfrag4 pf[2][4];
#pragma unroll
    for (int ni = 0; ni < 4; ++ni) {
      const f32x4 bias4 = *(const f32x4*)&mlb[ni * 16 + rg * 4];
#pragma unroll
      for (int mi = 0; mi < 2; ++mi) {
        const float p0 = exp2f(fmaf(s2[mi][ni][0], C1, bias4[0]));
        const float p1 = exp2f(fmaf(s2[mi][ni][1], C1, bias4[1]));
        const float p2 = exp2f(fmaf(s2[mi][ni][2], C1, bias4[2]));
        const float p3 = exp2f(fmaf(s2[mi][ni][3], C1, bias4[3]));
        l_part[mi] += (p0 + p1) + (p2 + p3);
        union { bfrag4 v; unsigned u[2]; } pk;
        pk.u[0] = cvt_pk_bf16(p0, p1);
        pk.u[1] = cvt_pk_bf16(p2, p3);
        pf[mi][ni] = pk.v;
      }
    }
    // PV: out[q][d] += P[q][key] V[key][d], K=16 per ni (keys ni*16..+15).
    // vf: B-frag lane holds V[key=ni*16+rg*4+e][d=di*16+col] = b64 from Vt.
#pragma unroll
    for (int ni = 0; ni < 4; ++ni) {
      bfrag4 vf[4];
#pragma unroll
      for (int di = 0; di < 4; ++di)
        vf[di] = *(const bfrag4*)&Vt[(di * 16 + col) * 72 + ni * 16 + rg * 4];
#pragma unroll
      for (int mi = 0; mi < 2; ++mi)
#pragma unroll
        for (int di = 0; di < 4; ++di)
          oa[mi][di] = mfma16k16(pf[mi][ni], vf[di], oa[mi][di]);
    }
    __syncthreads();
  }

  // denominator: reduce across rg groups (lanes sharing col), then bpermute
  // 1/l to oa's row layout (q = rg*4+r lives on lane col=q after reduce).
  float linv[2][4];
#pragma unroll
  for (int mi = 0; mi < 2; ++mi) {
    float l = l_part[mi];
    l += __shfl_xor(l, 16);
    l += __shfl_xor(l, 32);
#pragma unroll
    for (int r = 0; r < 4; ++r) {
      int lv = __builtin_amdgcn_ds_bpermute((rg * 4 + r) * 4, __float_as_int(l));
      linv[mi][r] = 1.f / __int_as_float(lv);
    }
  }
#pragma unroll
  for (int mi = 0; mi < 2; ++mi)
#pragma unroll
    for (int r = 0; r < 4; ++r) {
      const size_t row = (size_t)b * N_ + q0 + wq + mi * 16 + rg * 4 + r;
#pragma unroll
      for (int di = 0; di < 4; ++di)
        o[row * C_ + h * HD_ + di * 16 + col] = f2bf(oa[mi][di][r] * linv[mi][r]);
    }
}

// ---------------------------------------------------------------------------
// Launch
// ---------------------------------------------------------------------------
extern "C" void kernel_launch(void* const* d_in, const int* in_sizes, int n_in,
                              void* d_out, int out_size, void* d_ws, size_t ws_size,
                              hipStream_t stream) {
  (void)in_sizes; (void)n_in; (void)out_size; (void)ws_size;
  const float* x       = (const float*)d_in[0];
  const float* context = (const float*)d_in[1];
  const int*   mask    = (const int*)d_in[2];
  const float* ln_w    = (const float*)d_in[3];
  const float* ln_b    = (const float*)d_in[4];
  const float* Wq      = (const float*)d_in[5];
  const float* Wk      = (const float*)d_in[6];
  const float* Wv      = (const float*)d_in[7];
  const float* Wo      = (const float*)d_in[8];
  const float* Wctx    = (const float*)d_in[9];

  char* wsb = (char*)d_ws;
  ushort* qb    = (ushort*)(wsb + 0);          // 16384x512 bf16
  ushort* kb    = (ushort*)(wsb + 16777216);   //  8192x512
  ushort* vb    = (ushort*)(wsb + 25165824);   //  8192x512
  ushort* hn    = (ushort*)(wsb + 33554432);   // 16384x512 (later atto)
  ushort* ctx   = (ushort*)(wsb + 50331648);   //  8192x512
  ushort* wctxb = (ushort*)(wsb + 58720256);   //   512x768
  ushort* wqb   = (ushort*)(wsb + 59506688);   //   512x512 each
  ushort* wkb   = (ushort*)(wsb + 60030976);
  ushort* wvb   = (ushort*)(wsb + 60555264);
  ushort* wob   = (ushort*)(wsb + 61079552);

  cast5_kernel<<<1408, 256, 0, stream>>>(Wctx, Wq, Wk, Wv, Wo,
                                         wctxb, wqb, wkb, wvb, wob);
  ln_kernel<<<dim3(B_, N_ / 64), 1024, 0, stream>>>(x, ln_w, ln_b, hn);
  // ctx = context @ Wctx^T, fp32 A converted in staging
  gemm_ctx<<<dim3(64, 4), 256, 0, stream>>>(context, wctxb, ctx);
  // k,v fused (512 blocks = 2/CU), global_load_lds staging
  gemm_kv<<<dim3(64, 8), 256, 0, stream>>>(ctx, wkb, wvb, kb, vb);
  // q = hn @ Wq^T, global_load_lds staging
  gemm_g<<<dim3(128, 4), 256, 0, stream>>>(hn, wqb, qb, C_);
  attn_mfma<<<dim3(N_ / 128, NH_, B_), 256, 0, stream>>>(qb, kb, vb, mask, hn);
  // out = transpose(atto @ Wo^T) + x, fused epilogue, global_load_lds staging
  gemm_res<<<dim3(128, 4), 256, 0, stream>>>(hn, wob, x, (float*)d_out);
}

// Round 13
// 170.847 us; speedup vs baseline: 6.2762x; 1.0210x over previous
//
#include <hip/hip_runtime.h>

// Problem constants
#define B_   16
#define C_   512
#define N_   1024   // H*W
#define L_   512
#define CTX_ 768
#define NH_  8
#define HD_  64
#define EPS_ 1e-5f

typedef short bfrag  __attribute__((ext_vector_type(8)));  // 8 x bf16 bits
typedef short bfrag4 __attribute__((ext_vector_type(4)));  // 4 x bf16 bits
typedef float f32x4  __attribute__((ext_vector_type(4)));

// manual RNE f32->bf16 (finite inputs); measured equal to native (r10).
__device__ __forceinline__ ushort f2bf(float f) {
  union { float f; unsigned u; } v; v.f = f;
  unsigned r = v.u + 0x7fffu + ((v.u >> 16) & 1u);
  return (ushort)(r >> 16);
}

__device__ __forceinline__ f32x4 mfma16(bfrag a, bfrag b, f32x4 c) {
  return __builtin_amdgcn_mfma_f32_16x16x32_bf16(a, b, c, 0, 0, 0);
}
__device__ __forceinline__ f32x4 mfma16k16(bfrag4 a, bfrag4 b, f32x4 c) {
  return __builtin_amdgcn_mfma_f32_16x16x16bf16_1k(a, b, c, 0, 0, 0);
}
// pack 2 f32 -> 1 dword of 2 bf16 (lo in [15:0], hi in [31:16]), RNE
__device__ __forceinline__ unsigned cvt_pk_bf16(float lo, float hi) {
  unsigned d;
  asm("v_cvt_pk_bf16_f32 %0, %1, %2" : "=v"(d) : "v"(lo), "v"(hi));
  return d;
}

// async global->LDS, 16B/lane. dst must be wave-uniform base + lane*16.
__device__ __forceinline__ void g2l16(const ushort* g, ushort* l) {
  __builtin_amdgcn_global_load_lds(
      (const __attribute__((address_space(1))) void*)g,
      (__attribute__((address_space(3))) void*)l, 16, 0, 0);
}

// ---------------------------------------------------------------------------
// fused weight casts: Wctx (98304 f4) + Wq/Wk/Wv/Wo (65536 f4 each), ONE launch
// ---------------------------------------------------------------------------
__global__ __launch_bounds__(256) void cast5_kernel(
    const float* __restrict__ s0, const float* __restrict__ s1,
    const float* __restrict__ s2, const float* __restrict__ s3,
    const float* __restrict__ s4,
    ushort* __restrict__ d0, ushort* __restrict__ d1, ushort* __restrict__ d2,
    ushort* __restrict__ d3, ushort* __restrict__ d4) {
  int i = blockIdx.x * 256 + threadIdx.x;   // float4 index, total 360448
  const float* src; ushort* dst; int off;
  if      (i < 98304)  { src = s0; dst = d0; off = i; }
  else if (i < 163840) { src = s1; dst = d1; off = i - 98304; }
  else if (i < 229376) { src = s2; dst = d2; off = i - 163840; }
  else if (i < 294912) { src = s3; dst = d3; off = i - 229376; }
  else                 { src = s4; dst = d4; off = i - 294912; }
  float4 vv = ((const float4*)src)[off];
  ushort4 o;
  o.x = f2bf(vv.x); o.y = f2bf(vv.y); o.z = f2bf(vv.z); o.w = f2bf(vv.w);
  ((ushort4*)dst)[off] = o;
}

// ---------------------------------------------------------------------------
// LN stats only: mean/rstd per (b,n). LN application fused into gemm_lnq.
// ---------------------------------------------------------------------------
__global__ __launch_bounds__(1024) void ln_stats(const float* __restrict__ x,
                                                 float* __restrict__ mu_out,
                                                 float* __restrict__ rs_out) {
  const int b  = blockIdx.x;
  const int n0 = blockIdx.y * 64;
  const int tid = threadIdx.x;
  const int nx = tid & 63, cg = tid >> 6;   // cg 0..15
  const float* xb = x + (size_t)b * C_ * N_;

  float s = 0.f, s2 = 0.f;
  for (int c = cg; c < C_; c += 16) {
    float v = xb[(size_t)c * N_ + n0 + nx];
    s += v; s2 += v * v;
  }
  __shared__ float red[2][16][64];
  red[0][cg][nx] = s; red[1][cg][nx] = s2;
  __syncthreads();
  if (cg == 0) {
    float ss = 0.f, ss2 = 0.f;
#pragma unroll
    for (int i = 0; i < 16; ++i) { ss += red[0][i][nx]; ss2 += red[1][i][nx]; }
    float m  = ss * (1.f / C_);
    float var = ss2 * (1.f / C_) - m * m;
    mu_out[(size_t)b * N_ + n0 + nx] = m;
    rs_out[(size_t)b * N_ + n0 + nx] = rsqrtf(var + EPS_);
  }
}

// ---------------------------------------------------------------------------
// Shared GEMM core (bf16 inputs): 128x128x32 tile, 4 waves, 4x4 frags.
// global_load_lds width-16 staging into LINEAR [128][32] LDS, XOR-swizzled
// source/read quad (both-sides involution).
// ---------------------------------------------------------------------------
__device__ __forceinline__ void gemm_core(const ushort* __restrict__ A,
                                          const ushort* __restrict__ W,
                                          int K, ushort* la, ushort* lb,
                                          f32x4 acc[4][4],
                                          int tid, int wm, int we, int col, int rg) {
  const int lane = tid & 63, w = tid >> 6;
  const int rloc = lane >> 2, pt = lane & 3;
  const int pts = pt ^ ((rloc >> 1) & 3);       // source quad pre-swizzle
  const int qsel = (rg ^ ((col >> 1) & 3)) * 8; // read quad select (ushorts)

  for (int k0 = 0; k0 < K; k0 += 32) {
#pragma unroll
    for (int c = 0; c < 2; ++c) {
      const int chunk = w + c * 4;              // 16-row chunk, wave-uniform
      const int row = chunk * 16 + rloc;
      g2l16(A + (size_t)row * K + k0 + pts * 8, la + chunk * 512);
      g2l16(W + (size_t)row * K + k0 + pts * 8, lb + chunk * 512);
    }
    __syncthreads();
    bfrag af[4], bf[4];
#pragma unroll
    for (int i = 0; i < 4; ++i) {
      af[i] = *(const bfrag*)&la[(wm + i * 16 + col) * 32 + qsel];
      bf[i] = *(const bfrag*)&lb[(we + i * 16 + col) * 32 + qsel];
    }
#pragma unroll
    for (int i = 0; i < 4; ++i)
#pragma unroll
      for (int j = 0; j < 4; ++j)
        acc[i][j] = mfma16(af[i], bf[j], acc[i][j]);
    __syncthreads();
  }
}

// fused K+V projection: blockIdx.y<4 -> K-proj, else V-proj (512 blocks total)
__global__ __launch_bounds__(256) void gemm_kv(const ushort* __restrict__ A,
                                               const ushort* __restrict__ Wk,
                                               const ushort* __restrict__ Wv,
                                               ushort* __restrict__ Ko,
                                               ushort* __restrict__ Vo) {
  __shared__ ushort la[128 * 32];
  __shared__ ushort lb[128 * 32];
  const int isv = blockIdx.y >> 2;
  const ushort* W = isv ? Wv : Wk;
  ushort* out = isv ? Vo : Ko;
  const int m0 = blockIdx.x * 128, e0 = (blockIdx.y & 3) * 128;
  const int tid = threadIdx.x, lane = tid & 63, w = tid >> 6;
  const int wm = (w >> 1) * 64, we = (w & 1) * 64;
  const int col = lane & 15, rg = lane >> 4;

  f32x4 acc[4][4] = {};
  gemm_core(A + (size_t)m0 * C_, W + (size_t)e0 * C_, C_, la, lb, acc, tid, wm, we, col, rg);

#pragma unroll
  for (int i = 0; i < 4; ++i)
#pragma unroll
    for (int j = 0; j < 4; ++j)
#pragma unroll
      for (int r = 0; r < 4; ++r)
        out[(size_t)(m0 + wm + i * 16 + rg * 4 + r) * 512 + e0 + we + j * 16 + col] =
            f2bf(acc[i][j][r]);
}

// o-projection + transposed residual epilogue: out[b][c][n] = (A@Wo^T)+x
__global__ __launch_bounds__(256) void gemm_res(const ushort* __restrict__ A,
                                                const ushort* __restrict__ W,
                                                const float* __restrict__ x,
                                                float* __restrict__ out) {
  __shared__ ushort la[128 * 32];
  __shared__ ushort lb[128 * 32];
  __shared__ float T[16][132];
  const int m0 = blockIdx.x * 128, e0 = blockIdx.y * 128;
  const int tid = threadIdx.x, lane = tid & 63, w = tid >> 6;
  const int wm = (w >> 1) * 64, we = (w & 1) * 64;
  const int col = lane & 15, rg = lane >> 4;

  f32x4 acc[4][4] = {};
  gemm_core(A + (size_t)m0 * C_, W + (size_t)e0 * C_, C_, la, lb, acc, tid, wm, we, col, rg);

  const int b = m0 >> 10, n0l = m0 & 1023;
#pragma unroll
  for (int g = 0; g < 8; ++g) {
    if ((w & 1) == (g >> 2)) {          // wave-uniform: we-half owns this group
      const int j = g & 3;
#pragma unroll
      for (int i = 0; i < 4; ++i)
        *(f32x4*)&T[col][wm + i * 16 + rg * 4] = acc[i][j];
    }
    __syncthreads();
    const int n = tid & 127;
    for (int cc = tid >> 7; cc < 16; cc += 2) {
      const int c = e0 + g * 16 + cc;
      const size_t idx = (size_t)b * C_ * N_ + (size_t)c * N_ + n0l + n;
      out[idx] = T[cc][n] + x[idx];
    }
    __syncthreads();
  }
}

// ---------------------------------------------------------------------------
// ctx projection: A fp32 (converted in-reg during staging), out bf16.
// ---------------------------------------------------------------------------
__global__ __launch_bounds__(256) void gemm_ctx(const float* __restrict__ Ap,
                                                const ushort* __restrict__ W,
                                                ushort* __restrict__ outp) {
  __shared__ ushort la[128 * 40];
  __shared__ ushort lb[128 * 40];
  const int m0 = blockIdx.x * 128, e0 = blockIdx.y * 128;
  const int tid = threadIdx.x, lane = tid & 63, w = tid >> 6;
  const int wm = (w >> 1) * 64, we = (w & 1) * 64;
  const int col = lane & 15, rg = lane >> 4;
  const int srow = tid >> 1, sh = (tid & 1) * 16;
  const int K = CTX_;

  f32x4 acc[4][4] = {};

  for (int k0 = 0; k0 < K; k0 += 32) {
    {
      const float* ap = &Ap[(size_t)(m0 + srow) * K + k0 + sh];
      float4 f0 = ((const float4*)ap)[0];
      float4 f1 = ((const float4*)ap)[1];
      float4 f2 = ((const float4*)ap)[2];
      float4 f3 = ((const float4*)ap)[3];
      union { int4 v; ushort u[8]; } p0, p1;
      p0.u[0] = f2bf(f0.x); p0.u[1] = f2bf(f0.y); p0.u[2] = f2bf(f0.z); p0.u[3] = f2bf(f0.w);
      p0.u[4] = f2bf(f1.x); p0.u[5] = f2bf(f1.y); p0.u[6] = f2bf(f1.z); p0.u[7] = f2bf(f1.w);
      p1.u[0] = f2bf(f2.x); p1.u[1] = f2bf(f2.y); p1.u[2] = f2bf(f2.z); p1.u[3] = f2bf(f2.w);
      p1.u[4] = f2bf(f3.x); p1.u[5] = f2bf(f3.y); p1.u[6] = f2bf(f3.z); p1.u[7] = f2bf(f3.w);
      *(int4*)&la[srow * 40 + sh]     = p0.v;
      *(int4*)&la[srow * 40 + sh + 8] = p1.v;
      const ushort* wp = &W[(size_t)(e0 + srow) * K + k0 + sh];
      *(int4*)&lb[srow * 40 + sh]     = *(const int4*)wp;
      *(int4*)&lb[srow * 40 + sh + 8] = *(const int4*)(wp + 8);
    }
    __syncthreads();
    bfrag af[4], bf[4];
#pragma unroll
    for (int i = 0; i < 4; ++i) {
      af[i] = *(const bfrag*)&la[(wm + i * 16 + col) * 40 + rg * 8];
      bf[i] = *(const bfrag*)&lb[(we + i * 16 + col) * 40 + rg * 8];
    }
#pragma unroll
    for (int i = 0; i < 4; ++i)
#pragma unroll
      for (int j = 0; j < 4; ++j)
        acc[i][j] = mfma16(af[i], bf[j], acc[i][j]);
    __syncthreads();
  }

#pragma unroll
  for (int i = 0; i < 4; ++i)
#pragma unroll
    for (int j = 0; j < 4; ++j)
#pragma unroll
      for (int r = 0; r < 4; ++r)
        outp[(size_t)(m0 + wm + i * 16 + rg * 4 + r) * 512 + e0 + we + j * 16 + col] =
            f2bf(acc[i][j][r]);
}

// ---------------------------------------------------------------------------
// q-projection with fused LayerNorm: A[m=(b,n)][k=c] = (x[b][c][n]-mu)*rs*w+b,
// staged straight from x (no hn round-trip).
// ---------------------------------------------------------------------------
__global__ __launch_bounds__(256) void gemm_lnq(const float* __restrict__ x,
                                                const float* __restrict__ mu,
                                                const float* __restrict__ rs,
                                                const float* __restrict__ lnw,
                                                const float* __restrict__ lnb,
                                                const ushort* __restrict__ W,
                                                ushort* __restrict__ out) {
  __shared__ ushort la[128 * 40];
  __shared__ ushort lb[128 * 40];
  const int m0 = blockIdx.x * 128, e0 = blockIdx.y * 128;
  const int b = m0 >> 10, n0l = m0 & 1023;
  const int tid = threadIdx.x, lane = tid & 63, w = tid >> 6;
  const int wm = (w >> 1) * 64, we = (w & 1) * 64;
  const int col = lane & 15, rg = lane >> 4;
  const int nloc = tid & 127, chalf = (tid >> 7) * 16;
  const int srow = tid >> 1, sh = (tid & 1) * 16;

  const float muv = mu[(size_t)b * N_ + n0l + nloc];
  const float rsv = rs[(size_t)b * N_ + n0l + nloc];
  const float nmr = -muv * rsv;   // t = fma(x, rsv, nmr)
  const float* xb = x + (size_t)b * C_ * N_ + n0l + nloc;

  f32x4 acc[4][4] = {};

  for (int k0 = 0; k0 < C_; k0 += 32) {
    {
      union { int4 v[2]; ushort u[16]; } pk;
#pragma unroll
      for (int i = 0; i < 16; ++i) {
        const int c = k0 + chalf + i;
        const float xv = xb[(size_t)c * N_];
        const float t = fmaf(xv, rsv, nmr);
        pk.u[i] = f2bf(fmaf(t, lnw[c], lnb[c]));
      }
      *(int4*)&la[nloc * 40 + chalf]     = pk.v[0];
      *(int4*)&la[nloc * 40 + chalf + 8] = pk.v[1];
      const ushort* wp = &W[(size_t)(e0 + srow) * C_ + k0 + sh];
      *(int4*)&lb[srow * 40 + sh]     = *(const int4*)wp;
      *(int4*)&lb[srow * 40 + sh + 8] = *(const int4*)(wp + 8);
    }
    __syncthreads();
    bfrag af[4], bf[4];
#pragma unroll
    for (int i = 0; i < 4; ++i) {
      af[i] = *(const bfrag*)&la[(wm + i * 16 + col) * 40 + rg * 8];
      bf[i] = *(const bfrag*)&lb[(we + i * 16 + col) * 40 + rg * 8];
    }
#pragma unroll
    for (int i = 0; i < 4; ++i)
#pragma unroll
      for (int j = 0; j < 4; ++j)
        acc[i][j] = mfma16(af[i], bf[j], acc[i][j]);
    __syncthreads();
  }

#pragma unroll
  for (int i = 0; i < 4; ++i)
#pragma unroll
    for (int j = 0; j < 4; ++j)
#pragma unroll
      for (int r = 0; r < 4; ++r)
        out[(size_t)(m0 + wm + i * 16 + rg * 4 + r) * 512 + e0 + we + j * 16 + col] =
            f2bf(acc[i][j][r]);
}

// ---------------------------------------------------------------------------
// MFMA flash cross-attention (swapped QK^T, P in registers).
// EXACT r11 version (256 threads, grid N/128) — r12's 512-thread variant is
// reverted for bisection after the NaN fail.
// ---------------------------------------------------------------------------
__global__ __launch_bounds__(256) void attn_mfma(const ushort* __restrict__ q,
                                                 const ushort* __restrict__ k,
                                                 const ushort* __restrict__ v,
                                                 const int* __restrict__ mask,
                                                 ushort* __restrict__ o) {
  __shared__ ushort Kl[64 * 72];      // [key][72]
  __shared__ ushort Vt[64 * 72];      // [d][72]
  __shared__ float mlb[64];

  const int h = blockIdx.y, b = blockIdx.z;
  const int q0 = blockIdx.x * 128;
  const int tid = threadIdx.x, lane = tid & 63, w = tid >> 6;
  const int col = lane & 15, rg = lane >> 4;
  const int wq = w * 32;
  const float C1 = 0.18033688011112042f;  // 0.125 * log2(e)

  bfrag qf[2][2];
#pragma unroll
  for (int mi = 0; mi < 2; ++mi)
#pragma unroll
    for (int kc = 0; kc < 2; ++kc)
      qf[mi][kc] = *(const bfrag*)
          &q[((size_t)b * N_ + q0 + wq + mi * 16 + col) * C_ + h * HD_ + kc * 32 + rg * 8];

  f32x4 oa[2][4] = {};
  float l_part[2] = {0.f, 0.f};   // per-lane denominator for q = col

  for (int l0 = 0; l0 < L_; l0 += 64) {
#pragma unroll
    for (int it = 0; it < 2; ++it) {     // K: 64 keys x 128B
      const int idx = it * 256 + tid;
      const int key = idx >> 3, part = idx & 7;
      *(int4*)&Kl[key * 72 + part * 8] =
          *(const int4*)&k[((size_t)b * L_ + l0 + key) * C_ + h * HD_ + part * 8];
    }
#pragma unroll
    for (int it = 0; it < 4; ++it) {     // V transposed: Vt[d][key]
      const int idx = it * 256 + tid;
      const int key = idx & 63, d0 = (idx >> 6) * 4;
      ushort4 vv = *(const ushort4*)&v[((size_t)b * L_ + l0 + key) * C_ + h * HD_ + d0];
      Vt[(d0 + 0) * 72 + key] = vv.x;
      Vt[(d0 + 1) * 72 + key] = vv.y;
      Vt[(d0 + 2) * 72 + key] = vv.z;
      Vt[(d0 + 3) * 72 + key] = vv.w;
    }
    if (tid < 64) mlb[tid] = mask[b * L_ + l0 + tid] ? 0.f : -1e30f;
    __syncthreads();

    // S^T = K Q^T : kf as A-frag (row=key), qf as B-frag (col=q)
    f32x4 s2[2][4] = {};
#pragma unroll
    for (int kc = 0; kc < 2; ++kc) {
      bfrag kf[4];
#pragma unroll
      for (int ni = 0; ni < 4; ++ni)
        kf[ni] = *(const bfrag*)&Kl[(ni * 16 + col) * 72 + kc * 32 + rg * 8];
#pragma unroll
      for (int mi = 0; mi < 2; ++mi)
#pragma unroll
        for (int ni = 0; ni < 4; ++ni)
          s2[mi][ni] = mfma16(kf[ni], qf[mi][kc], s2[mi][ni]);
    }
    // p = exp2(s*C1 + bias[key]); key = ni*16 + rg*4 + r; pack A-frags in-reg
    bfrag4 pf[2][4];
#pragma unroll
    for (int ni = 0; ni < 4; ++ni) {
      const f32x4 bias4 = *(const f32x4*)&mlb[ni * 16 + rg * 4];
#pragma unroll
      for (int mi = 0; mi < 2; ++mi) {
        const float p0 = exp2f(fmaf(s2[mi][ni][0], C1, bias4[0]));
        const float p1 = exp2f(fmaf(s2[mi][ni][1], C1, bias4[1]));
        const float p2 = exp2f(fmaf(s2[mi][ni][2], C1, bias4[2]));
        const float p3 = exp2f(fmaf(s2[mi][ni][3], C1, bias4[3]));
        l_part[mi] += (p0 + p1) + (p2 + p3);
        union { bfrag4 v; unsigned u[2]; } pk;
        pk.u[0] = cvt_pk_bf16(p0, p1);
        pk.u[1] = cvt_pk_bf16(p2, p3);
        pf[mi][ni] = pk.v;
      }
    }
    // PV: out[q][d] += P[q][key] V[key][d], K=16 per ni
#pragma unroll
    for (int ni = 0; ni < 4; ++ni) {
      bfrag4 vf[4];
#pragma unroll
      for (int di = 0; di < 4; ++di)
        vf[di] = *(const bfrag4*)&Vt[(di * 16 + col) * 72 + ni * 16 + rg * 4];
#pragma unroll
      for (int mi = 0; mi < 2; ++mi)
#pragma unroll
        for (int di = 0; di < 4; ++di)
          oa[mi][di] = mfma16k16(pf[mi][ni], vf[di], oa[mi][di]);
    }
    __syncthreads();
  }

  // denominator: reduce across rg groups, bpermute 1/l to row layout
  float linv[2][4];
#pragma unroll
  for (int mi = 0; mi < 2; ++mi) {
    float l = l_part[mi];
    l += __shfl_xor(l, 16);
    l += __shfl_xor(l, 32);
#pragma unroll
    for (int r = 0; r < 4; ++r) {
      int lv = __builtin_amdgcn_ds_bpermute((rg * 4 + r) * 4, __float_as_int(l));
      linv[mi][r] = 1.f / __int_as_float(lv);
    }
  }
#pragma unroll
  for (int mi = 0; mi < 2; ++mi)
#pragma unroll
    for (int r = 0; r < 4; ++r) {
      const size_t row = (size_t)b * N_ + q0 + wq + mi * 16 + rg * 4 + r;
#pragma unroll
      for (int di = 0; di < 4; ++di)
        o[row * C_ + h * HD_ + di * 16 + col] = f2bf(oa[mi][di][r] * linv[mi][r]);
    }
}

// ---------------------------------------------------------------------------
// Launch
// ---------------------------------------------------------------------------
extern "C" void kernel_launch(void* const* d_in, const int* in_sizes, int n_in,
                              void* d_out, int out_size, void* d_ws, size_t ws_size,
                              hipStream_t stream) {
  (void)in_sizes; (void)n_in; (void)out_size; (void)ws_size;
  const float* x       = (const float*)d_in[0];
  const float* context = (const float*)d_in[1];
  const int*   mask    = (const int*)d_in[2];
  const float* ln_w    = (const float*)d_in[3];
  const float* ln_b    = (const float*)d_in[4];
  const float* Wq      = (const float*)d_in[5];
  const float* Wk      = (const float*)d_in[6];
  const float* Wv      = (const float*)d_in[7];
  const float* Wo      = (const float*)d_in[8];
  const float* Wctx    = (const float*)d_in[9];

  char* wsb = (char*)d_ws;
  ushort* qb    = (ushort*)(wsb + 0);          // 16384x512 bf16
  ushort* kb    = (ushort*)(wsb + 16777216);   //  8192x512
  ushort* vb    = (ushort*)(wsb + 25165824);   //  8192x512
  ushort* atto  = (ushort*)(wsb + 33554432);   // 16384x512 (attn out)
  ushort* ctx   = (ushort*)(wsb + 50331648);   //  8192x512
  ushort* wctxb = (ushort*)(wsb + 58720256);   //   512x768
  ushort* wqb   = (ushort*)(wsb + 59506688);   //   512x512 each
  ushort* wkb   = (ushort*)(wsb + 60030976);
  ushort* wvb   = (ushort*)(wsb + 60555264);
  ushort* wob   = (ushort*)(wsb + 61079552);
  float*  mub   = (float*)(wsb + 61603840);    // 16384 f32
  float*  rsb   = (float*)(wsb + 61669376);    // 16384 f32

  cast5_kernel<<<1408, 256, 0, stream>>>(Wctx, Wq, Wk, Wv, Wo,
                                         wctxb, wqb, wkb, wvb, wob);
  ln_stats<<<dim3(B_, N_ / 64), 1024, 0, stream>>>(x, mub, rsb);
  // ctx = context @ Wctx^T, fp32 A converted in staging
  gemm_ctx<<<dim3(64, 4), 256, 0, stream>>>(context, wctxb, ctx);
  // k,v fused (512 blocks = 2/CU), global_load_lds staging
  gemm_kv<<<dim3(64, 8), 256, 0, stream>>>(ctx, wkb, wvb, kb, vb);
  // q = LN(x) @ Wq^T, LN fused into staging (no hn round-trip)
  gemm_lnq<<<dim3(128, 4), 256, 0, stream>>>(x, mub, rsb, ln_w, ln_b, wqb, qb);
  attn_mfma<<<dim3(N_ / 128, NH_, B_), 256, 0, stream>>>(qb, kb, vb, mask, atto);
  // out = transpose(atto @ Wo^T) + x, fused epilogue, global_load_lds staging
  gemm_res<<<dim3(128, 4), 256, 0, stream>>>(atto, wob, x, (float*)d_out);
}

// Round 15
// 167.009 us; speedup vs baseline: 6.4204x; 1.0230x over previous
//
#include <hip/hip_runtime.h>

// Problem constants
#define B_   16
#define C_   512
#define N_   1024   // H*W
#define L_   512
#define CTX_ 768
#define NH_  8
#define HD_  64
#define EPS_ 1e-5f

typedef short bfrag  __attribute__((ext_vector_type(8)));  // 8 x bf16 bits
typedef short bfrag4 __attribute__((ext_vector_type(4)));  // 4 x bf16 bits
typedef float f32x4  __attribute__((ext_vector_type(4)));

// manual RNE f32->bf16 (finite inputs); measured equal to native (r10).
__device__ __forceinline__ ushort f2bf(float f) {
  union { float f; unsigned u; } v; v.f = f;
  unsigned r = v.u + 0x7fffu + ((v.u >> 16) & 1u);
  return (ushort)(r >> 16);
}

__device__ __forceinline__ f32x4 mfma16(bfrag a, bfrag b, f32x4 c) {
  return __builtin_amdgcn_mfma_f32_16x16x32_bf16(a, b, c, 0, 0, 0);
}
__device__ __forceinline__ f32x4 mfma16k16(bfrag4 a, bfrag4 b, f32x4 c) {
  return __builtin_amdgcn_mfma_f32_16x16x16bf16_1k(a, b, c, 0, 0, 0);
}
// pack 2 f32 -> 1 dword of 2 bf16 (lo in [15:0], hi in [31:16]), RNE
__device__ __forceinline__ unsigned cvt_pk_bf16(float lo, float hi) {
  unsigned d;
  asm("v_cvt_pk_bf16_f32 %0, %1, %2" : "=v"(d) : "v"(lo), "v"(hi));
  return d;
}

// async global->LDS, 16B/lane. dst must be wave-uniform base + lane*16.
__device__ __forceinline__ void g2l16(const ushort* g, ushort* l) {
  __builtin_amdgcn_global_load_lds(
      (const __attribute__((address_space(1))) void*)g,
      (__attribute__((address_space(3))) void*)l, 16, 0, 0);
}

// ---------------------------------------------------------------------------
// fused weight casts: Wctx (98304 f4) + Wq/Wk/Wv/Wo (65536 f4 each), ONE launch
// ---------------------------------------------------------------------------
__global__ __launch_bounds__(256) void cast5_kernel(
    const float* __restrict__ s0, const float* __restrict__ s1,
    const float* __restrict__ s2, const float* __restrict__ s3,
    const float* __restrict__ s4,
    ushort* __restrict__ d0, ushort* __restrict__ d1, ushort* __restrict__ d2,
    ushort* __restrict__ d3, ushort* __restrict__ d4) {
  int i = blockIdx.x * 256 + threadIdx.x;   // float4 index, total 360448
  const float* src; ushort* dst; int off;
  if      (i < 98304)  { src = s0; dst = d0; off = i; }
  else if (i < 163840) { src = s1; dst = d1; off = i - 98304; }
  else if (i < 229376) { src = s2; dst = d2; off = i - 163840; }
  else if (i < 294912) { src = s3; dst = d3; off = i - 229376; }
  else                 { src = s4; dst = d4; off = i - 294912; }
  float4 vv = ((const float4*)src)[off];
  ushort4 o;
  o.x = f2bf(vv.x); o.y = f2bf(vv.y); o.z = f2bf(vv.z); o.w = f2bf(vv.w);
  ((ushort4*)dst)[off] = o;
}

// ---------------------------------------------------------------------------
// LN stats only: mean/rstd per (b,n). LN application fused into gemm_lnq.
// ---------------------------------------------------------------------------
__global__ __launch_bounds__(1024) void ln_stats(const float* __restrict__ x,
                                                 float* __restrict__ mu_out,
                                                 float* __restrict__ rs_out) {
  const int b  = blockIdx.x;
  const int n0 = blockIdx.y * 64;
  const int tid = threadIdx.x;
  const int nx = tid & 63, cg = tid >> 6;   // cg 0..15
  const float* xb = x + (size_t)b * C_ * N_;

  float s = 0.f, s2 = 0.f;
  for (int c = cg; c < C_; c += 16) {
    float v = xb[(size_t)c * N_ + n0 + nx];
    s += v; s2 += v * v;
  }
  __shared__ float red[2][16][64];
  red[0][cg][nx] = s; red[1][cg][nx] = s2;
  __syncthreads();
  if (cg == 0) {
    float ss = 0.f, ss2 = 0.f;
#pragma unroll
    for (int i = 0; i < 16; ++i) { ss += red[0][i][nx]; ss2 += red[1][i][nx]; }
    float m  = ss * (1.f / C_);
    float var = ss2 * (1.f / C_) - m * m;
    mu_out[(size_t)b * N_ + n0 + nx] = m;
    rs_out[(size_t)b * N_ + n0 + nx] = rsqrtf(var + EPS_);
  }
}

// ---------------------------------------------------------------------------
// Shared GEMM core (bf16 inputs): 128x128x32 tile, 4 waves, 4x4 frags.
// global_load_lds width-16 staging into LINEAR [128][32] LDS, XOR-swizzled
// source/read quad (both-sides involution).
// ---------------------------------------------------------------------------
__device__ __forceinline__ void gemm_core(const ushort* __restrict__ A,
                                          const ushort* __restrict__ W,
                                          int K, ushort* la, ushort* lb,
                                          f32x4 acc[4][4],
                                          int tid, int wm, int we, int col, int rg) {
  const int lane = tid & 63, w = tid >> 6;
  const int rloc = lane >> 2, pt = lane & 3;
  const int pts = pt ^ ((rloc >> 1) & 3);       // source quad pre-swizzle
  const int qsel = (rg ^ ((col >> 1) & 3)) * 8; // read quad select (ushorts)

  for (int k0 = 0; k0 < K; k0 += 32) {
#pragma unroll
    for (int c = 0; c < 2; ++c) {
      const int chunk = w + c * 4;              // 16-row chunk, wave-uniform
      const int row = chunk * 16 + rloc;
      g2l16(A + (size_t)row * K + k0 + pts * 8, la + chunk * 512);
      g2l16(W + (size_t)row * K + k0 + pts * 8, lb + chunk * 512);
    }
    __syncthreads();
    bfrag af[4], bf[4];
#pragma unroll
    for (int i = 0; i < 4; ++i) {
      af[i] = *(const bfrag*)&la[(wm + i * 16 + col) * 32 + qsel];
      bf[i] = *(const bfrag*)&lb[(we + i * 16 + col) * 32 + qsel];
    }
#pragma unroll
    for (int i = 0; i < 4; ++i)
#pragma unroll
      for (int j = 0; j < 4; ++j)
        acc[i][j] = mfma16(af[i], bf[j], acc[i][j]);
    __syncthreads();
  }
}

// fused K+V projection: blockIdx.y<4 -> K-proj, else V-proj (512 blocks total)
__global__ __launch_bounds__(256) void gemm_kv(const ushort* __restrict__ A,
                                               const ushort* __restrict__ Wk,
                                               const ushort* __restrict__ Wv,
                                               ushort* __restrict__ Ko,
                                               ushort* __restrict__ Vo) {
  __shared__ ushort la[128 * 32];
  __shared__ ushort lb[128 * 32];
  const int isv = blockIdx.y >> 2;
  const ushort* W = isv ? Wv : Wk;
  ushort* out = isv ? Vo : Ko;
  const int m0 = blockIdx.x * 128, e0 = (blockIdx.y & 3) * 128;
  const int tid = threadIdx.x, lane = tid & 63, w = tid >> 6;
  const int wm = (w >> 1) * 64, we = (w & 1) * 64;
  const int col = lane & 15, rg = lane >> 4;

  f32x4 acc[4][4] = {};
  gemm_core(A + (size_t)m0 * C_, W + (size_t)e0 * C_, C_, la, lb, acc, tid, wm, we, col, rg);

#pragma unroll
  for (int i = 0; i < 4; ++i)
#pragma unroll
    for (int j = 0; j < 4; ++j)
#pragma unroll
      for (int r = 0; r < 4; ++r)
        out[(size_t)(m0 + wm + i * 16 + rg * 4 + r) * 512 + e0 + we + j * 16 + col] =
            f2bf(acc[i][j][r]);
}

// o-projection + transposed residual epilogue: out[b][c][n] = (A@Wo^T)+x
__global__ __launch_bounds__(256) void gemm_res(const ushort* __restrict__ A,
                                                const ushort* __restrict__ W,
                                                const float* __restrict__ x,
                                                float* __restrict__ out) {
  __shared__ ushort la[128 * 32];
  __shared__ ushort lb[128 * 32];
  __shared__ float T[16][132];
  const int m0 = blockIdx.x * 128, e0 = blockIdx.y * 128;
  const int tid = threadIdx.x, lane = tid & 63, w = tid >> 6;
  const int wm = (w >> 1) * 64, we = (w & 1) * 64;
  const int col = lane & 15, rg = lane >> 4;

  f32x4 acc[4][4] = {};
  gemm_core(A + (size_t)m0 * C_, W + (size_t)e0 * C_, C_, la, lb, acc, tid, wm, we, col, rg);

  const int b = m0 >> 10, n0l = m0 & 1023;
#pragma unroll
  for (int g = 0; g < 8; ++g) {
    if ((w & 1) == (g >> 2)) {          // wave-uniform: we-half owns this group
      const int j = g & 3;
#pragma unroll
      for (int i = 0; i < 4; ++i)
        *(f32x4*)&T[col][wm + i * 16 + rg * 4] = acc[i][j];
    }
    __syncthreads();
    const int n = tid & 127;
    for (int cc = tid >> 7; cc < 16; cc += 2) {
      const int c = e0 + g * 16 + cc;
      const size_t idx = (size_t)b * C_ * N_ + (size_t)c * N_ + n0l + n;
      out[idx] = T[cc][n] + x[idx];
    }
    __syncthreads();
  }
}

// ---------------------------------------------------------------------------
// ctx projection: A fp32 (converted in-reg during staging), out bf16.
// ---------------------------------------------------------------------------
__global__ __launch_bounds__(256) void gemm_ctx(const float* __restrict__ Ap,
                                                const ushort* __restrict__ W,
                                                ushort* __restrict__ outp) {
  __shared__ ushort la[128 * 40];
  __shared__ ushort lb[128 * 40];
  const int m0 = blockIdx.x * 128, e0 = blockIdx.y * 128;
  const int tid = threadIdx.x, lane = tid & 63, w = tid >> 6;
  const int wm = (w >> 1) * 64, we = (w & 1) * 64;
  const int col = lane & 15, rg = lane >> 4;
  const int srow = tid >> 1, sh = (tid & 1) * 16;
  const int K = CTX_;

  f32x4 acc[4][4] = {};

  for (int k0 = 0; k0 < K; k0 += 32) {
    {
      const float* ap = &Ap[(size_t)(m0 + srow) * K + k0 + sh];
      float4 f0 = ((const float4*)ap)[0];
      float4 f1 = ((const float4*)ap)[1];
      float4 f2 = ((const float4*)ap)[2];
      float4 f3 = ((const float4*)ap)[3];
      union { int4 v; ushort u[8]; } p0, p1;
      p0.u[0] = f2bf(f0.x); p0.u[1] = f2bf(f0.y); p0.u[2] = f2bf(f0.z); p0.u[3] = f2bf(f0.w);
      p0.u[4] = f2bf(f1.x); p0.u[5] = f2bf(f1.y); p0.u[6] = f2bf(f1.z); p0.u[7] = f2bf(f1.w);
      p1.u[0] = f2bf(f2.x); p1.u[1] = f2bf(f2.y); p1.u[2] = f2bf(f2.z); p1.u[3] = f2bf(f2.w);
      p1.u[4] = f2bf(f3.x); p1.u[5] = f2bf(f3.y); p1.u[6] = f2bf(f3.z); p1.u[7] = f2bf(f3.w);
      *(int4*)&la[srow * 40 + sh]     = p0.v;
      *(int4*)&la[srow * 40 + sh + 8] = p1.v;
      const ushort* wp = &W[(size_t)(e0 + srow) * K + k0 + sh];
      *(int4*)&lb[srow * 40 + sh]     = *(const int4*)wp;
      *(int4*)&lb[srow * 40 + sh + 8] = *(const int4*)(wp + 8);
    }
    __syncthreads();
    bfrag af[4], bf[4];
#pragma unroll
    for (int i = 0; i < 4; ++i) {
      af[i] = *(const bfrag*)&la[(wm + i * 16 + col) * 40 + rg * 8];
      bf[i] = *(const bfrag*)&lb[(we + i * 16 + col) * 40 + rg * 8];
    }
#pragma unroll
    for (int i = 0; i < 4; ++i)
#pragma unroll
      for (int j = 0; j < 4; ++j)
        acc[i][j] = mfma16(af[i], bf[j], acc[i][j]);
    __syncthreads();
  }

#pragma unroll
  for (int i = 0; i < 4; ++i)
#pragma unroll
    for (int j = 0; j < 4; ++j)
#pragma unroll
      for (int r = 0; r < 4; ++r)
        outp[(size_t)(m0 + wm + i * 16 + rg * 4 + r) * 512 + e0 + we + j * 16 + col] =
            f2bf(acc[i][j][r]);
}

// ---------------------------------------------------------------------------
// q-projection with fused LayerNorm: A[m=(b,n)][k=c] = (x[b][c][n]-mu)*rs*w+b,
// staged straight from x (no hn round-trip).
// ---------------------------------------------------------------------------
__global__ __launch_bounds__(256) void gemm_lnq(const float* __restrict__ x,
                                                const float* __restrict__ mu,
                                                const float* __restrict__ rs,
                                                const float* __restrict__ lnw,
                                                const float* __restrict__ lnb,
                                                const ushort* __restrict__ W,
                                                ushort* __restrict__ out) {
  __shared__ ushort la[128 * 40];
  __shared__ ushort lb[128 * 40];
  const int m0 = blockIdx.x * 128, e0 = blockIdx.y * 128;
  const int b = m0 >> 10, n0l = m0 & 1023;
  const int tid = threadIdx.x, lane = tid & 63, w = tid >> 6;
  const int wm = (w >> 1) * 64, we = (w & 1) * 64;
  const int col = lane & 15, rg = lane >> 4;
  const int nloc = tid & 127, chalf = (tid >> 7) * 16;
  const int srow = tid >> 1, sh = (tid & 1) * 16;

  const float muv = mu[(size_t)b * N_ + n0l + nloc];
  const float rsv = rs[(size_t)b * N_ + n0l + nloc];
  const float nmr = -muv * rsv;   // t = fma(x, rsv, nmr)
  const float* xb = x + (size_t)b * C_ * N_ + n0l + nloc;

  f32x4 acc[4][4] = {};

  for (int k0 = 0; k0 < C_; k0 += 32) {
    {
      union { int4 v[2]; ushort u[16]; } pk;
#pragma unroll
      for (int i = 0; i < 16; ++i) {
        const int c = k0 + chalf + i;
        const float xv = xb[(size_t)c * N_];
        const float t = fmaf(xv, rsv, nmr);
        pk.u[i] = f2bf(fmaf(t, lnw[c], lnb[c]));
      }
      *(int4*)&la[nloc * 40 + chalf]     = pk.v[0];
      *(int4*)&la[nloc * 40 + chalf + 8] = pk.v[1];
      const ushort* wp = &W[(size_t)(e0 + srow) * C_ + k0 + sh];
      *(int4*)&lb[srow * 40 + sh]     = *(const int4*)wp;
      *(int4*)&lb[srow * 40 + sh + 8] = *(const int4*)(wp + 8);
    }
    __syncthreads();
    bfrag af[4], bf[4];
#pragma unroll
    for (int i = 0; i < 4; ++i) {
      af[i] = *(const bfrag*)&la[(wm + i * 16 + col) * 40 + rg * 8];
      bf[i] = *(const bfrag*)&lb[(we + i * 16 + col) * 40 + rg * 8];
    }
#pragma unroll
    for (int i = 0; i < 4; ++i)
#pragma unroll
      for (int j = 0; j < 4; ++j)
        acc[i][j] = mfma16(af[i], bf[j], acc[i][j]);
    __syncthreads();
  }

#pragma unroll
  for (int i = 0; i < 4; ++i)
#pragma unroll
    for (int j = 0; j < 4; ++j)
#pragma unroll
      for (int r = 0; r < 4; ++r)
        out[(size_t)(m0 + wm + i * 16 + rg * 4 + r) * 512 + e0 + we + j * 16 + col] =
            f2bf(acc[i][j][r]);
}

// ---------------------------------------------------------------------------
// MFMA flash cross-attention (swapped QK^T, P in registers). Round-14:
// DOUBLE-BUFFERED K/V/mask (T14 async-STAGE): per tile, issue next-tile
// global loads into REGISTERS before compute (no vmem in compute section ->
// loads fly under QK^T/exp/PV), write regs->other LDS buf after compute,
// ONE barrier per tile (was 2). Compute body byte-identical to r11/r13.
// ---------------------------------------------------------------------------
__global__ __launch_bounds__(256) void attn_mfma(const ushort* __restrict__ q,
                                                 const ushort* __restrict__ k,
                                                 const ushort* __restrict__ v,
                                                 const int* __restrict__ mask,
                                                 ushort* __restrict__ o) {
  __shared__ ushort Kl[2][64 * 72];   // [buf][key][72]
  __shared__ ushort Vt[2][64 * 72];   // [buf][d][72]
  __shared__ float mlb[2][64];

  const int h = blockIdx.y, b = blockIdx.z;
  const int q0 = blockIdx.x * 128;
  const int tid = threadIdx.x, lane = tid & 63, w = tid >> 6;
  const int col = lane & 15, rg = lane >> 4;
  const int wq = w * 32;
  const float C1 = 0.18033688011112042f;  // 0.125 * log2(e)

  bfrag qf[2][2];
#pragma unroll
  for (int mi = 0; mi < 2; ++mi)
#pragma unroll
    for (int kc = 0; kc < 2; ++kc)
      qf[mi][kc] = *(const bfrag*)
          &q[((size_t)b * N_ + q0 + wq + mi * 16 + col) * C_ + h * HD_ + kc * 32 + rg * 8];

  f32x4 oa[2][4] = {};
  float l_part[2] = {0.f, 0.f};   // per-lane denominator for q = col

  // prologue: stage tile 0 into buf 0 (direct global->LDS, as r13)
  {
#pragma unroll
    for (int it = 0; it < 2; ++it) {
      const int idx = it * 256 + tid;
      const int key = idx >> 3, part = idx & 7;
      *(int4*)&Kl[0][key * 72 + part * 8] =
          *(const int4*)&k[((size_t)b * L_ + key) * C_ + h * HD_ + part * 8];
    }
#pragma unroll
    for (int it = 0; it < 4; ++it) {
      const int idx = it * 256 + tid;
      const int key = idx & 63, d0 = (idx >> 6) * 4;
      ushort4 vv = *(const ushort4*)&v[((size_t)b * L_ + key) * C_ + h * HD_ + d0];
      Vt[0][(d0 + 0) * 72 + key] = vv.x;
      Vt[0][(d0 + 1) * 72 + key] = vv.y;
      Vt[0][(d0 + 2) * 72 + key] = vv.z;
      Vt[0][(d0 + 3) * 72 + key] = vv.w;
    }
    if (tid < 64) mlb[0][tid] = mask[b * L_ + tid] ? 0.f : -1e30f;
  }
  __syncthreads();

  for (int t = 0; t < 8; ++t) {
    const int cur = t & 1;
    // issue next-tile loads into registers (retire at the write phase)
    int4 kreg[2];
    ushort4 vreg[4];
    float mreg = 0.f;
    if (t < 7) {
      const int l0n = (t + 1) * 64;
#pragma unroll
      for (int it = 0; it < 2; ++it) {
        const int idx = it * 256 + tid;
        const int key = idx >> 3, part = idx & 7;
        kreg[it] = *(const int4*)&k[((size_t)b * L_ + l0n + key) * C_ + h * HD_ + part * 8];
      }
#pragma unroll
      for (int it = 0; it < 4; ++it) {
        const int idx = it * 256 + tid;
        const int key = idx & 63, d0 = (idx >> 6) * 4;
        vreg[it] = *(const ushort4*)&v[((size_t)b * L_ + l0n + key) * C_ + h * HD_ + d0];
      }
      if (tid < 64) mreg = mask[b * L_ + l0n + tid] ? 0.f : -1e30f;
    }

    // ---- compute on buf cur (body identical to r11/r13) ----
    const ushort* Kc = &Kl[cur][0];
    const ushort* Vc = &Vt[cur][0];
    f32x4 s2[2][4] = {};
#pragma unroll
    for (int kc = 0; kc < 2; ++kc) {
      bfrag kf[4];
#pragma unroll
      for (int ni = 0; ni < 4; ++ni)
        kf[ni] = *(const bfrag*)&Kc[(ni * 16 + col) * 72 + kc * 32 + rg * 8];
#pragma unroll
      for (int mi = 0; mi < 2; ++mi)
#pragma unroll
        for (int ni = 0; ni < 4; ++ni)
          s2[mi][ni] = mfma16(kf[ni], qf[mi][kc], s2[mi][ni]);
    }
    bfrag4 pf[2][4];
#pragma unroll
    for (int ni = 0; ni < 4; ++ni) {
      const f32x4 bias4 = *(const f32x4*)&mlb[cur][ni * 16 + rg * 4];
#pragma unroll
      for (int mi = 0; mi < 2; ++mi) {
        const float p0 = exp2f(fmaf(s2[mi][ni][0], C1, bias4[0]));
        const float p1 = exp2f(fmaf(s2[mi][ni][1], C1, bias4[1]));
        const float p2 = exp2f(fmaf(s2[mi][ni][2], C1, bias4[2]));
        const float p3 = exp2f(fmaf(s2[mi][ni][3], C1, bias4[3]));
        l_part[mi] += (p0 + p1) + (p2 + p3);
        union { bfrag4 v; unsigned u[2]; } pk;
        pk.u[0] = cvt_pk_bf16(p0, p1);
        pk.u[1] = cvt_pk_bf16(p2, p3);
        pf[mi][ni] = pk.v;
      }
    }
#pragma unroll
    for (int ni = 0; ni < 4; ++ni) {
      bfrag4 vf[4];
#pragma unroll
      for (int di = 0; di < 4; ++di)
        vf[di] = *(const bfrag4*)&Vc[(di * 16 + col) * 72 + ni * 16 + rg * 4];
#pragma unroll
      for (int mi = 0; mi < 2; ++mi)
#pragma unroll
        for (int di = 0; di < 4; ++di)
          oa[mi][di] = mfma16k16(pf[mi][ni], vf[di], oa[mi][di]);
    }

    // ---- write next tile into the other buffer ----
    if (t < 7) {
      const int nb = cur ^ 1;
#pragma unroll
      for (int it = 0; it < 2; ++it) {
        const int idx = it * 256 + tid;
        const int key = idx >> 3, part = idx & 7;
        *(int4*)&Kl[nb][key * 72 + part * 8] = kreg[it];
      }
#pragma unroll
      for (int it = 0; it < 4; ++it) {
        const int idx = it * 256 + tid;
        const int key = idx & 63, d0 = (idx >> 6) * 4;
        Vt[nb][(d0 + 0) * 72 + key] = vreg[it].x;
        Vt[nb][(d0 + 1) * 72 + key] = vreg[it].y;
        Vt[nb][(d0 + 2) * 72 + key] = vreg[it].z;
        Vt[nb][(d0 + 3) * 72 + key] = vreg[it].w;
      }
      if (tid < 64) mlb[nb][tid] = mreg;
    }
    __syncthreads();   // one barrier per tile: readers done + next buf ready
  }

  // denominator: reduce across rg groups, bpermute 1/l to row layout
  float linv[2][4];
#pragma unroll
  for (int mi = 0; mi < 2; ++mi) {
    float l = l_part[mi];
    l += __shfl_xor(l, 16);
    l += __shfl_xor(l, 32);
#pragma unroll
    for (int r = 0; r < 4; ++r) {
      int lv = __builtin_amdgcn_ds_bpermute((rg * 4 + r) * 4, __float_as_int(l));
      linv[mi][r] = 1.f / __int_as_float(lv);
    }
  }
#pragma unroll
  for (int mi = 0; mi < 2; ++mi)
#pragma unroll
    for (int r = 0; r < 4; ++r) {
      const size_t row = (size_t)b * N_ + q0 + wq + mi * 16 + rg * 4 + r;
#pragma unroll
      for (int di = 0; di < 4; ++di)
        o[row * C_ + h * HD_ + di * 16 + col] = f2bf(oa[mi][di][r] * linv[mi][r]);
    }
}

// ---------------------------------------------------------------------------
// Launch
// ---------------------------------------------------------------------------
extern "C" void kernel_launch(void* const* d_in, const int* in_sizes, int n_in,
                              void* d_out, int out_size, void* d_ws, size_t ws_size,
                              hipStream_t stream) {
  (void)in_sizes; (void)n_in; (void)out_size; (void)ws_size;
  const float* x       = (const float*)d_in[0];
  const float* context = (const float*)d_in[1];
  const int*   mask    = (const int*)d_in[2];
  const float* ln_w    = (const float*)d_in[3];
  const float* ln_b    = (const float*)d_in[4];
  const float* Wq      = (const float*)d_in[5];
  const float* Wk      = (const float*)d_in[6];
  const float* Wv      = (const float*)d_in[7];
  const float* Wo      = (const float*)d_in[8];
  const float* Wctx    = (const float*)d_in[9];

  char* wsb = (char*)d_ws;
  ushort* qb    = (ushort*)(wsb + 0);          // 16384x512 bf16
  ushort* kb    = (ushort*)(wsb + 16777216);   //  8192x512
  ushort* vb    = (ushort*)(wsb + 25165824);   //  8192x512
  ushort* atto  = (ushort*)(wsb + 33554432);   // 16384x512 (attn out)
  ushort* ctx   = (ushort*)(wsb + 50331648);   //  8192x512
  ushort* wctxb = (ushort*)(wsb + 58720256);   //   512x768
  ushort* wqb   = (ushort*)(wsb + 59506688);   //   512x512 each
  ushort* wkb   = (ushort*)(wsb + 60030976);
  ushort* wvb   = (ushort*)(wsb + 60555264);
  ushort* wob   = (ushort*)(wsb + 61079552);
  float*  mub   = (float*)(wsb + 61603840);    // 16384 f32
  float*  rsb   = (float*)(wsb + 61669376);    // 16384 f32

  cast5_kernel<<<1408, 256, 0, stream>>>(Wctx, Wq, Wk, Wv, Wo,
                                         wctxb, wqb, wkb, wvb, wob);
  ln_stats<<<dim3(B_, N_ / 64), 1024, 0, stream>>>(x, mub, rsb);
  // ctx = context @ Wctx^T, fp32 A converted in staging
  gemm_ctx<<<dim3(64, 4), 256, 0, stream>>>(context, wctxb, ctx);
  // k,v fused (512 blocks = 2/CU), global_load_lds staging
  gemm_kv<<<dim3(64, 8), 256, 0, stream>>>(ctx, wkb, wvb, kb, vb);
  // q = LN(x) @ Wq^T, LN fused into staging (no hn round-trip)
  gemm_lnq<<<dim3(128, 4), 256, 0, stream>>>(x, mub, rsb, ln_w, ln_b, wqb, qb);
  attn_mfma<<<dim3(N_ / 128, NH_, B_), 256, 0, stream>>>(qb, kb, vb, mask, atto);
  // out = transpose(atto @ Wo^T) + x, fused epilogue, global_load_lds staging
  gemm_res<<<dim3(128, 4), 256, 0, stream>>>(atto, wob, x, (float*)d_out);
}

// Round 16
// 163.792 us; speedup vs baseline: 6.5465x; 1.0196x over previous
//
#include <hip/hip_runtime.h>

// Problem constants
#define B_   16
#define C_   512
#define N_   1024   // H*W
#define L_   512
#define CTX_ 768
#define NH_  8
#define HD_  64
#define EPS_ 1e-5f

typedef short bfrag  __attribute__((ext_vector_type(8)));  // 8 x bf16 bits
typedef short bfrag4 __attribute__((ext_vector_type(4)));  // 4 x bf16 bits
typedef float f32x4  __attribute__((ext_vector_type(4)));

// manual RNE f32->bf16 (finite inputs); measured equal to native (r10).
__device__ __forceinline__ ushort f2bf(float f) {
  union { float f; unsigned u; } v; v.f = f;
  unsigned r = v.u + 0x7fffu + ((v.u >> 16) & 1u);
  return (ushort)(r >> 16);
}

__device__ __forceinline__ f32x4 mfma16(bfrag a, bfrag b, f32x4 c) {
  return __builtin_amdgcn_mfma_f32_16x16x32_bf16(a, b, c, 0, 0, 0);
}
__device__ __forceinline__ f32x4 mfma16k16(bfrag4 a, bfrag4 b, f32x4 c) {
  return __builtin_amdgcn_mfma_f32_16x16x16bf16_1k(a, b, c, 0, 0, 0);
}
// pack 2 f32 -> 1 dword of 2 bf16 (lo in [15:0], hi in [31:16]), RNE
__device__ __forceinline__ unsigned cvt_pk_bf16(float lo, float hi) {
  unsigned d;
  asm("v_cvt_pk_bf16_f32 %0, %1, %2" : "=v"(d) : "v"(lo), "v"(hi));
  return d;
}

// async global->LDS, 16B/lane. dst must be wave-uniform base + lane*16.
__device__ __forceinline__ void g2l16(const ushort* g, ushort* l) {
  __builtin_amdgcn_global_load_lds(
      (const __attribute__((address_space(1))) void*)g,
      (__attribute__((address_space(3))) void*)l, 16, 0, 0);
}

// ---------------------------------------------------------------------------
// fused weight casts: Wctx (98304 f4) + Wq/Wk/Wv/Wo (65536 f4 each), ONE launch
// ---------------------------------------------------------------------------
__global__ __launch_bounds__(256) void cast5_kernel(
    const float* __restrict__ s0, const float* __restrict__ s1,
    const float* __restrict__ s2, const float* __restrict__ s3,
    const float* __restrict__ s4,
    ushort* __restrict__ d0, ushort* __restrict__ d1, ushort* __restrict__ d2,
    ushort* __restrict__ d3, ushort* __restrict__ d4) {
  int i = blockIdx.x * 256 + threadIdx.x;   // float4 index, total 360448
  const float* src; ushort* dst; int off;
  if      (i < 98304)  { src = s0; dst = d0; off = i; }
  else if (i < 163840) { src = s1; dst = d1; off = i - 98304; }
  else if (i < 229376) { src = s2; dst = d2; off = i - 163840; }
  else if (i < 294912) { src = s3; dst = d3; off = i - 229376; }
  else                 { src = s4; dst = d4; off = i - 294912; }
  float4 vv = ((const float4*)src)[off];
  ushort4 o;
  o.x = f2bf(vv.x); o.y = f2bf(vv.y); o.z = f2bf(vv.z); o.w = f2bf(vv.w);
  ((ushort4*)dst)[off] = o;
}

// ---------------------------------------------------------------------------
// LN stats only: mean/rstd per (b,n). LN application fused into gemm_lnq.
// ---------------------------------------------------------------------------
__global__ __launch_bounds__(1024) void ln_stats(const float* __restrict__ x,
                                                 float* __restrict__ mu_out,
                                                 float* __restrict__ rs_out) {
  const int b  = blockIdx.x;
  const int n0 = blockIdx.y * 64;
  const int tid = threadIdx.x;
  const int nx = tid & 63, cg = tid >> 6;   // cg 0..15
  const float* xb = x + (size_t)b * C_ * N_;

  float s = 0.f, s2 = 0.f;
  for (int c = cg; c < C_; c += 16) {
    float v = xb[(size_t)c * N_ + n0 + nx];
    s += v; s2 += v * v;
  }
  __shared__ float red[2][16][64];
  red[0][cg][nx] = s; red[1][cg][nx] = s2;
  __syncthreads();
  if (cg == 0) {
    float ss = 0.f, ss2 = 0.f;
#pragma unroll
    for (int i = 0; i < 16; ++i) { ss += red[0][i][nx]; ss2 += red[1][i][nx]; }
    float m  = ss * (1.f / C_);
    float var = ss2 * (1.f / C_) - m * m;
    mu_out[(size_t)b * N_ + n0 + nx] = m;
    rs_out[(size_t)b * N_ + n0 + nx] = rsqrtf(var + EPS_);
  }
}

// ---------------------------------------------------------------------------
// Shared GEMM core (bf16 inputs): 128x128x32 tile, 4 waves, 4x4 frags.
// global_load_lds width-16 staging into LINEAR [128][32] LDS, XOR-swizzled
// source/read quad (both-sides involution).
// ---------------------------------------------------------------------------
__device__ __forceinline__ void gemm_core(const ushort* __restrict__ A,
                                          const ushort* __restrict__ W,
                                          int K, ushort* la, ushort* lb,
                                          f32x4 acc[4][4],
                                          int tid, int wm, int we, int col, int rg) {
  const int lane = tid & 63, w = tid >> 6;
  const int rloc = lane >> 2, pt = lane & 3;
  const int pts = pt ^ ((rloc >> 1) & 3);       // source quad pre-swizzle
  const int qsel = (rg ^ ((col >> 1) & 3)) * 8; // read quad select (ushorts)

  for (int k0 = 0; k0 < K; k0 += 32) {
#pragma unroll
    for (int c = 0; c < 2; ++c) {
      const int chunk = w + c * 4;              // 16-row chunk, wave-uniform
      const int row = chunk * 16 + rloc;
      g2l16(A + (size_t)row * K + k0 + pts * 8, la + chunk * 512);
      g2l16(W + (size_t)row * K + k0 + pts * 8, lb + chunk * 512);
    }
    __syncthreads();
    bfrag af[4], bf[4];
#pragma unroll
    for (int i = 0; i < 4; ++i) {
      af[i] = *(const bfrag*)&la[(wm + i * 16 + col) * 32 + qsel];
      bf[i] = *(const bfrag*)&lb[(we + i * 16 + col) * 32 + qsel];
    }
#pragma unroll
    for (int i = 0; i < 4; ++i)
#pragma unroll
      for (int j = 0; j < 4; ++j)
        acc[i][j] = mfma16(af[i], bf[j], acc[i][j]);
    __syncthreads();
  }
}

// fused K+V projection: blockIdx.y<4 -> K-proj, else V-proj (512 blocks total)
__global__ __launch_bounds__(256) void gemm_kv(const ushort* __restrict__ A,
                                               const ushort* __restrict__ Wk,
                                               const ushort* __restrict__ Wv,
                                               ushort* __restrict__ Ko,
                                               ushort* __restrict__ Vo) {
  __shared__ ushort la[128 * 32];
  __shared__ ushort lb[128 * 32];
  const int isv = blockIdx.y >> 2;
  const ushort* W = isv ? Wv : Wk;
  ushort* out = isv ? Vo : Ko;
  const int m0 = blockIdx.x * 128, e0 = (blockIdx.y & 3) * 128;
  const int tid = threadIdx.x, lane = tid & 63, w = tid >> 6;
  const int wm = (w >> 1) * 64, we = (w & 1) * 64;
  const int col = lane & 15, rg = lane >> 4;

  f32x4 acc[4][4] = {};
  gemm_core(A + (size_t)m0 * C_, W + (size_t)e0 * C_, C_, la, lb, acc, tid, wm, we, col, rg);

#pragma unroll
  for (int i = 0; i < 4; ++i)
#pragma unroll
    for (int j = 0; j < 4; ++j)
#pragma unroll
      for (int r = 0; r < 4; ++r)
        out[(size_t)(m0 + wm + i * 16 + rg * 4 + r) * 512 + e0 + we + j * 16 + col] =
            f2bf(acc[i][j][r]);
}

// o-projection + transposed residual epilogue: out[b][c][n] = (A@Wo^T)+x
__global__ __launch_bounds__(256) void gemm_res(const ushort* __restrict__ A,
                                                const ushort* __restrict__ W,
                                                const float* __restrict__ x,
                                                float* __restrict__ out) {
  __shared__ ushort la[128 * 32];
  __shared__ ushort lb[128 * 32];
  __shared__ float T[16][132];
  const int m0 = blockIdx.x * 128, e0 = blockIdx.y * 128;
  const int tid = threadIdx.x, lane = tid & 63, w = tid >> 6;
  const int wm = (w >> 1) * 64, we = (w & 1) * 64;
  const int col = lane & 15, rg = lane >> 4;

  f32x4 acc[4][4] = {};
  gemm_core(A + (size_t)m0 * C_, W + (size_t)e0 * C_, C_, la, lb, acc, tid, wm, we, col, rg);

  const int b = m0 >> 10, n0l = m0 & 1023;
#pragma unroll
  for (int g = 0; g < 8; ++g) {
    if ((w & 1) == (g >> 2)) {          // wave-uniform: we-half owns this group
      const int j = g & 3;
#pragma unroll
      for (int i = 0; i < 4; ++i)
        *(f32x4*)&T[col][wm + i * 16 + rg * 4] = acc[i][j];
    }
    __syncthreads();
    const int n = tid & 127;
    for (int cc = tid >> 7; cc < 16; cc += 2) {
      const int c = e0 + g * 16 + cc;
      const size_t idx = (size_t)b * C_ * N_ + (size_t)c * N_ + n0l + n;
      out[idx] = T[cc][n] + x[idx];
    }
    __syncthreads();
  }
}

// ---------------------------------------------------------------------------
// ctx projection: A fp32 (converted in-reg during staging), out bf16.
// ---------------------------------------------------------------------------
__global__ __launch_bounds__(256) void gemm_ctx(const float* __restrict__ Ap,
                                                const ushort* __restrict__ W,
                                                ushort* __restrict__ outp) {
  __shared__ ushort la[128 * 40];
  __shared__ ushort lb[128 * 40];
  const int m0 = blockIdx.x * 128, e0 = blockIdx.y * 128;
  const int tid = threadIdx.x, lane = tid & 63, w = tid >> 6;
  const int wm = (w >> 1) * 64, we = (w & 1) * 64;
  const int col = lane & 15, rg = lane >> 4;
  const int srow = tid >> 1, sh = (tid & 1) * 16;
  const int K = CTX_;

  f32x4 acc[4][4] = {};

  for (int k0 = 0; k0 < K; k0 += 32) {
    {
      const float* ap = &Ap[(size_t)(m0 + srow) * K + k0 + sh];
      float4 f0 = ((const float4*)ap)[0];
      float4 f1 = ((const float4*)ap)[1];
      float4 f2 = ((const float4*)ap)[2];
      float4 f3 = ((const float4*)ap)[3];
      union { int4 v; ushort u[8]; } p0, p1;
      p0.u[0] = f2bf(f0.x); p0.u[1] = f2bf(f0.y); p0.u[2] = f2bf(f0.z); p0.u[3] = f2bf(f0.w);
      p0.u[4] = f2bf(f1.x); p0.u[5] = f2bf(f1.y); p0.u[6] = f2bf(f1.z); p0.u[7] = f2bf(f1.w);
      p1.u[0] = f2bf(f2.x); p1.u[1] = f2bf(f2.y); p1.u[2] = f2bf(f2.z); p1.u[3] = f2bf(f2.w);
      p1.u[4] = f2bf(f3.x); p1.u[5] = f2bf(f3.y); p1.u[6] = f2bf(f3.z); p1.u[7] = f2bf(f3.w);
      *(int4*)&la[srow * 40 + sh]     = p0.v;
      *(int4*)&la[srow * 40 + sh + 8] = p1.v;
      const ushort* wp = &W[(size_t)(e0 + srow) * K + k0 + sh];
      *(int4*)&lb[srow * 40 + sh]     = *(const int4*)wp;
      *(int4*)&lb[srow * 40 + sh + 8] = *(const int4*)(wp + 8);
    }
    __syncthreads();
    bfrag af[4], bf[4];
#pragma unroll
    for (int i = 0; i < 4; ++i) {
      af[i] = *(const bfrag*)&la[(wm + i * 16 + col) * 40 + rg * 8];
      bf[i] = *(const bfrag*)&lb[(we + i * 16 + col) * 40 + rg * 8];
    }
#pragma unroll
    for (int i = 0; i < 4; ++i)
#pragma unroll
      for (int j = 0; j < 4; ++j)
        acc[i][j] = mfma16(af[i], bf[j], acc[i][j]);
    __syncthreads();
  }

#pragma unroll
  for (int i = 0; i < 4; ++i)
#pragma unroll
    for (int j = 0; j < 4; ++j)
#pragma unroll
      for (int r = 0; r < 4; ++r)
        outp[(size_t)(m0 + wm + i * 16 + rg * 4 + r) * 512 + e0 + we + j * 16 + col] =
            f2bf(acc[i][j][r]);
}

// ---------------------------------------------------------------------------
// q-projection with fused LayerNorm: A[m=(b,n)][k=c] = (x[b][c][n]-mu)*rs*w+b,
// staged straight from x (no hn round-trip).
// ---------------------------------------------------------------------------
__global__ __launch_bounds__(256) void gemm_lnq(const float* __restrict__ x,
                                                const float* __restrict__ mu,
                                                const float* __restrict__ rs,
                                                const float* __restrict__ lnw,
                                                const float* __restrict__ lnb,
                                                const ushort* __restrict__ W,
                                                ushort* __restrict__ out) {
  __shared__ ushort la[128 * 40];
  __shared__ ushort lb[128 * 40];
  const int m0 = blockIdx.x * 128, e0 = blockIdx.y * 128;
  const int b = m0 >> 10, n0l = m0 & 1023;
  const int tid = threadIdx.x, lane = tid & 63, w = tid >> 6;
  const int wm = (w >> 1) * 64, we = (w & 1) * 64;
  const int col = lane & 15, rg = lane >> 4;
  const int nloc = tid & 127, chalf = (tid >> 7) * 16;
  const int srow = tid >> 1, sh = (tid & 1) * 16;

  const float muv = mu[(size_t)b * N_ + n0l + nloc];
  const float rsv = rs[(size_t)b * N_ + n0l + nloc];
  const float nmr = -muv * rsv;   // t = fma(x, rsv, nmr)
  const float* xb = x + (size_t)b * C_ * N_ + n0l + nloc;

  f32x4 acc[4][4] = {};

  for (int k0 = 0; k0 < C_; k0 += 32) {
    {
      union { int4 v[2]; ushort u[16]; } pk;
#pragma unroll
      for (int i = 0; i < 16; ++i) {
        const int c = k0 + chalf + i;
        const float xv = xb[(size_t)c * N_];
        const float t = fmaf(xv, rsv, nmr);
        pk.u[i] = f2bf(fmaf(t, lnw[c], lnb[c]));
      }
      *(int4*)&la[nloc * 40 + chalf]     = pk.v[0];
      *(int4*)&la[nloc * 40 + chalf + 8] = pk.v[1];
      const ushort* wp = &W[(size_t)(e0 + srow) * C_ + k0 + sh];
      *(int4*)&lb[srow * 40 + sh]     = *(const int4*)wp;
      *(int4*)&lb[srow * 40 + sh + 8] = *(const int4*)(wp + 8);
    }
    __syncthreads();
    bfrag af[4], bf[4];
#pragma unroll
    for (int i = 0; i < 4; ++i) {
      af[i] = *(const bfrag*)&la[(wm + i * 16 + col) * 40 + rg * 8];
      bf[i] = *(const bfrag*)&lb[(we + i * 16 + col) * 40 + rg * 8];
    }
#pragma unroll
    for (int i = 0; i < 4; ++i)
#pragma unroll
      for (int j = 0; j < 4; ++j)
        acc[i][j] = mfma16(af[i], bf[j], acc[i][j]);
    __syncthreads();
  }

#pragma unroll
  for (int i = 0; i < 4; ++i)
#pragma unroll
    for (int j = 0; j < 4; ++j)
#pragma unroll
      for (int r = 0; r < 4; ++r)
        out[(size_t)(m0 + wm + i * 16 + rg * 4 + r) * 512 + e0 + we + j * 16 + col] =
            f2bf(acc[i][j][r]);
}

// ---------------------------------------------------------------------------
// MFMA flash cross-attention (swapped QK^T, P in registers, double-buffered).
// Round-16: XCD-aware block swizzle (T1). r15 FETCH=74MB vs 32.5MB ideal:
// grid (8,8,16) put the 8 q-blocks sharing one (b,h)'s K/V on 8 DIFFERENT
// XCDs (consecutive linear ids round-robin). 1D grid + remap lin=qb*128+hb
// puts them on ONE XCD (lin mod 8 = hb mod 8 = h); per-XCD K/V set = 2MB
// fits the 4MB L2.
// ---------------------------------------------------------------------------
__global__ __launch_bounds__(256) void attn_mfma(const ushort* __restrict__ q,
                                                 const ushort* __restrict__ k,
                                                 const ushort* __restrict__ v,
                                                 const int* __restrict__ mask,
                                                 ushort* __restrict__ o) {
  __shared__ ushort Kl[2][64 * 72];   // [buf][key][72]
  __shared__ ushort Vt[2][64 * 72];   // [buf][d][72]
  __shared__ float mlb[2][64];

  const int lin = blockIdx.x;           // 0..1023
  const int hb = lin & 127, qb = lin >> 7;
  const int h = hb & 7, b = hb >> 3;
  const int q0 = qb * 128;
  const int tid = threadIdx.x, lane = tid & 63, w = tid >> 6;
  const int col = lane & 15, rg = lane >> 4;
  const int wq = w * 32;
  const float C1 = 0.18033688011112042f;  // 0.125 * log2(e)

  bfrag qf[2][2];
#pragma unroll
  for (int mi = 0; mi < 2; ++mi)
#pragma unroll
    for (int kc = 0; kc < 2; ++kc)
      qf[mi][kc] = *(const bfrag*)
          &q[((size_t)b * N_ + q0 + wq + mi * 16 + col) * C_ + h * HD_ + kc * 32 + rg * 8];

  f32x4 oa[2][4] = {};
  float l_part[2] = {0.f, 0.f};   // per-lane denominator for q = col

  // prologue: stage tile 0 into buf 0
  {
#pragma unroll
    for (int it = 0; it < 2; ++it) {
      const int idx = it * 256 + tid;
      const int key = idx >> 3, part = idx & 7;
      *(int4*)&Kl[0][key * 72 + part * 8] =
          *(const int4*)&k[((size_t)b * L_ + key) * C_ + h * HD_ + part * 8];
    }
#pragma unroll
    for (int it = 0; it < 4; ++it) {
      const int idx = it * 256 + tid;
      const int key = idx & 63, d0 = (idx >> 6) * 4;
      ushort4 vv = *(const ushort4*)&v[((size_t)b * L_ + key) * C_ + h * HD_ + d0];
      Vt[0][(d0 + 0) * 72 + key] = vv.x;
      Vt[0][(d0 + 1) * 72 + key] = vv.y;
      Vt[0][(d0 + 2) * 72 + key] = vv.z;
      Vt[0][(d0 + 3) * 72 + key] = vv.w;
    }
    if (tid < 64) mlb[0][tid] = mask[b * L_ + tid] ? 0.f : -1e30f;
  }
  __syncthreads();

  for (int t = 0; t < 8; ++t) {
    const int cur = t & 1;
    // issue next-tile loads into registers (retire at the write phase)
    int4 kreg[2];
    ushort4 vreg[4];
    float mreg = 0.f;
    if (t < 7) {
      const int l0n = (t + 1) * 64;
#pragma unroll
      for (int it = 0; it < 2; ++it) {
        const int idx = it * 256 + tid;
        const int key = idx >> 3, part = idx & 7;
        kreg[it] = *(const int4*)&k[((size_t)b * L_ + l0n + key) * C_ + h * HD_ + part * 8];
      }
#pragma unroll
      for (int it = 0; it < 4; ++it) {
        const int idx = it * 256 + tid;
        const int key = idx & 63, d0 = (idx >> 6) * 4;
        vreg[it] = *(const ushort4*)&v[((size_t)b * L_ + l0n + key) * C_ + h * HD_ + d0];
      }
      if (tid < 64) mreg = mask[b * L_ + l0n + tid] ? 0.f : -1e30f;
    }

    // ---- compute on buf cur ----
    const ushort* Kc = &Kl[cur][0];
    const ushort* Vc = &Vt[cur][0];
    f32x4 s2[2][4] = {};
#pragma unroll
    for (int kc = 0; kc < 2; ++kc) {
      bfrag kf[4];
#pragma unroll
      for (int ni = 0; ni < 4; ++ni)
        kf[ni] = *(const bfrag*)&Kc[(ni * 16 + col) * 72 + kc * 32 + rg * 8];
#pragma unroll
      for (int mi = 0; mi < 2; ++mi)
#pragma unroll
        for (int ni = 0; ni < 4; ++ni)
          s2[mi][ni] = mfma16(kf[ni], qf[mi][kc], s2[mi][ni]);
    }
    bfrag4 pf[2][4];
#pragma unroll
    for (int ni = 0; ni < 4; ++ni) {
      const f32x4 bias4 = *(const f32x4*)&mlb[cur][ni * 16 + rg * 4];
#pragma unroll
      for (int mi = 0; mi < 2; ++mi) {
        const float p0 = exp2f(fmaf(s2[mi][ni][0], C1, bias4[0]));
        const float p1 = exp2f(fmaf(s2[mi][ni][1], C1, bias4[1]));
        const float p2 = exp2f(fmaf(s2[mi][ni][2], C1, bias4[2]));
        const float p3 = exp2f(fmaf(s2[mi][ni][3], C1, bias4[3]));
        l_part[mi] += (p0 + p1) + (p2 + p3);
        union { bfrag4 v; unsigned u[2]; } pk;
        pk.u[0] = cvt_pk_bf16(p0, p1);
        pk.u[1] = cvt_pk_bf16(p2, p3);
        pf[mi][ni] = pk.v;
      }
    }
#pragma unroll
    for (int ni = 0; ni < 4; ++ni) {
      bfrag4 vf[4];
#pragma unroll
      for (int di = 0; di < 4; ++di)
        vf[di] = *(const bfrag4*)&Vc[(di * 16 + col) * 72 + ni * 16 + rg * 4];
#pragma unroll
      for (int mi = 0; mi < 2; ++mi)
#pragma unroll
        for (int di = 0; di < 4; ++di)
          oa[mi][di] = mfma16k16(pf[mi][ni], vf[di], oa[mi][di]);
    }

    // ---- write next tile into the other buffer ----
    if (t < 7) {
      const int nb = cur ^ 1;
#pragma unroll
      for (int it = 0; it < 2; ++it) {
        const int idx = it * 256 + tid;
        const int key = idx >> 3, part = idx & 7;
        *(int4*)&Kl[nb][key * 72 + part * 8] = kreg[it];
      }
#pragma unroll
      for (int it = 0; it < 4; ++it) {
        const int idx = it * 256 + tid;
        const int key = idx & 63, d0 = (idx >> 6) * 4;
        Vt[nb][(d0 + 0) * 72 + key] = vreg[it].x;
        Vt[nb][(d0 + 1) * 72 + key] = vreg[it].y;
        Vt[nb][(d0 + 2) * 72 + key] = vreg[it].z;
        Vt[nb][(d0 + 3) * 72 + key] = vreg[it].w;
      }
      if (tid < 64) mlb[nb][tid] = mreg;
    }
    __syncthreads();   // one barrier per tile: readers done + next buf ready
  }

  // denominator: reduce across rg groups, bpermute 1/l to row layout
  float linv[2][4];
#pragma unroll
  for (int mi = 0; mi < 2; ++mi) {
    float l = l_part[mi];
    l += __shfl_xor(l, 16);
    l += __shfl_xor(l, 32);
#pragma unroll
    for (int r = 0; r < 4; ++r) {
      int lv = __builtin_amdgcn_ds_bpermute((rg * 4 + r) * 4, __float_as_int(l));
      linv[mi][r] = 1.f / __int_as_float(lv);
    }
  }
#pragma unroll
  for (int mi = 0; mi < 2; ++mi)
#pragma unroll
    for (int r = 0; r < 4; ++r) {
      const size_t row = (size_t)b * N_ + q0 + wq + mi * 16 + rg * 4 + r;
#pragma unroll
      for (int di = 0; di < 4; ++di)
        o[row * C_ + h * HD_ + di * 16 + col] = f2bf(oa[mi][di][r] * linv[mi][r]);
    }
}

// ---------------------------------------------------------------------------
// Launch
// ---------------------------------------------------------------------------
extern "C" void kernel_launch(void* const* d_in, const int* in_sizes, int n_in,
                              void* d_out, int out_size, void* d_ws, size_t ws_size,
                              hipStream_t stream) {
  (void)in_sizes; (void)n_in; (void)out_size; (void)ws_size;
  const float* x       = (const float*)d_in[0];
  const float* context = (const float*)d_in[1];
  const int*   mask    = (const int*)d_in[2];
  const float* ln_w    = (const float*)d_in[3];
  const float* ln_b    = (const float*)d_in[4];
  const float* Wq      = (const float*)d_in[5];
  const float* Wk      = (const float*)d_in[6];
  const float* Wv      = (const float*)d_in[7];
  const float* Wo      = (const float*)d_in[8];
  const float* Wctx    = (const float*)d_in[9];

  char* wsb = (char*)d_ws;
  ushort* qb    = (ushort*)(wsb + 0);          // 16384x512 bf16
  ushort* kb    = (ushort*)(wsb + 16777216);   //  8192x512
  ushort* vb    = (ushort*)(wsb + 25165824);   //  8192x512
  ushort* atto  = (ushort*)(wsb + 33554432);   // 16384x512 (attn out)
  ushort* ctx   = (ushort*)(wsb + 50331648);   //  8192x512
  ushort* wctxb = (ushort*)(wsb + 58720256);   //   512x768
  ushort* wqb   = (ushort*)(wsb + 59506688);   //   512x512 each
  ushort* wkb   = (ushort*)(wsb + 60030976);
  ushort* wvb   = (ushort*)(wsb + 60555264);
  ushort* wob   = (ushort*)(wsb + 61079552);
  float*  mub   = (float*)(wsb + 61603840);    // 16384 f32
  float*  rsb   = (float*)(wsb + 61669376);    // 16384 f32

  cast5_kernel<<<1408, 256, 0, stream>>>(Wctx, Wq, Wk, Wv, Wo,
                                         wctxb, wqb, wkb, wvb, wob);
  ln_stats<<<dim3(B_, N_ / 64), 1024, 0, stream>>>(x, mub, rsb);
  // ctx = context @ Wctx^T, fp32 A converted in staging
  gemm_ctx<<<dim3(64, 4), 256, 0, stream>>>(context, wctxb, ctx);
  // k,v fused (512 blocks = 2/CU), global_load_lds staging
  gemm_kv<<<dim3(64, 8), 256, 0, stream>>>(ctx, wkb, wvb, kb, vb);
  // q = LN(x) @ Wq^T, LN fused into staging (no hn round-trip)
  gemm_lnq<<<dim3(128, 4), 256, 0, stream>>>(x, mub, rsb, ln_w, ln_b, wqb, qb);
  // XCD-swizzled 1D grid (T1): all q-blocks of one (b,h) on the same XCD
  attn_mfma<<<1024, 256, 0, stream>>>(qb, kb, vb, mask, atto);
  // out = transpose(atto @ Wo^T) + x, fused epilogue, global_load_lds staging
  gemm_res<<<dim3(128, 4), 256, 0, stream>>>(atto, wob, x, (float*)d_out);
}

// Round 18
// 158.534 us; speedup vs baseline: 6.7636x; 1.0332x over previous
//
#include <hip/hip_runtime.h>

// Problem constants
#define B_   16
#define C_   512
#define N_   1024   // H*W
#define L_   512
#define CTX_ 768
#define NH_  8
#define HD_  64
#define EPS_ 1e-5f

typedef short bfrag  __attribute__((ext_vector_type(8)));  // 8 x bf16 bits
typedef short bfrag4 __attribute__((ext_vector_type(4)));  // 4 x bf16 bits
typedef float f32x4  __attribute__((ext_vector_type(4)));

// manual RNE f32->bf16 (finite inputs); measured equal to native (r10).
__device__ __forceinline__ ushort f2bf(float f) {
  union { float f; unsigned u; } v; v.f = f;
  unsigned r = v.u + 0x7fffu + ((v.u >> 16) & 1u);
  return (ushort)(r >> 16);
}

__device__ __forceinline__ f32x4 mfma16(bfrag a, bfrag b, f32x4 c) {
  return __builtin_amdgcn_mfma_f32_16x16x32_bf16(a, b, c, 0, 0, 0);
}
__device__ __forceinline__ f32x4 mfma16k16(bfrag4 a, bfrag4 b, f32x4 c) {
  return __builtin_amdgcn_mfma_f32_16x16x16bf16_1k(a, b, c, 0, 0, 0);
}
// pack 2 f32 -> 1 dword of 2 bf16 (lo in [15:0], hi in [31:16]), RNE
__device__ __forceinline__ unsigned cvt_pk_bf16(float lo, float hi) {
  unsigned d;
  asm("v_cvt_pk_bf16_f32 %0, %1, %2" : "=v"(d) : "v"(lo), "v"(hi));
  return d;
}

// async global->LDS, 16B/lane. dst must be wave-uniform base + lane*16.
__device__ __forceinline__ void g2l16(const ushort* g, ushort* l) {
  __builtin_amdgcn_global_load_lds(
      (const __attribute__((address_space(1))) void*)g,
      (__attribute__((address_space(3))) void*)l, 16, 0, 0);
}

// ---------------------------------------------------------------------------
// fused weight casts: Wctx (98304 f4) + Wq/Wk/Wv/Wo (65536 f4 each), ONE launch
// ---------------------------------------------------------------------------
__global__ __launch_bounds__(256) void cast5_kernel(
    const float* __restrict__ s0, const float* __restrict__ s1,
    const float* __restrict__ s2, const float* __restrict__ s3,
    const float* __restrict__ s4,
    ushort* __restrict__ d0, ushort* __restrict__ d1, ushort* __restrict__ d2,
    ushort* __restrict__ d3, ushort* __restrict__ d4) {
  int i = blockIdx.x * 256 + threadIdx.x;   // float4 index, total 360448
  const float* src; ushort* dst; int off;
  if      (i < 98304)  { src = s0; dst = d0; off = i; }
  else if (i < 163840) { src = s1; dst = d1; off = i - 98304; }
  else if (i < 229376) { src = s2; dst = d2; off = i - 163840; }
  else if (i < 294912) { src = s3; dst = d3; off = i - 229376; }
  else                 { src = s4; dst = d4; off = i - 294912; }
  float4 vv = ((const float4*)src)[off];
  ushort4 o;
  o.x = f2bf(vv.x); o.y = f2bf(vv.y); o.z = f2bf(vv.z); o.w = f2bf(vv.w);
  ((ushort4*)dst)[off] = o;
}

// ---------------------------------------------------------------------------
// LN stats only: mean/rstd per (b,n). LN application fused into gemm_lnq.
// ---------------------------------------------------------------------------
__global__ __launch_bounds__(1024) void ln_stats(const float* __restrict__ x,
                                                 float* __restrict__ mu_out,
                                                 float* __restrict__ rs_out) {
  const int b  = blockIdx.x;
  const int n0 = blockIdx.y * 64;
  const int tid = threadIdx.x;
  const int nx = tid & 63, cg = tid >> 6;   // cg 0..15
  const float* xb = x + (size_t)b * C_ * N_;

  float s = 0.f, s2 = 0.f;
  for (int c = cg; c < C_; c += 16) {
    float v = xb[(size_t)c * N_ + n0 + nx];
    s += v; s2 += v * v;
  }
  __shared__ float red[2][16][64];
  red[0][cg][nx] = s; red[1][cg][nx] = s2;
  __syncthreads();
  if (cg == 0) {
    float ss = 0.f, ss2 = 0.f;
#pragma unroll
    for (int i = 0; i < 16; ++i) { ss += red[0][i][nx]; ss2 += red[1][i][nx]; }
    float m  = ss * (1.f / C_);
    float var = ss2 * (1.f / C_) - m * m;
    mu_out[(size_t)b * N_ + n0 + nx] = m;
    rs_out[(size_t)b * N_ + n0 + nx] = rsqrtf(var + EPS_);
  }
}

// ---------------------------------------------------------------------------
// Shared GEMM core (bf16 inputs): 128x128x32 tile, 4 waves, 4x4 frags.
// global_load_lds width-16 staging into LINEAR [128][32] LDS, XOR-swizzled
// source/read quad (both-sides involution).
// ---------------------------------------------------------------------------
__device__ __forceinline__ void gemm_core(const ushort* __restrict__ A,
                                          const ushort* __restrict__ W,
                                          int K, ushort* la, ushort* lb,
                                          f32x4 acc[4][4],
                                          int tid, int wm, int we, int col, int rg) {
  const int lane = tid & 63, w = tid >> 6;
  const int rloc = lane >> 2, pt = lane & 3;
  const int pts = pt ^ ((rloc >> 1) & 3);       // source quad pre-swizzle
  const int qsel = (rg ^ ((col >> 1) & 3)) * 8; // read quad select (ushorts)

  for (int k0 = 0; k0 < K; k0 += 32) {
#pragma unroll
    for (int c = 0; c < 2; ++c) {
      const int chunk = w + c * 4;              // 16-row chunk, wave-uniform
      const int row = chunk * 16 + rloc;
      g2l16(A + (size_t)row * K + k0 + pts * 8, la + chunk * 512);
      g2l16(W + (size_t)row * K + k0 + pts * 8, lb + chunk * 512);
    }
    __syncthreads();
    bfrag af[4], bf[4];
#pragma unroll
    for (int i = 0; i < 4; ++i) {
      af[i] = *(const bfrag*)&la[(wm + i * 16 + col) * 32 + qsel];
      bf[i] = *(const bfrag*)&lb[(we + i * 16 + col) * 32 + qsel];
    }
#pragma unroll
    for (int i = 0; i < 4; ++i)
#pragma unroll
      for (int j = 0; j < 4; ++j)
        acc[i][j] = mfma16(af[i], bf[j], acc[i][j]);
    __syncthreads();
  }
}

// ---------------------------------------------------------------------------
// fused K+V projection: blockIdx.y<4 -> K-proj (row-major out), else V-proj
// with TRANSPOSED output vt[(b*512+e)*512+l] (moves the V transpose out of
// attn, where all 8 q-blocks per (b,h) redid it with scalar LDS stores).
// ---------------------------------------------------------------------------
__global__ __launch_bounds__(256) void gemm_kv(const ushort* __restrict__ A,
                                               const ushort* __restrict__ Wk,
                                               const ushort* __restrict__ Wv,
                                               ushort* __restrict__ Ko,
                                               ushort* __restrict__ Vt_g) {
  __shared__ ushort la[128 * 32];
  __shared__ ushort lb[128 * 32];
  __shared__ float T[16][132];
  const int isv = blockIdx.y >> 2;
  const ushort* W = isv ? Wv : Wk;
  const int m0 = blockIdx.x * 128, e0 = (blockIdx.y & 3) * 128;
  const int tid = threadIdx.x, lane = tid & 63, w = tid >> 6;
  const int wm = (w >> 1) * 64, we = (w & 1) * 64;
  const int col = lane & 15, rg = lane >> 4;

  f32x4 acc[4][4] = {};
  gemm_core(A + (size_t)m0 * C_, W + (size_t)e0 * C_, C_, la, lb, acc, tid, wm, we, col, rg);

  if (!isv) {
#pragma unroll
    for (int i = 0; i < 4; ++i)
#pragma unroll
      for (int j = 0; j < 4; ++j)
#pragma unroll
        for (int r = 0; r < 4; ++r)
          Ko[(size_t)(m0 + wm + i * 16 + rg * 4 + r) * 512 + e0 + we + j * 16 + col] =
              f2bf(acc[i][j][r]);
  } else {
    // transposed V write via LDS tile (gemm_res pattern): e-major output
    const int b = m0 >> 9, l0 = m0 & 511;
#pragma unroll
    for (int g = 0; g < 8; ++g) {
      if ((w & 1) == (g >> 2)) {        // wave-uniform: we-half owns this group
        const int j = g & 3;
#pragma unroll
        for (int i = 0; i < 4; ++i)
          *(f32x4*)&T[col][wm + i * 16 + rg * 4] = acc[i][j];
      }
      __syncthreads();
      const int n = tid & 127;
      for (int cc = tid >> 7; cc < 16; cc += 2) {
        const int e = e0 + g * 16 + cc;
        Vt_g[((size_t)b * 512 + e) * 512 + l0 + n] = f2bf(T[cc][n]);
      }
      __syncthreads();
    }
  }
}

// o-projection + transposed residual epilogue: out[b][c][n] = (A@Wo^T)+x
__global__ __launch_bounds__(256) void gemm_res(const ushort* __restrict__ A,
                                                const ushort* __restrict__ W,
                                                const float* __restrict__ x,
                                                float* __restrict__ out) {
  __shared__ ushort la[128 * 32];
  __shared__ ushort lb[128 * 32];
  __shared__ float T[16][132];
  const int m0 = blockIdx.x * 128, e0 = blockIdx.y * 128;
  const int tid = threadIdx.x, lane = tid & 63, w = tid >> 6;
  const int wm = (w >> 1) * 64, we = (w & 1) * 64;
  const int col = lane & 15, rg = lane >> 4;

  f32x4 acc[4][4] = {};
  gemm_core(A + (size_t)m0 * C_, W + (size_t)e0 * C_, C_, la, lb, acc, tid, wm, we, col, rg);

  const int b = m0 >> 10, n0l = m0 & 1023;
#pragma unroll
  for (int g = 0; g < 8; ++g) {
    if ((w & 1) == (g >> 2)) {          // wave-uniform: we-half owns this group
      const int j = g & 3;
#pragma unroll
      for (int i = 0; i < 4; ++i)
        *(f32x4*)&T[col][wm + i * 16 + rg * 4] = acc[i][j];
    }
    __syncthreads();
    const int n = tid & 127;
    for (int cc = tid >> 7; cc < 16; cc += 2) {
      const int c = e0 + g * 16 + cc;
      const size_t idx = (size_t)b * C_ * N_ + (size_t)c * N_ + n0l + n;
      out[idx] = T[cc][n] + x[idx];
    }
    __syncthreads();
  }
}

// ---------------------------------------------------------------------------
// ctx projection: A fp32 (converted in-reg during staging), out bf16.
// ---------------------------------------------------------------------------
__global__ __launch_bounds__(256) void gemm_ctx(const float* __restrict__ Ap,
                                                const ushort* __restrict__ W,
                                                ushort* __restrict__ outp) {
  __shared__ ushort la[128 * 40];
  __shared__ ushort lb[128 * 40];
  const int m0 = blockIdx.x * 128, e0 = blockIdx.y * 128;
  const int tid = threadIdx.x, lane = tid & 63, w = tid >> 6;
  const int wm = (w >> 1) * 64, we = (w & 1) * 64;
  const int col = lane & 15, rg = lane >> 4;
  const int srow = tid >> 1, sh = (tid & 1) * 16;
  const int K = CTX_;

  f32x4 acc[4][4] = {};

  for (int k0 = 0; k0 < K; k0 += 32) {
    {
      const float* ap = &Ap[(size_t)(m0 + srow) * K + k0 + sh];
      float4 f0 = ((const float4*)ap)[0];
      float4 f1 = ((const float4*)ap)[1];
      float4 f2 = ((const float4*)ap)[2];
      float4 f3 = ((const float4*)ap)[3];
      union { int4 v; ushort u[8]; } p0, p1;
      p0.u[0] = f2bf(f0.x); p0.u[1] = f2bf(f0.y); p0.u[2] = f2bf(f0.z); p0.u[3] = f2bf(f0.w);
      p0.u[4] = f2bf(f1.x); p0.u[5] = f2bf(f1.y); p0.u[6] = f2bf(f1.z); p0.u[7] = f2bf(f1.w);
      p1.u[0] = f2bf(f2.x); p1.u[1] = f2bf(f2.y); p1.u[2] = f2bf(f2.z); p1.u[3] = f2bf(f2.w);
      p1.u[4] = f2bf(f3.x); p1.u[5] = f2bf(f3.y); p1.u[6] = f2bf(f3.z); p1.u[7] = f2bf(f3.w);
      *(int4*)&la[srow * 40 + sh]     = p0.v;
      *(int4*)&la[srow * 40 + sh + 8] = p1.v;
      const ushort* wp = &W[(size_t)(e0 + srow) * K + k0 + sh];
      *(int4*)&lb[srow * 40 + sh]     = *(const int4*)wp;
      *(int4*)&lb[srow * 40 + sh + 8] = *(const int4*)(wp + 8);
    }
    __syncthreads();
    bfrag af[4], bf[4];
#pragma unroll
    for (int i = 0; i < 4; ++i) {
      af[i] = *(const bfrag*)&la[(wm + i * 16 + col) * 40 + rg * 8];
      bf[i] = *(const bfrag*)&lb[(we + i * 16 + col) * 40 + rg * 8];
    }
#pragma unroll
    for (int i = 0; i < 4; ++i)
#pragma unroll
      for (int j = 0; j < 4; ++j)
        acc[i][j] = mfma16(af[i], bf[j], acc[i][j]);
    __syncthreads();
  }

#pragma unroll
  for (int i = 0; i < 4; ++i)
#pragma unroll
    for (int j = 0; j < 4; ++j)
#pragma unroll
      for (int r = 0; r < 4; ++r)
        outp[(size_t)(m0 + wm + i * 16 + rg * 4 + r) * 512 + e0 + we + j * 16 + col] =
            f2bf(acc[i][j][r]);
}

// ---------------------------------------------------------------------------
// q-projection with fused LayerNorm: A[m=(b,n)][k=c] = (x[b][c][n]-mu)*rs*w+b,
// staged straight from x (no hn round-trip).
// ---------------------------------------------------------------------------
__global__ __launch_bounds__(256) void gemm_lnq(const float* __restrict__ x,
                                                const float* __restrict__ mu,
                                                const float* __restrict__ rs,
                                                const float* __restrict__ lnw,
                                                const float* __restrict__ lnb,
                                                const ushort* __restrict__ W,
                                                ushort* __restrict__ out) {
  __shared__ ushort la[128 * 40];
  __shared__ ushort lb[128 * 40];
  const int m0 = blockIdx.x * 128, e0 = blockIdx.y * 128;
  const int b = m0 >> 10, n0l = m0 & 1023;
  const int tid = threadIdx.x, lane = tid & 63, w = tid >> 6;
  const int wm = (w >> 1) * 64, we = (w & 1) * 64;
  const int col = lane & 15, rg = lane >> 4;
  const int nloc = tid & 127, chalf = (tid >> 7) * 16;
  const int srow = tid >> 1, sh = (tid & 1) * 16;

  const float muv = mu[(size_t)b * N_ + n0l + nloc];
  const float rsv = rs[(size_t)b * N_ + n0l + nloc];
  const float nmr = -muv * rsv;   // t = fma(x, rsv, nmr)
  const float* xb = x + (size_t)b * C_ * N_ + n0l + nloc;

  f32x4 acc[4][4] = {};

  for (int k0 = 0; k0 < C_; k0 += 32) {
    {
      union { int4 v[2]; ushort u[16]; } pk;
#pragma unroll
      for (int i = 0; i < 16; ++i) {
        const int c = k0 + chalf + i;
        const float xv = xb[(size_t)c * N_];
        const float t = fmaf(xv, rsv, nmr);
        pk.u[i] = f2bf(fmaf(t, lnw[c], lnb[c]));
      }
      *(int4*)&la[nloc * 40 + chalf]     = pk.v[0];
      *(int4*)&la[nloc * 40 + chalf + 8] = pk.v[1];
      const ushort* wp = &W[(size_t)(e0 + srow) * C_ + k0 + sh];
      *(int4*)&lb[srow * 40 + sh]     = *(const int4*)wp;
      *(int4*)&lb[srow * 40 + sh + 8] = *(const int4*)(wp + 8);
    }
    __syncthreads();
    bfrag af[4], bf[4];
#pragma unroll
    for (int i = 0; i < 4; ++i) {
      af[i] = *(const bfrag*)&la[(wm + i * 16 + col) * 40 + rg * 8];
      bf[i] = *(const bfrag*)&lb[(we + i * 16 + col) * 40 + rg * 8];
    }
#pragma unroll
    for (int i = 0; i < 4; ++i)
#pragma unroll
      for (int j = 0; j < 4; ++j)
        acc[i][j] = mfma16(af[i], bf[j], acc[i][j]);
    __syncthreads();
  }

#pragma unroll
  for (int i = 0; i < 4; ++i)
#pragma unroll
    for (int j = 0; j < 4; ++j)
#pragma unroll
      for (int r = 0; r < 4; ++r)
        out[(size_t)(m0 + wm + i * 16 + rg * 4 + r) * 512 + e0 + we + j * 16 + col] =
            f2bf(acc[i][j][r]);
}

// ---------------------------------------------------------------------------
// MFMA flash cross-attention (swapped QK^T, P in registers, double-buffered,
// XCD-swizzled). V arrives PRE-TRANSPOSED from gemm_kv (vt[(b*512+e)*512+l])
// -> V staging is 2 b128 loads + 2 b128 LDS writes per thread (was 4 loads +
// 16 scalar b16 stores). LDS layout Vt[d][72] unchanged.
// ---------------------------------------------------------------------------
__global__ __launch_bounds__(256) void attn_mfma(const ushort* __restrict__ q,
                                                 const ushort* __restrict__ k,
                                                 const ushort* __restrict__ vt,
                                                 const int* __restrict__ mask,
                                                 ushort* __restrict__ o) {
  __shared__ ushort Kl[2][64 * 72];   // [buf][key][72]
  __shared__ ushort Vt[2][64 * 72];   // [buf][d][72]
  __shared__ float mlb[2][64];

  const int lin = blockIdx.x;           // 0..1023
  const int hb = lin & 127, qb = lin >> 7;
  const int h = hb & 7, b = hb >> 3;
  const int q0 = qb * 128;
  const int tid = threadIdx.x, lane = tid & 63, w = tid >> 6;
  const int col = lane & 15, rg = lane >> 4;
  const int wq = w * 32;
  const float C1 = 0.18033688011112042f;  // 0.125 * log2(e)

  bfrag qf[2][2];
#pragma unroll
  for (int mi = 0; mi < 2; ++mi)
#pragma unroll
    for (int kc = 0; kc < 2; ++kc)
      qf[mi][kc] = *(const bfrag*)
          &q[((size_t)b * N_ + q0 + wq + mi * 16 + col) * C_ + h * HD_ + kc * 32 + rg * 8];

  f32x4 oa[2][4] = {};
  float l_part[2] = {0.f, 0.f};   // per-lane denominator for q = col

  // prologue: stage tile 0 into buf 0
  {
#pragma unroll
    for (int it = 0; it < 2; ++it) {
      const int idx = it * 256 + tid;
      const int key = idx >> 3, part = idx & 7;
      *(int4*)&Kl[0][key * 72 + part * 8] =
          *(const int4*)&k[((size_t)b * L_ + key) * C_ + h * HD_ + part * 8];
    }
#pragma unroll
    for (int it = 0; it < 2; ++it) {    // V^T: row d, 8 keys per b128
      const int idx = it * 256 + tid;
      const int d = idx >> 3, k8 = (idx & 7) * 8;
      *(int4*)&Vt[0][d * 72 + k8] =
          *(const int4*)&vt[((size_t)b * 512 + h * HD_ + d) * 512 + k8];
    }
    if (tid < 64) mlb[0][tid] = mask[b * L_ + tid] ? 0.f : -1e30f;
  }
  __syncthreads();

  for (int t = 0; t < 8; ++t) {
    const int cur = t & 1;
    // issue next-tile loads into registers (retire at the write phase)
    int4 kreg[2];
    int4 vreg[2];
    float mreg = 0.f;
    if (t < 7) {
      const int l0n = (t + 1) * 64;
#pragma unroll
      for (int it = 0; it < 2; ++it) {
        const int idx = it * 256 + tid;
        const int key = idx >> 3, part = idx & 7;
        kreg[it] = *(const int4*)&k[((size_t)b * L_ + l0n + key) * C_ + h * HD_ + part * 8];
      }
#pragma unroll
      for (int it = 0; it < 2; ++it) {
        const int idx = it * 256 + tid;
        const int d = idx >> 3, k8 = (idx & 7) * 8;
        vreg[it] = *(const int4*)&vt[((size_t)b * 512 + h * HD_ + d) * 512 + l0n + k8];
      }
      if (tid < 64) mreg = mask[b * L_ + l0n + tid] ? 0.f : -1e30f;
    }

    // ---- compute on buf cur ----
    const ushort* Kc = &Kl[cur][0];
    const ushort* Vc = &Vt[cur][0];
    f32x4 s2[2][4] = {};
#pragma unroll
    for (int kc = 0; kc < 2; ++kc) {
      bfrag kf[4];
#pragma unroll
      for (int ni = 0; ni < 4; ++ni)
        kf[ni] = *(const bfrag*)&Kc[(ni * 16 + col) * 72 + kc * 32 + rg * 8];
#pragma unroll
      for (int mi = 0; mi < 2; ++mi)
#pragma unroll
        for (int ni = 0; ni < 4; ++ni)
          s2[mi][ni] = mfma16(kf[ni], qf[mi][kc], s2[mi][ni]);
    }
    bfrag4 pf[2][4];
#pragma unroll
    for (int ni = 0; ni < 4; ++ni) {
      const f32x4 bias4 = *(const f32x4*)&mlb[cur][ni * 16 + rg * 4];
#pragma unroll
      for (int mi = 0; mi < 2; ++mi) {
        const float p0 = exp2f(fmaf(s2[mi][ni][0], C1, bias4[0]));
        const float p1 = exp2f(fmaf(s2[mi][ni][1], C1, bias4[1]));
        const float p2 = exp2f(fmaf(s2[mi][ni][2], C1, bias4[2]));
        const float p3 = exp2f(fmaf(s2[mi][ni][3], C1, bias4[3]));
        l_part[mi] += (p0 + p1) + (p2 + p3);
        union { bfrag4 v; unsigned u[2]; } pk;
        pk.u[0] = cvt_pk_bf16(p0, p1);
        pk.u[1] = cvt_pk_bf16(p2, p3);
        pf[mi][ni] = pk.v;
      }
    }
#pragma unroll
    for (int ni = 0; ni < 4; ++ni) {
      bfrag4 vf[4];
#pragma unroll
      for (int di = 0; di < 4; ++di)
        vf[di] = *(const bfrag4*)&Vc[(di * 16 + col) * 72 + ni * 16 + rg * 4];
#pragma unroll
      for (int mi = 0; mi < 2; ++mi)
#pragma unroll
        for (int di = 0; di < 4; ++di)
          oa[mi][di] = mfma16k16(pf[mi][ni], vf[di], oa[mi][di]);
    }

    // ---- write next tile into the other buffer ----
    if (t < 7) {
      const int nb = cur ^ 1;
#pragma unroll
      for (int it = 0; it < 2; ++it) {
        const int idx = it * 256 + tid;
        const int key = idx >> 3, part = idx & 7;
        *(int4*)&Kl[nb][key * 72 + part * 8] = kreg[it];
      }
#pragma unroll
      for (int it = 0; it < 2; ++it) {
        const int idx = it * 256 + tid;
        const int d = idx >> 3, k8 = (idx & 7) * 8;
        *(int4*)&Vt[nb][d * 72 + k8] = vreg[it];
      }
      if (tid < 64) mlb[nb][tid] = mreg;
    }
    __syncthreads();   // one barrier per tile: readers done + next buf ready
  }

  // denominator: reduce across rg groups, bpermute 1/l to row layout
  float linv[2][4];
#pragma unroll
  for (int mi = 0; mi < 2; ++mi) {
    float l = l_part[mi];
    l += __shfl_xor(l, 16);
    l += __shfl_xor(l, 32);
#pragma unroll
    for (int r = 0; r < 4; ++r) {
      int lv = __builtin_amdgcn_ds_bpermute((rg * 4 + r) * 4, __float_as_int(l));
      linv[mi][r] = 1.f / __int_as_float(lv);
    }
  }
#pragma unroll
  for (int mi = 0; mi < 2; ++mi)
#pragma unroll
    for (int r = 0; r < 4; ++r) {
      const size_t row = (size_t)b * N_ + q0 + wq + mi * 16 + rg * 4 + r;
#pragma unroll
      for (int di = 0; di < 4; ++di)
        o[row * C_ + h * HD_ + di * 16 + col] = f2bf(oa[mi][di][r] * linv[mi][r]);
    }
}

// ---------------------------------------------------------------------------
// Launch
// ---------------------------------------------------------------------------
extern "C" void kernel_launch(void* const* d_in, const int* in_sizes, int n_in,
                              void* d_out, int out_size, void* d_ws, size_t ws_size,
                              hipStream_t stream) {
  (void)in_sizes; (void)n_in; (void)out_size; (void)ws_size;
  const float* x       = (const float*)d_in[0];
  const float* context = (const float*)d_in[1];
  const int*   mask    = (const int*)d_in[2];
  const float* ln_w    = (const float*)d_in[3];
  const float* ln_b    = (const float*)d_in[4];
  const float* Wq      = (const float*)d_in[5];
  const float* Wk      = (const float*)d_in[6];
  const float* Wv      = (const float*)d_in[7];
  const float* Wo      = (const float*)d_in[8];
  const float* Wctx    = (const float*)d_in[9];

  char* wsb = (char*)d_ws;
  ushort* qb    = (ushort*)(wsb + 0);          // 16384x512 bf16
  ushort* kb    = (ushort*)(wsb + 16777216);   //  8192x512
  ushort* vb    = (ushort*)(wsb + 25165824);   //  8192x512 (V^T: (b*512+e)*512+l)
  ushort* atto  = (ushort*)(wsb + 33554432);   // 16384x512 (attn out)
  ushort* ctx   = (ushort*)(wsb + 50331648);   //  8192x512
  ushort* wctxb = (ushort*)(wsb + 58720256);   //   512x768
  ushort* wqb   = (ushort*)(wsb + 59506688);   //   512x512 each
  ushort* wkb   = (ushort*)(wsb + 60030976);
  ushort* wvb   = (ushort*)(wsb + 60555264);
  ushort* wob   = (ushort*)(wsb + 61079552);
  float*  mub   = (float*)(wsb + 61603840);    // 16384 f32
  float*  rsb   = (float*)(wsb + 61669376);    // 16384 f32

  cast5_kernel<<<1408, 256, 0, stream>>>(Wctx, Wq, Wk, Wv, Wo,
                                         wctxb, wqb, wkb, wvb, wob);
  ln_stats<<<dim3(B_, N_ / 64), 1024, 0, stream>>>(x, mub, rsb);
  // ctx = context @ Wctx^T, fp32 A converted in staging
  gemm_ctx<<<dim3(64, 4), 256, 0, stream>>>(context, wctxb, ctx);
  // k row-major, v TRANSPOSED (e-major) for attn staging
  gemm_kv<<<dim3(64, 8), 256, 0, stream>>>(ctx, wkb, wvb, kb, vb);
  // q = LN(x) @ Wq^T, LN fused into staging (no hn round-trip)
  gemm_lnq<<<dim3(128, 4), 256, 0, stream>>>(x, mub, rsb, ln_w, ln_b, wqb, qb);
  // XCD-swizzled 1D grid (T1): all q-blocks of one (b,h) on the same XCD
  attn_mfma<<<1024, 256, 0, stream>>>(qb, kb, vb, mask, atto);
  // out = transpose(atto @ Wo^T) + x, fused epilogue, global_load_lds staging
  gemm_res<<<dim3(128, 4), 256, 0, stream>>>(atto, wob, x, (float*)d_out);
}

// Round 19
// 157.530 us; speedup vs baseline: 6.8068x; 1.0064x over previous
//
#include <hip/hip_runtime.h>

// Problem constants
#define B_   16
#define C_   512
#define N_   1024   // H*W
#define L_   512
#define CTX_ 768
#define NH_  8
#define HD_  64
#define EPS_ 1e-5f

typedef short bfrag  __attribute__((ext_vector_type(8)));  // 8 x bf16 bits
typedef short bfrag4 __attribute__((ext_vector_type(4)));  // 4 x bf16 bits
typedef float f32x4  __attribute__((ext_vector_type(4)));

// manual RNE f32->bf16 (finite inputs); measured equal to native (r10).
__device__ __forceinline__ ushort f2bf(float f) {
  union { float f; unsigned u; } v; v.f = f;
  unsigned r = v.u + 0x7fffu + ((v.u >> 16) & 1u);
  return (ushort)(r >> 16);
}

__device__ __forceinline__ f32x4 mfma16(bfrag a, bfrag b, f32x4 c) {
  return __builtin_amdgcn_mfma_f32_16x16x32_bf16(a, b, c, 0, 0, 0);
}
__device__ __forceinline__ f32x4 mfma16k16(bfrag4 a, bfrag4 b, f32x4 c) {
  return __builtin_amdgcn_mfma_f32_16x16x16bf16_1k(a, b, c, 0, 0, 0);
}
// pack 2 f32 -> 1 dword of 2 bf16 (lo in [15:0], hi in [31:16]), RNE
__device__ __forceinline__ unsigned cvt_pk_bf16(float lo, float hi) {
  unsigned d;
  asm("v_cvt_pk_bf16_f32 %0, %1, %2" : "=v"(d) : "v"(lo), "v"(hi));
  return d;
}

// async global->LDS, 16B/lane. dst must be wave-uniform base + lane*16.
__device__ __forceinline__ void g2l16(const ushort* g, ushort* l) {
  __builtin_amdgcn_global_load_lds(
      (const __attribute__((address_space(1))) void*)g,
      (__attribute__((address_space(3))) void*)l, 16, 0, 0);
}

// ---------------------------------------------------------------------------
// fused weight casts: Wctx (98304 f4) + Wq/Wk/Wv/Wo (65536 f4 each), ONE launch
// ---------------------------------------------------------------------------
__global__ __launch_bounds__(256) void cast5_kernel(
    const float* __restrict__ s0, const float* __restrict__ s1,
    const float* __restrict__ s2, const float* __restrict__ s3,
    const float* __restrict__ s4,
    ushort* __restrict__ d0, ushort* __restrict__ d1, ushort* __restrict__ d2,
    ushort* __restrict__ d3, ushort* __restrict__ d4) {
  int i = blockIdx.x * 256 + threadIdx.x;   // float4 index, total 360448
  const float* src; ushort* dst; int off;
  if      (i < 98304)  { src = s0; dst = d0; off = i; }
  else if (i < 163840) { src = s1; dst = d1; off = i - 98304; }
  else if (i < 229376) { src = s2; dst = d2; off = i - 163840; }
  else if (i < 294912) { src = s3; dst = d3; off = i - 229376; }
  else                 { src = s4; dst = d4; off = i - 294912; }
  float4 vv = ((const float4*)src)[off];
  ushort4 o;
  o.x = f2bf(vv.x); o.y = f2bf(vv.y); o.z = f2bf(vv.z); o.w = f2bf(vv.w);
  ((ushort4*)dst)[off] = o;
}

// ---------------------------------------------------------------------------
// LN stats only: mean/rstd per (b,n). LN application fused into the lnq path.
// ---------------------------------------------------------------------------
__global__ __launch_bounds__(1024) void ln_stats(const float* __restrict__ x,
                                                 float* __restrict__ mu_out,
                                                 float* __restrict__ rs_out) {
  const int b  = blockIdx.x;
  const int n0 = blockIdx.y * 64;
  const int tid = threadIdx.x;
  const int nx = tid & 63, cg = tid >> 6;   // cg 0..15
  const float* xb = x + (size_t)b * C_ * N_;

  float s = 0.f, s2 = 0.f;
  for (int c = cg; c < C_; c += 16) {
    float v = xb[(size_t)c * N_ + n0 + nx];
    s += v; s2 += v * v;
  }
  __shared__ float red[2][16][64];
  red[0][cg][nx] = s; red[1][cg][nx] = s2;
  __syncthreads();
  if (cg == 0) {
    float ss = 0.f, ss2 = 0.f;
#pragma unroll
    for (int i = 0; i < 16; ++i) { ss += red[0][i][nx]; ss2 += red[1][i][nx]; }
    float m  = ss * (1.f / C_);
    float var = ss2 * (1.f / C_) - m * m;
    mu_out[(size_t)b * N_ + n0 + nx] = m;
    rs_out[(size_t)b * N_ + n0 + nx] = rsqrtf(var + EPS_);
  }
}

// ---------------------------------------------------------------------------
// Shared GEMM core (bf16 inputs): 128x128x32 tile, 4 waves, 4x4 frags.
// global_load_lds width-16 staging into LINEAR [128][32] LDS, XOR-swizzled
// source/read quad (both-sides involution).
// ---------------------------------------------------------------------------
__device__ __forceinline__ void gemm_core(const ushort* __restrict__ A,
                                          const ushort* __restrict__ W,
                                          int K, ushort* la, ushort* lb,
                                          f32x4 acc[4][4],
                                          int tid, int wm, int we, int col, int rg) {
  const int lane = tid & 63, w = tid >> 6;
  const int rloc = lane >> 2, pt = lane & 3;
  const int pts = pt ^ ((rloc >> 1) & 3);       // source quad pre-swizzle
  const int qsel = (rg ^ ((col >> 1) & 3)) * 8; // read quad select (ushorts)

  for (int k0 = 0; k0 < K; k0 += 32) {
#pragma unroll
    for (int c = 0; c < 2; ++c) {
      const int chunk = w + c * 4;              // 16-row chunk, wave-uniform
      const int row = chunk * 16 + rloc;
      g2l16(A + (size_t)row * K + k0 + pts * 8, la + chunk * 512);
      g2l16(W + (size_t)row * K + k0 + pts * 8, lb + chunk * 512);
    }
    __syncthreads();
    bfrag af[4], bf[4];
#pragma unroll
    for (int i = 0; i < 4; ++i) {
      af[i] = *(const bfrag*)&la[(wm + i * 16 + col) * 32 + qsel];
      bf[i] = *(const bfrag*)&lb[(we + i * 16 + col) * 32 + qsel];
    }
#pragma unroll
    for (int i = 0; i < 4; ++i)
#pragma unroll
      for (int j = 0; j < 4; ++j)
        acc[i][j] = mfma16(af[i], bf[j], acc[i][j]);
    __syncthreads();
  }
}

// ---------------------------------------------------------------------------
// fused K+V projection: blockIdx.y<4 -> K-proj (row-major out), else V-proj
// with TRANSPOSED output vt[(b*512+e)*512+l].
// ---------------------------------------------------------------------------
__global__ __launch_bounds__(256) void gemm_kv(const ushort* __restrict__ A,
                                               const ushort* __restrict__ Wk,
                                               const ushort* __restrict__ Wv,
                                               ushort* __restrict__ Ko,
                                               ushort* __restrict__ Vt_g) {
  __shared__ ushort la[128 * 32];
  __shared__ ushort lb[128 * 32];
  __shared__ float T[16][132];
  const int isv = blockIdx.y >> 2;
  const ushort* W = isv ? Wv : Wk;
  const int m0 = blockIdx.x * 128, e0 = (blockIdx.y & 3) * 128;
  const int tid = threadIdx.x, lane = tid & 63, w = tid >> 6;
  const int wm = (w >> 1) * 64, we = (w & 1) * 64;
  const int col = lane & 15, rg = lane >> 4;

  f32x4 acc[4][4] = {};
  gemm_core(A + (size_t)m0 * C_, W + (size_t)e0 * C_, C_, la, lb, acc, tid, wm, we, col, rg);

  if (!isv) {
#pragma unroll
    for (int i = 0; i < 4; ++i)
#pragma unroll
      for (int j = 0; j < 4; ++j)
#pragma unroll
        for (int r = 0; r < 4; ++r)
          Ko[(size_t)(m0 + wm + i * 16 + rg * 4 + r) * 512 + e0 + we + j * 16 + col] =
              f2bf(acc[i][j][r]);
  } else {
    // transposed V write via LDS tile: e-major output
    const int b = m0 >> 9, l0 = m0 & 511;
#pragma unroll
    for (int g = 0; g < 8; ++g) {
      if ((w & 1) == (g >> 2)) {        // wave-uniform: we-half owns this group
        const int j = g & 3;
#pragma unroll
        for (int i = 0; i < 4; ++i)
          *(f32x4*)&T[col][wm + i * 16 + rg * 4] = acc[i][j];
      }
      __syncthreads();
      const int n = tid & 127;
      for (int cc = tid >> 7; cc < 16; cc += 2) {
        const int e = e0 + g * 16 + cc;
        Vt_g[((size_t)b * 512 + e) * 512 + l0 + n] = f2bf(T[cc][n]);
      }
      __syncthreads();
    }
  }
}

// o-projection + transposed residual epilogue: out[b][c][n] = (A@Wo^T)+x
__global__ __launch_bounds__(256) void gemm_res(const ushort* __restrict__ A,
                                                const ushort* __restrict__ W,
                                                const float* __restrict__ x,
                                                float* __restrict__ out) {
  __shared__ ushort la[128 * 32];
  __shared__ ushort lb[128 * 32];
  __shared__ float T[16][132];
  const int m0 = blockIdx.x * 128, e0 = blockIdx.y * 128;
  const int tid = threadIdx.x, lane = tid & 63, w = tid >> 6;
  const int wm = (w >> 1) * 64, we = (w & 1) * 64;
  const int col = lane & 15, rg = lane >> 4;

  f32x4 acc[4][4] = {};
  gemm_core(A + (size_t)m0 * C_, W + (size_t)e0 * C_, C_, la, lb, acc, tid, wm, we, col, rg);

  const int b = m0 >> 10, n0l = m0 & 1023;
#pragma unroll
  for (int g = 0; g < 8; ++g) {
    if ((w & 1) == (g >> 2)) {          // wave-uniform: we-half owns this group
      const int j = g & 3;
#pragma unroll
      for (int i = 0; i < 4; ++i)
        *(f32x4*)&T[col][wm + i * 16 + rg * 4] = acc[i][j];
    }
    __syncthreads();
    const int n = tid & 127;
    for (int cc = tid >> 7; cc < 16; cc += 2) {
      const int c = e0 + g * 16 + cc;
      const size_t idx = (size_t)b * C_ * N_ + (size_t)c * N_ + n0l + n;
      out[idx] = T[cc][n] + x[idx];
    }
    __syncthreads();
  }
}

// ---------------------------------------------------------------------------
// Round-19: FUSED ctx-projection + lnq-projection (independent GEMMs that ran
// serially at 1-2 blocks/CU each; one 768-block dispatch fills the machine).
// Blocks 0..255: ctx = context @ Wctx^T (A fp32 in-reg convert, K=768).
// Blocks 256..767: q = LN(x) @ Wq^T (LN fused in staging, K=512).
// Both bodies byte-identical to r18's gemm_ctx / gemm_lnq.
// ---------------------------------------------------------------------------
__global__ __launch_bounds__(256) void gemm_ctxlnq(
    const float* __restrict__ context, const ushort* __restrict__ Wctxb,
    ushort* __restrict__ ctxo,
    const float* __restrict__ x, const float* __restrict__ mu,
    const float* __restrict__ rs, const float* __restrict__ lnw,
    const float* __restrict__ lnb, const ushort* __restrict__ Wqb,
    ushort* __restrict__ qo) {
  __shared__ ushort la[128 * 40];
  __shared__ ushort lb[128 * 40];
  const int bid = blockIdx.x;
  const int tid = threadIdx.x, lane = tid & 63, w = tid >> 6;
  const int wm = (w >> 1) * 64, we = (w & 1) * 64;
  const int col = lane & 15, rg = lane >> 4;
  const int srow = tid >> 1, sh = (tid & 1) * 16;

  f32x4 acc[4][4] = {};

  if (bid < 256) {
    // ---- ctx path ----
    const int m0 = (bid >> 2) * 128, e0 = (bid & 3) * 128;
    const int K = CTX_;
    for (int k0 = 0; k0 < K; k0 += 32) {
      {
        const float* ap = &context[(size_t)(m0 + srow) * K + k0 + sh];
        float4 f0 = ((const float4*)ap)[0];
        float4 f1 = ((const float4*)ap)[1];
        float4 f2 = ((const float4*)ap)[2];
        float4 f3 = ((const float4*)ap)[3];
        union { int4 v; ushort u[8]; } p0, p1;
        p0.u[0] = f2bf(f0.x); p0.u[1] = f2bf(f0.y); p0.u[2] = f2bf(f0.z); p0.u[3] = f2bf(f0.w);
        p0.u[4] = f2bf(f1.x); p0.u[5] = f2bf(f1.y); p0.u[6] = f2bf(f1.z); p0.u[7] = f2bf(f1.w);
        p1.u[0] = f2bf(f2.x); p1.u[1] = f2bf(f2.y); p1.u[2] = f2bf(f2.z); p1.u[3] = f2bf(f2.w);
        p1.u[4] = f2bf(f3.x); p1.u[5] = f2bf(f3.y); p1.u[6] = f2bf(f3.z); p1.u[7] = f2bf(f3.w);
        *(int4*)&la[srow * 40 + sh]     = p0.v;
        *(int4*)&la[srow * 40 + sh + 8] = p1.v;
        const ushort* wp = &Wctxb[(size_t)(e0 + srow) * K + k0 + sh];
        *(int4*)&lb[srow * 40 + sh]     = *(const int4*)wp;
        *(int4*)&lb[srow * 40 + sh + 8] = *(const int4*)(wp + 8);
      }
      __syncthreads();
      bfrag af[4], bf[4];
#pragma unroll
      for (int i = 0; i < 4; ++i) {
        af[i] = *(const bfrag*)&la[(wm + i * 16 + col) * 40 + rg * 8];
        bf[i] = *(const bfrag*)&lb[(we + i * 16 + col) * 40 + rg * 8];
      }
#pragma unroll
      for (int i = 0; i < 4; ++i)
#pragma unroll
        for (int j = 0; j < 4; ++j)
          acc[i][j] = mfma16(af[i], bf[j], acc[i][j]);
      __syncthreads();
    }
#pragma unroll
    for (int i = 0; i < 4; ++i)
#pragma unroll
      for (int j = 0; j < 4; ++j)
#pragma unroll
        for (int r = 0; r < 4; ++r)
          ctxo[(size_t)(m0 + wm + i * 16 + rg * 4 + r) * 512 + e0 + we + j * 16 + col] =
              f2bf(acc[i][j][r]);
  } else {
    // ---- lnq path ----
    const int b2 = bid - 256;
    const int m0 = (b2 >> 2) * 128, e0 = (b2 & 3) * 128;
    const int b = m0 >> 10, n0l = m0 & 1023;
    const int nloc = tid & 127, chalf = (tid >> 7) * 16;

    const float muv = mu[(size_t)b * N_ + n0l + nloc];
    const float rsv = rs[(size_t)b * N_ + n0l + nloc];
    const float nmr = -muv * rsv;   // t = fma(x, rsv, nmr)
    const float* xb = x + (size_t)b * C_ * N_ + n0l + nloc;

    for (int k0 = 0; k0 < C_; k0 += 32) {
      {
        union { int4 v[2]; ushort u[16]; } pk;
#pragma unroll
        for (int i = 0; i < 16; ++i) {
          const int c = k0 + chalf + i;
          const float xv = xb[(size_t)c * N_];
          const float t = fmaf(xv, rsv, nmr);
          pk.u[i] = f2bf(fmaf(t, lnw[c], lnb[c]));
        }
        *(int4*)&la[nloc * 40 + chalf]     = pk.v[0];
        *(int4*)&la[nloc * 40 + chalf + 8] = pk.v[1];
        const ushort* wp = &Wqb[(size_t)(e0 + srow) * C_ + k0 + sh];
        *(int4*)&lb[srow * 40 + sh]     = *(const int4*)wp;
        *(int4*)&lb[srow * 40 + sh + 8] = *(const int4*)(wp + 8);
      }
      __syncthreads();
      bfrag af[4], bf[4];
#pragma unroll
      for (int i = 0; i < 4; ++i) {
        af[i] = *(const bfrag*)&la[(wm + i * 16 + col) * 40 + rg * 8];
        bf[i] = *(const bfrag*)&lb[(we + i * 16 + col) * 40 + rg * 8];
      }
#pragma unroll
      for (int i = 0; i < 4; ++i)
#pragma unroll
        for (int j = 0; j < 4; ++j)
          acc[i][j] = mfma16(af[i], bf[j], acc[i][j]);
      __syncthreads();
    }
#pragma unroll
    for (int i = 0; i < 4; ++i)
#pragma unroll
      for (int j = 0; j < 4; ++j)
#pragma unroll
        for (int r = 0; r < 4; ++r)
          qo[(size_t)(m0 + wm + i * 16 + rg * 4 + r) * 512 + e0 + we + j * 16 + col] =
              f2bf(acc[i][j][r]);
  }
}

// ---------------------------------------------------------------------------
// MFMA flash cross-attention (swapped QK^T, P in registers, double-buffered,
// XCD-swizzled, V pre-transposed). Unchanged from r18.
// ---------------------------------------------------------------------------
__global__ __launch_bounds__(256) void attn_mfma(const ushort* __restrict__ q,
                                                 const ushort* __restrict__ k,
                                                 const ushort* __restrict__ vt,
                                                 const int* __restrict__ mask,
                                                 ushort* __restrict__ o) {
  __shared__ ushort Kl[2][64 * 72];   // [buf][key][72]
  __shared__ ushort Vt[2][64 * 72];   // [buf][d][72]
  __shared__ float mlb[2][64];

  const int lin = blockIdx.x;           // 0..1023
  const int hb = lin & 127, qb = lin >> 7;
  const int h = hb & 7, b = hb >> 3;
  const int q0 = qb * 128;
  const int tid = threadIdx.x, lane = tid & 63, w = tid >> 6;
  const int col = lane & 15, rg = lane >> 4;
  const int wq = w * 32;
  const float C1 = 0.18033688011112042f;  // 0.125 * log2(e)

  bfrag qf[2][2];
#pragma unroll
  for (int mi = 0; mi < 2; ++mi)
#pragma unroll
    for (int kc = 0; kc < 2; ++kc)
      qf[mi][kc] = *(const bfrag*)
          &q[((size_t)b * N_ + q0 + wq + mi * 16 + col) * C_ + h * HD_ + kc * 32 + rg * 8];

  f32x4 oa[2][4] = {};
  float l_part[2] = {0.f, 0.f};   // per-lane denominator for q = col

  // prologue: stage tile 0 into buf 0
  {
#pragma unroll
    for (int it = 0; it < 2; ++it) {
      const int idx = it * 256 + tid;
      const int key = idx >> 3, part = idx & 7;
      *(int4*)&Kl[0][key * 72 + part * 8] =
          *(const int4*)&k[((size_t)b * L_ + key) * C_ + h * HD_ + part * 8];
    }
#pragma unroll
    for (int it = 0; it < 2; ++it) {    // V^T: row d, 8 keys per b128
      const int idx = it * 256 + tid;
      const int d = idx >> 3, k8 = (idx & 7) * 8;
      *(int4*)&Vt[0][d * 72 + k8] =
          *(const int4*)&vt[((size_t)b * 512 + h * HD_ + d) * 512 + k8];
    }
    if (tid < 64) mlb[0][tid] = mask[b * L_ + tid] ? 0.f : -1e30f;
  }
  __syncthreads();

  for (int t = 0; t < 8; ++t) {
    const int cur = t & 1;
    // issue next-tile loads into registers (retire at the write phase)
    int4 kreg[2];
    int4 vreg[2];
    float mreg = 0.f;
    if (t < 7) {
      const int l0n = (t + 1) * 64;
#pragma unroll
      for (int it = 0; it < 2; ++it) {
        const int idx = it * 256 + tid;
        const int key = idx >> 3, part = idx & 7;
        kreg[it] = *(const int4*)&k[((size_t)b * L_ + l0n + key) * C_ + h * HD_ + part * 8];
      }
#pragma unroll
      for (int it = 0; it < 2; ++it) {
        const int idx = it * 256 + tid;
        const int d = idx >> 3, k8 = (idx & 7) * 8;
        vreg[it] = *(const int4*)&vt[((size_t)b * 512 + h * HD_ + d) * 512 + l0n + k8];
      }
      if (tid < 64) mreg = mask[b * L_ + l0n + tid] ? 0.f : -1e30f;
    }

    // ---- compute on buf cur ----
    const ushort* Kc = &Kl[cur][0];
    const ushort* Vc = &Vt[cur][0];
    f32x4 s2[2][4] = {};
#pragma unroll
    for (int kc = 0; kc < 2; ++kc) {
      bfrag kf[4];
#pragma unroll
      for (int ni = 0; ni < 4; ++ni)
        kf[ni] = *(const bfrag*)&Kc[(ni * 16 + col) * 72 + kc * 32 + rg * 8];
#pragma unroll
      for (int mi = 0; mi < 2; ++mi)
#pragma unroll
        for (int ni = 0; ni < 4; ++ni)
          s2[mi][ni] = mfma16(kf[ni], qf[mi][kc], s2[mi][ni]);
    }
    bfrag4 pf[2][4];
#pragma unroll
    for (int ni = 0; ni < 4; ++ni) {
      const f32x4 bias4 = *(const f32x4*)&mlb[cur][ni * 16 + rg * 4];
#pragma unroll
      for (int mi = 0; mi < 2; ++mi) {
        const float p0 = exp2f(fmaf(s2[mi][ni][0], C1, bias4[0]));
        const float p1 = exp2f(fmaf(s2[mi][ni][1], C1, bias4[1]));
        const float p2 = exp2f(fmaf(s2[mi][ni][2], C1, bias4[2]));
        const float p3 = exp2f(fmaf(s2[mi][ni][3], C1, bias4[3]));
        l_part[mi] += (p0 + p1) + (p2 + p3);
        union { bfrag4 v; unsigned u[2]; } pk;
        pk.u[0] = cvt_pk_bf16(p0, p1);
        pk.u[1] = cvt_pk_bf16(p2, p3);
        pf[mi][ni] = pk.v;
      }
    }
#pragma unroll
    for (int ni = 0; ni < 4; ++ni) {
      bfrag4 vf[4];
#pragma unroll
      for (int di = 0; di < 4; ++di)
        vf[di] = *(const bfrag4*)&Vc[(di * 16 + col) * 72 + ni * 16 + rg * 4];
#pragma unroll
      for (int mi = 0; mi < 2; ++mi)
#pragma unroll
        for (int di = 0; di < 4; ++di)
          oa[mi][di] = mfma16k16(pf[mi][ni], vf[di], oa[mi][di]);
    }

    // ---- write next tile into the other buffer ----
    if (t < 7) {
      const int nb = cur ^ 1;
#pragma unroll
      for (int it = 0; it < 2; ++it) {
        const int idx = it * 256 + tid;
        const int key = idx >> 3, part = idx & 7;
        *(int4*)&Kl[nb][key * 72 + part * 8] = kreg[it];
      }
#pragma unroll
      for (int it = 0; it < 2; ++it) {
        const int idx = it * 256 + tid;
        const int d = idx >> 3, k8 = (idx & 7) * 8;
        *(int4*)&Vt[nb][d * 72 + k8] = vreg[it];
      }
      if (tid < 64) mlb[nb][tid] = mreg;
    }
    __syncthreads();   // one barrier per tile: readers done + next buf ready
  }

  // denominator: reduce across rg groups, bpermute 1/l to row layout
  float linv[2][4];
#pragma unroll
  for (int mi = 0; mi < 2; ++mi) {
    float l = l_part[mi];
    l += __shfl_xor(l, 16);
    l += __shfl_xor(l, 32);
#pragma unroll
    for (int r = 0; r < 4; ++r) {
      int lv = __builtin_amdgcn_ds_bpermute((rg * 4 + r) * 4, __float_as_int(l));
      linv[mi][r] = 1.f / __int_as_float(lv);
    }
  }
#pragma unroll
  for (int mi = 0; mi < 2; ++mi)
#pragma unroll
    for (int r = 0; r < 4; ++r) {
      const size_t row = (size_t)b * N_ + q0 + wq + mi * 16 + rg * 4 + r;
#pragma unroll
      for (int di = 0; di < 4; ++di)
        o[row * C_ + h * HD_ + di * 16 + col] = f2bf(oa[mi][di][r] * linv[mi][r]);
    }
}

// ---------------------------------------------------------------------------
// Launch
// ---------------------------------------------------------------------------
extern "C" void kernel_launch(void* const* d_in, const int* in_sizes, int n_in,
                              void* d_out, int out_size, void* d_ws, size_t ws_size,
                              hipStream_t stream) {
  (void)in_sizes; (void)n_in; (void)out_size; (void)ws_size;
  const float* x       = (const float*)d_in[0];
  const float* context = (const float*)d_in[1];
  const int*   mask    = (const int*)d_in[2];
  const float* ln_w    = (const float*)d_in[3];
  const float* ln_b    = (const float*)d_in[4];
  const float* Wq      = (const float*)d_in[5];
  const float* Wk      = (const float*)d_in[6];
  const float* Wv      = (const float*)d_in[7];
  const float* Wo      = (const float*)d_in[8];
  const float* Wctx    = (const float*)d_in[9];

  char* wsb = (char*)d_ws;
  ushort* qb    = (ushort*)(wsb + 0);          // 16384x512 bf16
  ushort* kb    = (ushort*)(wsb + 16777216);   //  8192x512
  ushort* vb    = (ushort*)(wsb + 25165824);   //  8192x512 (V^T: (b*512+e)*512+l)
  ushort* atto  = (ushort*)(wsb + 33554432);   // 16384x512 (attn out)
  ushort* ctx   = (ushort*)(wsb + 50331648);   //  8192x512
  ushort* wctxb = (ushort*)(wsb + 58720256);   //   512x768
  ushort* wqb   = (ushort*)(wsb + 59506688);   //   512x512 each
  ushort* wkb   = (ushort*)(wsb + 60030976);
  ushort* wvb   = (ushort*)(wsb + 60555264);
  ushort* wob   = (ushort*)(wsb + 61079552);
  float*  mub   = (float*)(wsb + 61603840);    // 16384 f32
  float*  rsb   = (float*)(wsb + 61669376);    // 16384 f32

  cast5_kernel<<<1408, 256, 0, stream>>>(Wctx, Wq, Wk, Wv, Wo,
                                         wctxb, wqb, wkb, wvb, wob);
  ln_stats<<<dim3(B_, N_ / 64), 1024, 0, stream>>>(x, mub, rsb);
  // FUSED: ctx = context @ Wctx^T  ||  q = LN(x) @ Wq^T  (768 blocks)
  gemm_ctxlnq<<<768, 256, 0, stream>>>(context, wctxb, ctx,
                                       x, mub, rsb, ln_w, ln_b, wqb, qb);
  // k row-major, v TRANSPOSED (e-major) for attn staging
  gemm_kv<<<dim3(64, 8), 256, 0, stream>>>(ctx, wkb, wvb, kb, vb);
  // XCD-swizzled 1D grid (T1): all q-blocks of one (b,h) on the same XCD
  attn_mfma<<<1024, 256, 0, stream>>>(qb, kb, vb, mask, atto);
  // out = transpose(atto @ Wo^T) + x, fused epilogue, global_load_lds staging
  gemm_res<<<dim3(128, 4), 256, 0, stream>>>(atto, wob, x, (float*)d_out);
}

// Round 20
// 148.220 us; speedup vs baseline: 7.2343x; 1.0628x over previous
//
#include <hip/hip_runtime.h>

// Problem constants
#define B_   16
#define C_   512
#define N_   1024   // H*W
#define L_   512
#define CTX_ 768
#define NH_  8
#define HD_  64
#define EPS_ 1e-5f

typedef short bfrag  __attribute__((ext_vector_type(8)));  // 8 x bf16 bits
typedef short bfrag4 __attribute__((ext_vector_type(4)));  // 4 x bf16 bits
typedef float f32x4  __attribute__((ext_vector_type(4)));

// manual RNE f32->bf16 (finite inputs); measured equal to native (r10).
__device__ __forceinline__ ushort f2bf(float f) {
  union { float f; unsigned u; } v; v.f = f;
  unsigned r = v.u + 0x7fffu + ((v.u >> 16) & 1u);
  return (ushort)(r >> 16);
}

__device__ __forceinline__ f32x4 mfma16(bfrag a, bfrag b, f32x4 c) {
  return __builtin_amdgcn_mfma_f32_16x16x32_bf16(a, b, c, 0, 0, 0);
}
__device__ __forceinline__ f32x4 mfma16k16(bfrag4 a, bfrag4 b, f32x4 c) {
  return __builtin_amdgcn_mfma_f32_16x16x16bf16_1k(a, b, c, 0, 0, 0);
}
// pack 2 f32 -> 1 dword of 2 bf16 (lo in [15:0], hi in [31:16]), RNE
__device__ __forceinline__ unsigned cvt_pk_bf16(float lo, float hi) {
  unsigned d;
  asm("v_cvt_pk_bf16_f32 %0, %1, %2" : "=v"(d) : "v"(lo), "v"(hi));
  return d;
}

// async global->LDS, 16B/lane. dst must be wave-uniform base + lane*16.
__device__ __forceinline__ void g2l16(const ushort* g, ushort* l) {
  __builtin_amdgcn_global_load_lds(
      (const __attribute__((address_space(1))) void*)g,
      (__attribute__((address_space(3))) void*)l, 16, 0, 0);
}

// ---------------------------------------------------------------------------
// fused casts: context (1572864 f4) + Wctx (98304) + Wq/Wk/Wv/Wo (65536 each).
// Round-20: context cast restored (r19 counters: reading context fp32 per e0
// tile cost ~100MB of the 117MB FETCH in gemm_ctxlnq).
// ---------------------------------------------------------------------------
__global__ __launch_bounds__(256) void cast6_kernel(
    const float* __restrict__ s0, const float* __restrict__ s1,
    const float* __restrict__ s2, const float* __restrict__ s3,
    const float* __restrict__ s4, const float* __restrict__ s5,
    ushort* __restrict__ d0, ushort* __restrict__ d1, ushort* __restrict__ d2,
    ushort* __restrict__ d3, ushort* __restrict__ d4, ushort* __restrict__ d5) {
  int i = blockIdx.x * 256 + threadIdx.x;   // float4 index, total 1933312
  const float* src; ushort* dst; int off;
  if      (i < 1572864) { src = s0; dst = d0; off = i; }            // context
  else if (i < 1671168) { src = s1; dst = d1; off = i - 1572864; }  // Wctx
  else if (i < 1736704) { src = s2; dst = d2; off = i - 1671168; }  // Wq
  else if (i < 1802240) { src = s3; dst = d3; off = i - 1736704; }  // Wk
  else if (i < 1867776) { src = s4; dst = d4; off = i - 1802240; }  // Wv
  else                  { src = s5; dst = d5; off = i - 1867776; }  // Wo
  float4 vv = ((const float4*)src)[off];
  ushort4 o;
  o.x = f2bf(vv.x); o.y = f2bf(vv.y); o.z = f2bf(vv.z); o.w = f2bf(vv.w);
  ((ushort4*)dst)[off] = o;
}

// ---------------------------------------------------------------------------
// LayerNorm over C with transpose (B,C,N) -> bf16 hn[(b*N+n)*C + c].
// r11-proven 1024-thread version (restored: materializing hn once beats
// re-deriving LN per e0 tile inside the q-GEMM staging).
// ---------------------------------------------------------------------------
__global__ __launch_bounds__(1024) void ln_kernel(const float* __restrict__ x,
                                                  const float* __restrict__ w,
                                                  const float* __restrict__ bia,
                                                  ushort* __restrict__ hn) {
  const int b  = blockIdx.x;
  const int n0 = blockIdx.y * 64;
  const int tid = threadIdx.x;
  const int nx = tid & 63, cg = tid >> 6;   // cg 0..15
  const float* xb = x + (size_t)b * C_ * N_;

  float s = 0.f, s2 = 0.f;
  for (int c = cg; c < C_; c += 16) {
    float v = xb[(size_t)c * N_ + n0 + nx];
    s += v; s2 += v * v;
  }
  __shared__ float red[2][16][64];
  __shared__ float mean[64], rstd[64];
  red[0][cg][nx] = s; red[1][cg][nx] = s2;
  __syncthreads();
  if (cg == 0) {
    float ss = 0.f, ss2 = 0.f;
#pragma unroll
    for (int i = 0; i < 16; ++i) { ss += red[0][i][nx]; ss2 += red[1][i][nx]; }
    float mu  = ss * (1.f / C_);
    float var = ss2 * (1.f / C_) - mu * mu;
    mean[nx] = mu;
    rstd[nx] = rsqrtf(var + EPS_);
  }
  __syncthreads();

  __shared__ float tile[64][65];
  for (int ct = 0; ct < 8; ++ct) {
    const int c0 = ct * 64;
    for (int cy = cg; cy < 64; cy += 16)
      tile[cy][nx] = xb[(size_t)(c0 + cy) * N_ + n0 + nx];
    __syncthreads();
    const int cx = tid & 63, ng = tid >> 6;
    const float wv = w[c0 + cx], bv = bia[c0 + cx];
    for (int ny = ng; ny < 64; ny += 16) {
      float val = (tile[cx][ny] - mean[ny]) * rstd[ny] * wv + bv;
      hn[((size_t)b * N_ + n0 + ny) * C_ + c0 + cx] = f2bf(val);
    }
    __syncthreads();
  }
}

// ---------------------------------------------------------------------------
// Shared GEMM core (bf16 inputs): 128x128x32 tile, 4 waves, 4x4 frags.
// global_load_lds width-16 staging into LINEAR [128][32] LDS, XOR-swizzled
// source/read quad (both-sides involution).
// ---------------------------------------------------------------------------
__device__ __forceinline__ void gemm_core(const ushort* __restrict__ A,
                                          const ushort* __restrict__ W,
                                          int K, ushort* la, ushort* lb,
                                          f32x4 acc[4][4],
                                          int tid, int wm, int we, int col, int rg) {
  const int lane = tid & 63, w = tid >> 6;
  const int rloc = lane >> 2, pt = lane & 3;
  const int pts = pt ^ ((rloc >> 1) & 3);       // source quad pre-swizzle
  const int qsel = (rg ^ ((col >> 1) & 3)) * 8; // read quad select (ushorts)

  for (int k0 = 0; k0 < K; k0 += 32) {
#pragma unroll
    for (int c = 0; c < 2; ++c) {
      const int chunk = w + c * 4;              // 16-row chunk, wave-uniform
      const int row = chunk * 16 + rloc;
      g2l16(A + (size_t)row * K + k0 + pts * 8, la + chunk * 512);
      g2l16(W + (size_t)row * K + k0 + pts * 8, lb + chunk * 512);
    }
    __syncthreads();
    bfrag af[4], bf[4];
#pragma unroll
    for (int i = 0; i < 4; ++i) {
      af[i] = *(const bfrag*)&la[(wm + i * 16 + col) * 32 + qsel];
      bf[i] = *(const bfrag*)&lb[(we + i * 16 + col) * 32 + qsel];
    }
#pragma unroll
    for (int i = 0; i < 4; ++i)
#pragma unroll
      for (int j = 0; j < 4; ++j)
        acc[i][j] = mfma16(af[i], bf[j], acc[i][j]);
    __syncthreads();
  }
}

// ---------------------------------------------------------------------------
// Round-20: FUSED ctx + q projections, BOTH through gemm_core on bf16 A
// (r19's 63us/117MB dispatch was fp32-A re-reads + in-staging VALU).
// Blocks 0..255: ctx = ctxb @ Wctx^T (K=768). 256..767: q = hn @ Wq^T (K=512).
// ---------------------------------------------------------------------------
__global__ __launch_bounds__(256) void gemm_ctxq(const ushort* __restrict__ ctxb,
                                                 const ushort* __restrict__ Wctxb,
                                                 ushort* __restrict__ ctxo,
                                                 const ushort* __restrict__ hn,
                                                 const ushort* __restrict__ Wqb,
                                                 ushort* __restrict__ qo) {
  __shared__ ushort la[128 * 32];
  __shared__ ushort lb[128 * 32];
  const int bid = blockIdx.x;
  const int tid = threadIdx.x, lane = tid & 63, w = tid >> 6;
  const int wm = (w >> 1) * 64, we = (w & 1) * 64;
  const int col = lane & 15, rg = lane >> 4;

  const ushort* A; const ushort* W; ushort* out; int K, m0, e0;
  if (bid < 256) {
    m0 = (bid >> 2) * 128; e0 = (bid & 3) * 128;
    A = ctxb; W = Wctxb; out = ctxo; K = CTX_;
  } else {
    const int b2 = bid - 256;
    m0 = (b2 >> 2) * 128; e0 = (b2 & 3) * 128;
    A = hn; W = Wqb; out = qo; K = C_;
  }

  f32x4 acc[4][4] = {};
  gemm_core(A + (size_t)m0 * K, W + (size_t)e0 * K, K, la, lb, acc, tid, wm, we, col, rg);

#pragma unroll
  for (int i = 0; i < 4; ++i)
#pragma unroll
    for (int j = 0; j < 4; ++j)
#pragma unroll
      for (int r = 0; r < 4; ++r)
        out[(size_t)(m0 + wm + i * 16 + rg * 4 + r) * 512 + e0 + we + j * 16 + col] =
            f2bf(acc[i][j][r]);
}

// ---------------------------------------------------------------------------
// fused K+V projection: blockIdx.y<4 -> K-proj (row-major out), else V-proj
// with TRANSPOSED output vt[(b*512+e)*512+l].
// ---------------------------------------------------------------------------
__global__ __launch_bounds__(256) void gemm_kv(const ushort* __restrict__ A,
                                               const ushort* __restrict__ Wk,
                                               const ushort* __restrict__ Wv,
                                               ushort* __restrict__ Ko,
                                               ushort* __restrict__ Vt_g) {
  __shared__ ushort la[128 * 32];
  __shared__ ushort lb[128 * 32];
  __shared__ float T[16][132];
  const int isv = blockIdx.y >> 2;
  const ushort* W = isv ? Wv : Wk;
  const int m0 = blockIdx.x * 128, e0 = (blockIdx.y & 3) * 128;
  const int tid = threadIdx.x, lane = tid & 63, w = tid >> 6;
  const int wm = (w >> 1) * 64, we = (w & 1) * 64;
  const int col = lane & 15, rg = lane >> 4;

  f32x4 acc[4][4] = {};
  gemm_core(A + (size_t)m0 * C_, W + (size_t)e0 * C_, C_, la, lb, acc, tid, wm, we, col, rg);

  if (!isv) {
#pragma unroll
    for (int i = 0; i < 4; ++i)
#pragma unroll
      for (int j = 0; j < 4; ++j)
#pragma unroll
        for (int r = 0; r < 4; ++r)
          Ko[(size_t)(m0 + wm + i * 16 + rg * 4 + r) * 512 + e0 + we + j * 16 + col] =
              f2bf(acc[i][j][r]);
  } else {
    // transposed V write via LDS tile: e-major output
    const int b = m0 >> 9, l0 = m0 & 511;
#pragma unroll
    for (int g = 0; g < 8; ++g) {
      if ((w & 1) == (g >> 2)) {        // wave-uniform: we-half owns this group
        const int j = g & 3;
#pragma unroll
        for (int i = 0; i < 4; ++i)
          *(f32x4*)&T[col][wm + i * 16 + rg * 4] = acc[i][j];
      }
      __syncthreads();
      const int n = tid & 127;
      for (int cc = tid >> 7; cc < 16; cc += 2) {
        const int e = e0 + g * 16 + cc;
        Vt_g[((size_t)b * 512 + e) * 512 + l0 + n] = f2bf(T[cc][n]);
      }
      __syncthreads();
    }
  }
}

// o-projection + transposed residual epilogue: out[b][c][n] = (A@Wo^T)+x
__global__ __launch_bounds__(256) void gemm_res(const ushort* __restrict__ A,
                                                const ushort* __restrict__ W,
                                                const float* __restrict__ x,
                                                float* __restrict__ out) {
  __shared__ ushort la[128 * 32];
  __shared__ ushort lb[128 * 32];
  __shared__ float T[16][132];
  const int m0 = blockIdx.x * 128, e0 = blockIdx.y * 128;
  const int tid = threadIdx.x, lane = tid & 63, w = tid >> 6;
  const int wm = (w >> 1) * 64, we = (w & 1) * 64;
  const int col = lane & 15, rg = lane >> 4;

  f32x4 acc[4][4] = {};
  gemm_core(A + (size_t)m0 * C_, W + (size_t)e0 * C_, C_, la, lb, acc, tid, wm, we, col, rg);

  const int b = m0 >> 10, n0l = m0 & 1023;
#pragma unroll
  for (int g = 0; g < 8; ++g) {
    if ((w & 1) == (g >> 2)) {          // wave-uniform: we-half owns this group
      const int j = g & 3;
#pragma unroll
      for (int i = 0; i < 4; ++i)
        *(f32x4*)&T[col][wm + i * 16 + rg * 4] = acc[i][j];
    }
    __syncthreads();
    const int n = tid & 127;
    for (int cc = tid >> 7; cc < 16; cc += 2) {
      const int c = e0 + g * 16 + cc;
      const size_t idx = (size_t)b * C_ * N_ + (size_t)c * N_ + n0l + n;
      out[idx] = T[cc][n] + x[idx];
    }
    __syncthreads();
  }
}

// ---------------------------------------------------------------------------
// MFMA flash cross-attention (swapped QK^T, P in registers, double-buffered,
// XCD-swizzled, V pre-transposed). Unchanged from r18.
// ---------------------------------------------------------------------------
__global__ __launch_bounds__(256) void attn_mfma(const ushort* __restrict__ q,
                                                 const ushort* __restrict__ k,
                                                 const ushort* __restrict__ vt,
                                                 const int* __restrict__ mask,
                                                 ushort* __restrict__ o) {
  __shared__ ushort Kl[2][64 * 72];   // [buf][key][72]
  __shared__ ushort Vt[2][64 * 72];   // [buf][d][72]
  __shared__ float mlb[2][64];

  const int lin = blockIdx.x;           // 0..1023
  const int hb = lin & 127, qb = lin >> 7;
  const int h = hb & 7, b = hb >> 3;
  const int q0 = qb * 128;
  const int tid = threadIdx.x, lane = tid & 63, w = tid >> 6;
  const int col = lane & 15, rg = lane >> 4;
  const int wq = w * 32;
  const float C1 = 0.18033688011112042f;  // 0.125 * log2(e)

  bfrag qf[2][2];
#pragma unroll
  for (int mi = 0; mi < 2; ++mi)
#pragma unroll
    for (int kc = 0; kc < 2; ++kc)
      qf[mi][kc] = *(const bfrag*)
          &q[((size_t)b * N_ + q0 + wq + mi * 16 + col) * C_ + h * HD_ + kc * 32 + rg * 8];

  f32x4 oa[2][4] = {};
  float l_part[2] = {0.f, 0.f};   // per-lane denominator for q = col

  // prologue: stage tile 0 into buf 0
  {
#pragma unroll
    for (int it = 0; it < 2; ++it) {
      const int idx = it * 256 + tid;
      const int key = idx >> 3, part = idx & 7;
      *(int4*)&Kl[0][key * 72 + part * 8] =
          *(const int4*)&k[((size_t)b * L_ + key) * C_ + h * HD_ + part * 8];
    }
#pragma unroll
    for (int it = 0; it < 2; ++it) {    // V^T: row d, 8 keys per b128
      const int idx = it * 256 + tid;
      const int d = idx >> 3, k8 = (idx & 7) * 8;
      *(int4*)&Vt[0][d * 72 + k8] =
          *(const int4*)&vt[((size_t)b * 512 + h * HD_ + d) * 512 + k8];
    }
    if (tid < 64) mlb[0][tid] = mask[b * L_ + tid] ? 0.f : -1e30f;
  }
  __syncthreads();

  for (int t = 0; t < 8; ++t) {
    const int cur = t & 1;
    // issue next-tile loads into registers (retire at the write phase)
    int4 kreg[2];
    int4 vreg[2];
    float mreg = 0.f;
    if (t < 7) {
      const int l0n = (t + 1) * 64;
#pragma unroll
      for (int it = 0; it < 2; ++it) {
        const int idx = it * 256 + tid;
        const int key = idx >> 3, part = idx & 7;
        kreg[it] = *(const int4*)&k[((size_t)b * L_ + l0n + key) * C_ + h * HD_ + part * 8];
      }
#pragma unroll
      for (int it = 0; it < 2; ++it) {
        const int idx = it * 256 + tid;
        const int d = idx >> 3, k8 = (idx & 7) * 8;
        vreg[it] = *(const int4*)&vt[((size_t)b * 512 + h * HD_ + d) * 512 + l0n + k8];
      }
      if (tid < 64) mreg = mask[b * L_ + l0n + tid] ? 0.f : -1e30f;
    }

    // ---- compute on buf cur ----
    const ushort* Kc = &Kl[cur][0];
    const ushort* Vc = &Vt[cur][0];
    f32x4 s2[2][4] = {};
#pragma unroll
    for (int kc = 0; kc < 2; ++kc) {
      bfrag kf[4];
#pragma unroll
      for (int ni = 0; ni < 4; ++ni)
        kf[ni] = *(const bfrag*)&Kc[(ni * 16 + col) * 72 + kc * 32 + rg * 8];
#pragma unroll
      for (int mi = 0; mi < 2; ++mi)
#pragma unroll
        for (int ni = 0; ni < 4; ++ni)
          s2[mi][ni] = mfma16(kf[ni], qf[mi][kc], s2[mi][ni]);
    }
    bfrag4 pf[2][4];
#pragma unroll
    for (int ni = 0; ni < 4; ++ni) {
      const f32x4 bias4 = *(const f32x4*)&mlb[cur][ni * 16 + rg * 4];
#pragma unroll
      for (int mi = 0; mi < 2; ++mi) {
        const float p0 = exp2f(fmaf(s2[mi][ni][0], C1, bias4[0]));
        const float p1 = exp2f(fmaf(s2[mi][ni][1], C1, bias4[1]));
        const float p2 = exp2f(fmaf(s2[mi][ni][2], C1, bias4[2]));
        const float p3 = exp2f(fmaf(s2[mi][ni][3], C1, bias4[3]));
        l_part[mi] += (p0 + p1) + (p2 + p3);
        union { bfrag4 v; unsigned u[2]; } pk;
        pk.u[0] = cvt_pk_bf16(p0, p1);
        pk.u[1] = cvt_pk_bf16(p2, p3);
        pf[mi][ni] = pk.v;
      }
    }
#pragma unroll
    for (int ni = 0; ni < 4; ++ni) {
      bfrag4 vf[4];
#pragma unroll
      for (int di = 0; di < 4; ++di)
        vf[di] = *(const bfrag4*)&Vc[(di * 16 + col) * 72 + ni * 16 + rg * 4];
#pragma unroll
      for (int mi = 0; mi < 2; ++mi)
#pragma unroll
        for (int di = 0; di < 4; ++di)
          oa[mi][di] = mfma16k16(pf[mi][ni], vf[di], oa[mi][di]);
    }

    // ---- write next tile into the other buffer ----
    if (t < 7) {
      const int nb = cur ^ 1;
#pragma unroll
      for (int it = 0; it < 2; ++it) {
        const int idx = it * 256 + tid;
        const int key = idx >> 3, part = idx & 7;
        *(int4*)&Kl[nb][key * 72 + part * 8] = kreg[it];
      }
#pragma unroll
      for (int it = 0; it < 2; ++it) {
        const int idx = it * 256 + tid;
        const int d = idx >> 3, k8 = (idx & 7) * 8;
        *(int4*)&Vt[nb][d * 72 + k8] = vreg[it];
      }
      if (tid < 64) mlb[nb][tid] = mreg;
    }
    __syncthreads();   // one barrier per tile: readers done + next buf ready
  }

  // denominator: reduce across rg groups, bpermute 1/l to row layout
  float linv[2][4];
#pragma unroll
  for (int mi = 0; mi < 2; ++mi) {
    float l = l_part[mi];
    l += __shfl_xor(l, 16);
    l += __shfl_xor(l, 32);
#pragma unroll
    for (int r = 0; r < 4; ++r) {
      int lv = __builtin_amdgcn_ds_bpermute((rg * 4 + r) * 4, __float_as_int(l));
      linv[mi][r] = 1.f / __int_as_float(lv);
    }
  }
#pragma unroll
  for (int mi = 0; mi < 2; ++mi)
#pragma unroll
    for (int r = 0; r < 4; ++r) {
      const size_t row = (size_t)b * N_ + q0 + wq + mi * 16 + rg * 4 + r;
#pragma unroll
      for (int di = 0; di < 4; ++di)
        o[row * C_ + h * HD_ + di * 16 + col] = f2bf(oa[mi][di][r] * linv[mi][r]);
    }
}

// ---------------------------------------------------------------------------
// Launch
// ---------------------------------------------------------------------------
extern "C" void kernel_launch(void* const* d_in, const int* in_sizes, int n_in,
                              void* d_out, int out_size, void* d_ws, size_t ws_size,
                              hipStream_t stream) {
  (void)in_sizes; (void)n_in; (void)out_size; (void)ws_size;
  const float* x       = (const float*)d_in[0];
  const float* context = (const float*)d_in[1];
  const int*   mask    = (const int*)d_in[2];
  const float* ln_w    = (const float*)d_in[3];
  const float* ln_b    = (const float*)d_in[4];
  const float* Wq      = (const float*)d_in[5];
  const float* Wk      = (const float*)d_in[6];
  const float* Wv      = (const float*)d_in[7];
  const float* Wo      = (const float*)d_in[8];
  const float* Wctx    = (const float*)d_in[9];

  char* wsb = (char*)d_ws;
  ushort* qb    = (ushort*)(wsb + 0);          // 16384x512 bf16
  ushort* kb    = (ushort*)(wsb + 16777216);   //  8192x512
  ushort* vb    = (ushort*)(wsb + 25165824);   //  8192x512 (V^T: (b*512+e)*512+l)
  ushort* atto  = (ushort*)(wsb + 33554432);   // 16384x512 (attn out)
  ushort* ctx   = (ushort*)(wsb + 50331648);   //  8192x512 (projected context)
  ushort* wctxb = (ushort*)(wsb + 58720256);   //   512x768
  ushort* wqb   = (ushort*)(wsb + 59506688);   //   512x512 each
  ushort* wkb   = (ushort*)(wsb + 60030976);
  ushort* wvb   = (ushort*)(wsb + 60555264);
  ushort* wob   = (ushort*)(wsb + 61079552);
  ushort* hn    = (ushort*)(wsb + 61603840);   // 16384x512 bf16 (LN'd hidden)
  ushort* ctxb  = (ushort*)(wsb + 78381056);   //  8192x768 bf16 (context cast)
  // total 90,963,968 bytes

  cast6_kernel<<<7552, 256, 0, stream>>>(context, Wctx, Wq, Wk, Wv, Wo,
                                         ctxb, wctxb, wqb, wkb, wvb, wob);
  ln_kernel<<<dim3(B_, N_ / 64), 1024, 0, stream>>>(x, ln_w, ln_b, hn);
  // FUSED: ctx = ctxb @ Wctx^T || q = hn @ Wq^T, both via gemm_core (768 blk)
  gemm_ctxq<<<768, 256, 0, stream>>>(ctxb, wctxb, ctx, hn, wqb, qb);
  // k row-major, v TRANSPOSED (e-major) for attn staging
  gemm_kv<<<dim3(64, 8), 256, 0, stream>>>(ctx, wkb, wvb, kb, vb);
  // XCD-swizzled 1D grid (T1): all q-blocks of one (b,h) on the same XCD
  attn_mfma<<<1024, 256, 0, stream>>>(qb, kb, vb, mask, atto);
  // out = transpose(atto @ Wo^T) + x, fused epilogue
  gemm_res<<<dim3(128, 4), 256, 0, stream>>>(atto, wob, x, (float*)d_out);
}

// Round 21
// 146.587 us; speedup vs baseline: 7.3149x; 1.0111x over previous
//
#include <hip/hip_runtime.h>

// Problem constants
#define B_   16
#define C_   512
#define N_   1024   // H*W
#define L_   512
#define CTX_ 768
#define NH_  8
#define HD_  64
#define EPS_ 1e-5f

typedef short bfrag  __attribute__((ext_vector_type(8)));  // 8 x bf16 bits
typedef short bfrag4 __attribute__((ext_vector_type(4)));  // 4 x bf16 bits
typedef float f32x4  __attribute__((ext_vector_type(4)));

// manual RNE f32->bf16 (finite inputs); measured equal to native (r10).
__device__ __forceinline__ ushort f2bf(float f) {
  union { float f; unsigned u; } v; v.f = f;
  unsigned r = v.u + 0x7fffu + ((v.u >> 16) & 1u);
  return (ushort)(r >> 16);
}

__device__ __forceinline__ f32x4 mfma16(bfrag a, bfrag b, f32x4 c) {
  return __builtin_amdgcn_mfma_f32_16x16x32_bf16(a, b, c, 0, 0, 0);
}
__device__ __forceinline__ f32x4 mfma16k16(bfrag4 a, bfrag4 b, f32x4 c) {
  return __builtin_amdgcn_mfma_f32_16x16x16bf16_1k(a, b, c, 0, 0, 0);
}
// pack 2 f32 -> 1 dword of 2 bf16 (lo in [15:0], hi in [31:16]), RNE
__device__ __forceinline__ unsigned cvt_pk_bf16(float lo, float hi) {
  unsigned d;
  asm("v_cvt_pk_bf16_f32 %0, %1, %2" : "=v"(d) : "v"(lo), "v"(hi));
  return d;
}

// async global->LDS, 16B/lane. dst must be wave-uniform base + lane*16.
__device__ __forceinline__ void g2l16(const ushort* g, ushort* l) {
  __builtin_amdgcn_global_load_lds(
      (const __attribute__((address_space(1))) void*)g,
      (__attribute__((address_space(3))) void*)l, 16, 0, 0);
}

// ---------------------------------------------------------------------------
// fused casts: context (1572864 f4) + Wctx (98304) + Wq/Wk/Wv/Wo (65536 each).
// ---------------------------------------------------------------------------
__global__ __launch_bounds__(256) void cast6_kernel(
    const float* __restrict__ s0, const float* __restrict__ s1,
    const float* __restrict__ s2, const float* __restrict__ s3,
    const float* __restrict__ s4, const float* __restrict__ s5,
    ushort* __restrict__ d0, ushort* __restrict__ d1, ushort* __restrict__ d2,
    ushort* __restrict__ d3, ushort* __restrict__ d4, ushort* __restrict__ d5) {
  int i = blockIdx.x * 256 + threadIdx.x;   // float4 index, total 1933312
  const float* src; ushort* dst; int off;
  if      (i < 1572864) { src = s0; dst = d0; off = i; }            // context
  else if (i < 1671168) { src = s1; dst = d1; off = i - 1572864; }  // Wctx
  else if (i < 1736704) { src = s2; dst = d2; off = i - 1671168; }  // Wq
  else if (i < 1802240) { src = s3; dst = d3; off = i - 1736704; }  // Wk
  else if (i < 1867776) { src = s4; dst = d4; off = i - 1802240; }  // Wv
  else                  { src = s5; dst = d5; off = i - 1867776; }  // Wo
  float4 vv = ((const float4*)src)[off];
  ushort4 o;
  o.x = f2bf(vv.x); o.y = f2bf(vv.y); o.z = f2bf(vv.z); o.w = f2bf(vv.w);
  ((ushort4*)dst)[off] = o;
}

// ---------------------------------------------------------------------------
// LayerNorm over C with transpose (B,C,N) -> bf16 hn[(b*N+n)*C + c].
// ---------------------------------------------------------------------------
__global__ __launch_bounds__(1024) void ln_kernel(const float* __restrict__ x,
                                                  const float* __restrict__ w,
                                                  const float* __restrict__ bia,
                                                  ushort* __restrict__ hn) {
  const int b  = blockIdx.x;
  const int n0 = blockIdx.y * 64;
  const int tid = threadIdx.x;
  const int nx = tid & 63, cg = tid >> 6;   // cg 0..15
  const float* xb = x + (size_t)b * C_ * N_;

  float s = 0.f, s2 = 0.f;
  for (int c = cg; c < C_; c += 16) {
    float v = xb[(size_t)c * N_ + n0 + nx];
    s += v; s2 += v * v;
  }
  __shared__ float red[2][16][64];
  __shared__ float mean[64], rstd[64];
  red[0][cg][nx] = s; red[1][cg][nx] = s2;
  __syncthreads();
  if (cg == 0) {
    float ss = 0.f, ss2 = 0.f;
#pragma unroll
    for (int i = 0; i < 16; ++i) { ss += red[0][i][nx]; ss2 += red[1][i][nx]; }
    float mu  = ss * (1.f / C_);
    float var = ss2 * (1.f / C_) - mu * mu;
    mean[nx] = mu;
    rstd[nx] = rsqrtf(var + EPS_);
  }
  __syncthreads();

  __shared__ float tile[64][65];
  for (int ct = 0; ct < 8; ++ct) {
    const int c0 = ct * 64;
    for (int cy = cg; cy < 64; cy += 16)
      tile[cy][nx] = xb[(size_t)(c0 + cy) * N_ + n0 + nx];
    __syncthreads();
    const int cx = tid & 63, ng = tid >> 6;
    const float wv = w[c0 + cx], bv = bia[c0 + cx];
    for (int ny = ng; ny < 64; ny += 16) {
      float val = (tile[cx][ny] - mean[ny]) * rstd[ny] * wv + bv;
      hn[((size_t)b * N_ + n0 + ny) * C_ + c0 + cx] = f2bf(val);
    }
    __syncthreads();
  }
}

// ---------------------------------------------------------------------------
// Shared GEMM core (bf16 inputs): 128x128x32 tile, 4 waves, 4x4 frags.
// global_load_lds width-16 staging into LINEAR [128][32] LDS, XOR-swizzled
// source/read quad (both-sides involution).
// ---------------------------------------------------------------------------
__device__ __forceinline__ void gemm_core(const ushort* __restrict__ A,
                                          const ushort* __restrict__ W,
                                          int K, ushort* la, ushort* lb,
                                          f32x4 acc[4][4],
                                          int tid, int wm, int we, int col, int rg) {
  const int lane = tid & 63, w = tid >> 6;
  const int rloc = lane >> 2, pt = lane & 3;
  const int pts = pt ^ ((rloc >> 1) & 3);       // source quad pre-swizzle
  const int qsel = (rg ^ ((col >> 1) & 3)) * 8; // read quad select (ushorts)

  for (int k0 = 0; k0 < K; k0 += 32) {
#pragma unroll
    for (int c = 0; c < 2; ++c) {
      const int chunk = w + c * 4;              // 16-row chunk, wave-uniform
      const int row = chunk * 16 + rloc;
      g2l16(A + (size_t)row * K + k0 + pts * 8, la + chunk * 512);
      g2l16(W + (size_t)row * K + k0 + pts * 8, lb + chunk * 512);
    }
    __syncthreads();
    bfrag af[4], bf[4];
#pragma unroll
    for (int i = 0; i < 4; ++i) {
      af[i] = *(const bfrag*)&la[(wm + i * 16 + col) * 32 + qsel];
      bf[i] = *(const bfrag*)&lb[(we + i * 16 + col) * 32 + qsel];
    }
#pragma unroll
    for (int i = 0; i < 4; ++i)
#pragma unroll
      for (int j = 0; j < 4; ++j)
        acc[i][j] = mfma16(af[i], bf[j], acc[i][j]);
    __syncthreads();
  }
}

// ---------------------------------------------------------------------------
// Round-21: FUSED ctx + q projections with XCD-friendly block remap.
// r20 map bid=m*4+e put the 4 e-variants of one A-panel on 4 DIFFERENT XCDs
// (consecutive ids round-robin) -> A-panels re-fetched per XCD. New map puts
// same-m blocks 64 (ctx) / 128 (q) apart -> lin % 8 == m % 8 -> same XCD
// (the r16-measured T1 mechanism; gemm_kv/gemm_res already have this by
// their 2D-grid linearization).
// Blocks 0..255: ctx = ctxb @ Wctx^T (K=768). 256..767: q = hn @ Wq^T (K=512).
// ---------------------------------------------------------------------------
__global__ __launch_bounds__(256) void gemm_ctxq(const ushort* __restrict__ ctxb,
                                                 const ushort* __restrict__ Wctxb,
                                                 ushort* __restrict__ ctxo,
                                                 const ushort* __restrict__ hn,
                                                 const ushort* __restrict__ Wqb,
                                                 ushort* __restrict__ qo) {
  __shared__ ushort la[128 * 32];
  __shared__ ushort lb[128 * 32];
  const int bid = blockIdx.x;
  const int tid = threadIdx.x, lane = tid & 63, w = tid >> 6;
  const int wm = (w >> 1) * 64, we = (w & 1) * 64;
  const int col = lane & 15, rg = lane >> 4;

  const ushort* A; const ushort* W; ushort* out; int K, m0, e0;
  if (bid < 256) {
    m0 = (bid & 63) * 128; e0 = (bid >> 6) * 128;   // same-m blocks 64 apart
    A = ctxb; W = Wctxb; out = ctxo; K = CTX_;
  } else {
    const int b2 = bid - 256;
    m0 = (b2 & 127) * 128; e0 = (b2 >> 7) * 128;    // same-m blocks 128 apart
    A = hn; W = Wqb; out = qo; K = C_;
  }

  f32x4 acc[4][4] = {};
  gemm_core(A + (size_t)m0 * K, W + (size_t)e0 * K, K, la, lb, acc, tid, wm, we, col, rg);

#pragma unroll
  for (int i = 0; i < 4; ++i)
#pragma unroll
    for (int j = 0; j < 4; ++j)
#pragma unroll
      for (int r = 0; r < 4; ++r)
        out[(size_t)(m0 + wm + i * 16 + rg * 4 + r) * 512 + e0 + we + j * 16 + col] =
            f2bf(acc[i][j][r]);
}

// ---------------------------------------------------------------------------
// fused K+V projection: blockIdx.y<4 -> K-proj (row-major out), else V-proj
// with TRANSPOSED output vt[(b*512+e)*512+l].
// ---------------------------------------------------------------------------
__global__ __launch_bounds__(256) void gemm_kv(const ushort* __restrict__ A,
                                               const ushort* __restrict__ Wk,
                                               const ushort* __restrict__ Wv,
                                               ushort* __restrict__ Ko,
                                               ushort* __restrict__ Vt_g) {
  __shared__ ushort la[128 * 32];
  __shared__ ushort lb[128 * 32];
  __shared__ float T[16][132];
  const int isv = blockIdx.y >> 2;
  const ushort* W = isv ? Wv : Wk;
  const int m0 = blockIdx.x * 128, e0 = (blockIdx.y & 3) * 128;
  const int tid = threadIdx.x, lane = tid & 63, w = tid >> 6;
  const int wm = (w >> 1) * 64, we = (w & 1) * 64;
  const int col = lane & 15, rg = lane >> 4;

  f32x4 acc[4][4] = {};
  gemm_core(A + (size_t)m0 * C_, W + (size_t)e0 * C_, C_, la, lb, acc, tid, wm, we, col, rg);

  if (!isv) {
#pragma unroll
    for (int i = 0; i < 4; ++i)
#pragma unroll
      for (int j = 0; j < 4; ++j)
#pragma unroll
        for (int r = 0; r < 4; ++r)
          Ko[(size_t)(m0 + wm + i * 16 + rg * 4 + r) * 512 + e0 + we + j * 16 + col] =
              f2bf(acc[i][j][r]);
  } else {
    // transposed V write via LDS tile: e-major output
    const int b = m0 >> 9, l0 = m0 & 511;
#pragma unroll
    for (int g = 0; g < 8; ++g) {
      if ((w & 1) == (g >> 2)) {        // wave-uniform: we-half owns this group
        const int j = g & 3;
#pragma unroll
        for (int i = 0; i < 4; ++i)
          *(f32x4*)&T[col][wm + i * 16 + rg * 4] = acc[i][j];
      }
      __syncthreads();
      const int n = tid & 127;
      for (int cc = tid >> 7; cc < 16; cc += 2) {
        const int e = e0 + g * 16 + cc;
        Vt_g[((size_t)b * 512 + e) * 512 + l0 + n] = f2bf(T[cc][n]);
      }
      __syncthreads();
    }
  }
}

// o-projection + transposed residual epilogue: out[b][c][n] = (A@Wo^T)+x
__global__ __launch_bounds__(256) void gemm_res(const ushort* __restrict__ A,
                                                const ushort* __restrict__ W,
                                                const float* __restrict__ x,
                                                float* __restrict__ out) {
  __shared__ ushort la[128 * 32];
  __shared__ ushort lb[128 * 32];
  __shared__ float T[16][132];
  const int m0 = blockIdx.x * 128, e0 = blockIdx.y * 128;
  const int tid = threadIdx.x, lane = tid & 63, w = tid >> 6;
  const int wm = (w >> 1) * 64, we = (w & 1) * 64;
  const int col = lane & 15, rg = lane >> 4;

  f32x4 acc[4][4] = {};
  gemm_core(A + (size_t)m0 * C_, W + (size_t)e0 * C_, C_, la, lb, acc, tid, wm, we, col, rg);

  const int b = m0 >> 10, n0l = m0 & 1023;
#pragma unroll
  for (int g = 0; g < 8; ++g) {
    if ((w & 1) == (g >> 2)) {          // wave-uniform: we-half owns this group
      const int j = g & 3;
#pragma unroll
      for (int i = 0; i < 4; ++i)
        *(f32x4*)&T[col][wm + i * 16 + rg * 4] = acc[i][j];
    }
    __syncthreads();
    const int n = tid & 127;
    for (int cc = tid >> 7; cc < 16; cc += 2) {
      const int c = e0 + g * 16 + cc;
      const size_t idx = (size_t)b * C_ * N_ + (size_t)c * N_ + n0l + n;
      out[idx] = T[cc][n] + x[idx];
    }
    __syncthreads();
  }
}

// ---------------------------------------------------------------------------
// MFMA flash cross-attention (swapped QK^T, P in registers, double-buffered,
// XCD-swizzled, V pre-transposed). Unchanged from r18.
// ---------------------------------------------------------------------------
__global__ __launch_bounds__(256) void attn_mfma(const ushort* __restrict__ q,
                                                 const ushort* __restrict__ k,
                                                 const ushort* __restrict__ vt,
                                                 const int* __restrict__ mask,
                                                 ushort* __restrict__ o) {
  __shared__ ushort Kl[2][64 * 72];   // [buf][key][72]
  __shared__ ushort Vt[2][64 * 72];   // [buf][d][72]
  __shared__ float mlb[2][64];

  const int lin = blockIdx.x;           // 0..1023
  const int hb = lin & 127, qb = lin >> 7;
  const int h = hb & 7, b = hb >> 3;
  const int q0 = qb * 128;
  const int tid = threadIdx.x, lane = tid & 63, w = tid >> 6;
  const int col = lane & 15, rg = lane >> 4;
  const int wq = w * 32;
  const float C1 = 0.18033688011112042f;  // 0.125 * log2(e)

  bfrag qf[2][2];
#pragma unroll
  for (int mi = 0; mi < 2; ++mi)
#pragma unroll
    for (int kc = 0; kc < 2; ++kc)
      qf[mi][kc] = *(const bfrag*)
          &q[((size_t)b * N_ + q0 + wq + mi * 16 + col) * C_ + h * HD_ + kc * 32 + rg * 8];

  f32x4 oa[2][4] = {};
  float l_part[2] = {0.f, 0.f};   // per-lane denominator for q = col

  // prologue: stage tile 0 into buf 0
  {
#pragma unroll
    for (int it = 0; it < 2; ++it) {
      const int idx = it * 256 + tid;
      const int key = idx >> 3, part = idx & 7;
      *(int4*)&Kl[0][key * 72 + part * 8] =
          *(const int4*)&k[((size_t)b * L_ + key) * C_ + h * HD_ + part * 8];
    }
#pragma unroll
    for (int it = 0; it < 2; ++it) {    // V^T: row d, 8 keys per b128
      const int idx = it * 256 + tid;
      const int d = idx >> 3, k8 = (idx & 7) * 8;
      *(int4*)&Vt[0][d * 72 + k8] =
          *(const int4*)&vt[((size_t)b * 512 + h * HD_ + d) * 512 + k8];
    }
    if (tid < 64) mlb[0][tid] = mask[b * L_ + tid] ? 0.f : -1e30f;
  }
  __syncthreads();

  for (int t = 0; t < 8; ++t) {
    const int cur = t & 1;
    // issue next-tile loads into registers (retire at the write phase)
    int4 kreg[2];
    int4 vreg[2];
    float mreg = 0.f;
    if (t < 7) {
      const int l0n = (t + 1) * 64;
#pragma unroll
      for (int it = 0; it < 2; ++it) {
        const int idx = it * 256 + tid;
        const int key = idx >> 3, part = idx & 7;
        kreg[it] = *(const int4*)&k[((size_t)b * L_ + l0n + key) * C_ + h * HD_ + part * 8];
      }
#pragma unroll
      for (int it = 0; it < 2; ++it) {
        const int idx = it * 256 + tid;
        const int d = idx >> 3, k8 = (idx & 7) * 8;
        vreg[it] = *(const int4*)&vt[((size_t)b * 512 + h * HD_ + d) * 512 + l0n + k8];
      }
      if (tid < 64) mreg = mask[b * L_ + l0n + tid] ? 0.f : -1e30f;
    }

    // ---- compute on buf cur ----
    const ushort* Kc = &Kl[cur][0];
    const ushort* Vc = &Vt[cur][0];
    f32x4 s2[2][4] = {};
#pragma unroll
    for (int kc = 0; kc < 2; ++kc) {
      bfrag kf[4];
#pragma unroll
      for (int ni = 0; ni < 4; ++ni)
        kf[ni] = *(const bfrag*)&Kc[(ni * 16 + col) * 72 + kc * 32 + rg * 8];
#pragma unroll
      for (int mi = 0; mi < 2; ++mi)
#pragma unroll
        for (int ni = 0; ni < 4; ++ni)
          s2[mi][ni] = mfma16(kf[ni], qf[mi][kc], s2[mi][ni]);
    }
    bfrag4 pf[2][4];
#pragma unroll
    for (int ni = 0; ni < 4; ++ni) {
      const f32x4 bias4 = *(const f32x4*)&mlb[cur][ni * 16 + rg * 4];
#pragma unroll
      for (int mi = 0; mi < 2; ++mi) {
        const float p0 = exp2f(fmaf(s2[mi][ni][0], C1, bias4[0]));
        const float p1 = exp2f(fmaf(s2[mi][ni][1], C1, bias4[1]));
        const float p2 = exp2f(fmaf(s2[mi][ni][2], C1, bias4[2]));
        const float p3 = exp2f(fmaf(s2[mi][ni][3], C1, bias4[3]));
        l_part[mi] += (p0 + p1) + (p2 + p3);
        union { bfrag4 v; unsigned u[2]; } pk;
        pk.u[0] = cvt_pk_bf16(p0, p1);
        pk.u[1] = cvt_pk_bf16(p2, p3);
        pf[mi][ni] = pk.v;
      }
    }
#pragma unroll
    for (int ni = 0; ni < 4; ++ni) {
      bfrag4 vf[4];
#pragma unroll
      for (int di = 0; di < 4; ++di)
        vf[di] = *(const bfrag4*)&Vc[(di * 16 + col) * 72 + ni * 16 + rg * 4];
#pragma unroll
      for (int mi = 0; mi < 2; ++mi)
#pragma unroll
        for (int di = 0; di < 4; ++di)
          oa[mi][di] = mfma16k16(pf[mi][ni], vf[di], oa[mi][di]);
    }

    // ---- write next tile into the other buffer ----
    if (t < 7) {
      const int nb = cur ^ 1;
#pragma unroll
      for (int it = 0; it < 2; ++it) {
        const int idx = it * 256 + tid;
        const int key = idx >> 3, part = idx & 7;
        *(int4*)&Kl[nb][key * 72 + part * 8] = kreg[it];
      }
#pragma unroll
      for (int it = 0; it < 2; ++it) {
        const int idx = it * 256 + tid;
        const int d = idx >> 3, k8 = (idx & 7) * 8;
        *(int4*)&Vt[nb][d * 72 + k8] = vreg[it];
      }
      if (tid < 64) mlb[nb][tid] = mreg;
    }
    __syncthreads();   // one barrier per tile: readers done + next buf ready
  }

  // denominator: reduce across rg groups, bpermute 1/l to row layout
  float linv[2][4];
#pragma unroll
  for (int mi = 0; mi < 2; ++mi) {
    float l = l_part[mi];
    l += __shfl_xor(l, 16);
    l += __shfl_xor(l, 32);
#pragma unroll
    for (int r = 0; r < 4; ++r) {
      int lv = __builtin_amdgcn_ds_bpermute((rg * 4 + r) * 4, __float_as_int(l));
      linv[mi][r] = 1.f / __int_as_float(lv);
    }
  }
#pragma unroll
  for (int mi = 0; mi < 2; ++mi)
#pragma unroll
    for (int r = 0; r < 4; ++r) {
      const size_t row = (size_t)b * N_ + q0 + wq + mi * 16 + rg * 4 + r;
#pragma unroll
      for (int di = 0; di < 4; ++di)
        o[row * C_ + h * HD_ + di * 16 + col] = f2bf(oa[mi][di][r] * linv[mi][r]);
    }
}

// ---------------------------------------------------------------------------
// Launch
// ---------------------------------------------------------------------------
extern "C" void kernel_launch(void* const* d_in, const int* in_sizes, int n_in,
                              void* d_out, int out_size, void* d_ws, size_t ws_size,
                              hipStream_t stream) {
  (void)in_sizes; (void)n_in; (void)out_size; (void)ws_size;
  const float* x       = (const float*)d_in[0];
  const float* context = (const float*)d_in[1];
  const int*   mask    = (const int*)d_in[2];
  const float* ln_w    = (const float*)d_in[3];
  const float* ln_b    = (const float*)d_in[4];
  const float* Wq      = (const float*)d_in[5];
  const float* Wk      = (const float*)d_in[6];
  const float* Wv      = (const float*)d_in[7];
  const float* Wo      = (const float*)d_in[8];
  const float* Wctx    = (const float*)d_in[9];

  char* wsb = (char*)d_ws;
  ushort* qb    = (ushort*)(wsb + 0);          // 16384x512 bf16
  ushort* kb    = (ushort*)(wsb + 16777216);   //  8192x512
  ushort* vb    = (ushort*)(wsb + 25165824);   //  8192x512 (V^T: (b*512+e)*512+l)
  ushort* atto  = (ushort*)(wsb + 33554432);   // 16384x512 (attn out)
  ushort* ctx   = (ushort*)(wsb + 50331648);   //  8192x512 (projected context)
  ushort* wctxb = (ushort*)(wsb + 58720256);   //   512x768
  ushort* wqb   = (ushort*)(wsb + 59506688);   //   512x512 each
  ushort* wkb   = (ushort*)(wsb + 60030976);
  ushort* wvb   = (ushort*)(wsb + 60555264);
  ushort* wob   = (ushort*)(wsb + 61079552);
  ushort* hn    = (ushort*)(wsb + 61603840);   // 16384x512 bf16 (LN'd hidden)
  ushort* ctxb  = (ushort*)(wsb + 78381056);   //  8192x768 bf16 (context cast)
  // total 90,963,968 bytes

  cast6_kernel<<<7552, 256, 0, stream>>>(context, Wctx, Wq, Wk, Wv, Wo,
                                         ctxb, wctxb, wqb, wkb, wvb, wob);
  ln_kernel<<<dim3(B_, N_ / 64), 1024, 0, stream>>>(x, ln_w, ln_b, hn);
  // FUSED: ctx = ctxb @ Wctx^T || q = hn @ Wq^T (768 blk, XCD-friendly map)
  gemm_ctxq<<<768, 256, 0, stream>>>(ctxb, wctxb, ctx, hn, wqb, qb);
  // k row-major, v TRANSPOSED (e-major) for attn staging
  gemm_kv<<<dim3(64, 8), 256, 0, stream>>>(ctx, wkb, wvb, kb, vb);
  // XCD-swizzled 1D grid (T1): all q-blocks of one (b,h) on the same XCD
  attn_mfma<<<1024, 256, 0, stream>>>(qb, kb, vb, mask, atto);
  // out = transpose(atto @ Wo^T) + x, fused epilogue
  gemm_res<<<dim3(128, 4), 256, 0, stream>>>(atto, wob, x, (float*)d_out);
}